// Round 1
// baseline (1194.398 us; speedup 1.0000x reference)
//
#include <hip/hip_runtime.h>

// ---------------- problem constants ----------------
#define B_N 8
#define D_N 512
#define T_N 36
#define HW_N 84
#define THW_N 3024
#define DT_N 4
#define OT_N 32
#define NH_N 4
#define FF_N 128
#define CH_N 32
#define DI_N 336      // demo tokens 4*84
#define OI_N 2688     // obs tokens 32*84
#define CAT_N 420
#define INV_TEMP 0.04419417382415922f   // 1/sqrt(512)
#define BN_EPS 1e-5f

// workspace float offsets
#define WS_DQ   ((size_t)0)
#define WS_DK   ((size_t)344064)
#define WS_DV   ((size_t)688128)
#define WS_DVA  ((size_t)1032192)
#define WS_OQ   ((size_t)1376256)
#define WS_OK   ((size_t)4128768)
#define WS_OV   ((size_t)6881280)
#define WS_OVA  ((size_t)9633792)
#define WS_STATS ((size_t)12386304)

// ---------------- QKV projection (demo+obs, all 6 GEMMs) ----------------
// demo: Y(128x336) = W(128x512) * X[:, 0:336]     (12 tiles/b/w, 288 blocks)
// obs : Y(128x2688) = W(128x512) * X[:, 336:3024] (84 tiles/b/w, 2016 blocks)
__global__ __launch_bounds__(256) void proj_kernel(
    const float* __restrict__ x,
    const float* __restrict__ dwq, const float* __restrict__ dwk, const float* __restrict__ dwv,
    const float* __restrict__ owq, const float* __restrict__ owk, const float* __restrict__ owv,
    float* __restrict__ ws)
{
    __shared__ float As[16][68];  // [kk][o], pad 68 -> 16B-aligned rows, 2-way max
    __shared__ float Bs[16][64];  // [kk][i]

    int bid = blockIdx.x;
    int wsel, b, mt, nt, L, off;
    const float* Wm; float* Y;
    if (bid < 288) {
        wsel = bid / 96; int rem = bid - wsel * 96;
        b = rem / 12; int tt = rem - b * 12; mt = tt / 6; nt = tt - mt * 6;
        L = DI_N; off = 0;
        Wm = wsel == 0 ? dwq : (wsel == 1 ? dwk : dwv);
        Y = ws + (size_t)wsel * (B_N * FF_N * DI_N);
    } else {
        int e = bid - 288;
        wsel = e / 672; int rem = e - wsel * 672;
        b = rem / 84; int tt = rem - b * 84; mt = tt / 42; nt = tt - mt * 42;
        L = OI_N; off = DI_N;
        Wm = wsel == 0 ? owq : (wsel == 1 ? owk : owv);
        Y = ws + WS_OQ + (size_t)wsel * (B_N * FF_N * OI_N);
    }
    const float* Xb = x + (size_t)b * D_N * THW_N + off;
    const float* Wb = Wm + (size_t)(mt * 64) * D_N;
    float* Yb = Y + (size_t)b * FF_N * L + (size_t)(mt * 64) * L + nt * 64;
    const int col0 = nt * 64;

    const int tid = threadIdx.x;
    const int ty = tid >> 4, tx = tid & 15;

    float acc[4][4] = {};

    for (int k0 = 0; k0 < D_N; k0 += 16) {
        #pragma unroll
        for (int it = 0; it < 4; ++it) {
            int l = tid + it * 256;
            int o = l >> 4, kk = l & 15;
            As[kk][o] = Wb[(size_t)o * D_N + k0 + kk];
        }
        #pragma unroll
        for (int it = 0; it < 4; ++it) {
            int l = tid + it * 256;
            int kk = l >> 6, i = l & 63;
            int col = col0 + i;
            Bs[kk][i] = (col < L) ? Xb[(size_t)(k0 + kk) * THW_N + col] : 0.f;
        }
        __syncthreads();
        #pragma unroll
        for (int kk = 0; kk < 16; ++kk) {
            const float4 a4 = *reinterpret_cast<const float4*>(&As[kk][ty * 4]);
            const float4 b4 = *reinterpret_cast<const float4*>(&Bs[kk][tx * 4]);
            const float ar[4] = {a4.x, a4.y, a4.z, a4.w};
            const float br[4] = {b4.x, b4.y, b4.z, b4.w};
            #pragma unroll
            for (int u = 0; u < 4; ++u)
                #pragma unroll
                for (int w = 0; w < 4; ++w)
                    acc[u][w] += ar[u] * br[w];
        }
        __syncthreads();
    }
    #pragma unroll
    for (int u = 0; u < 4; ++u)
        #pragma unroll
        for (int w = 0; w < 4; ++w) {
            int col = col0 + tx * 4 + w;
            if (col < L) Yb[(size_t)(ty * 4 + u) * L + tx * 4 + w] = acc[u][w];
        }
}

// ---------------- demo attention ----------------
// S[i][j] = dot_c(dk[:,i], dq[:,j]) / TEMP,  allowed j < (i/84+1)*84
// softmax over j, out[c][i] = sum_j attn[i][j] * dv[c][j]
// block: one (b, n, 32-row tile); 8 lanes per row, online softmax per lane, shfl merge
__global__ __launch_bounds__(256) void demo_attn_kernel(
    const float* __restrict__ dq, const float* __restrict__ dk,
    const float* __restrict__ dv, float* __restrict__ dva)
{
    __shared__ float k_s[32][33];
    __shared__ float q_s[32][85];
    __shared__ float v_s[32][85];

    int bid = blockIdx.x;
    int b = bid / 44; int rem = bid - b * 44; int n = rem / 11; int rt = rem - n * 11;
    int r0 = rt * 32;

    const float* dq_b = dq + ((size_t)b * FF_N + n * CH_N) * DI_N;
    const float* dk_b = dk + ((size_t)b * FF_N + n * CH_N) * DI_N;
    const float* dv_b = dv + ((size_t)b * FF_N + n * CH_N) * DI_N;
    float* dva_b = dva + ((size_t)b * FF_N + n * CH_N) * DI_N;

    const int tid = threadIdx.x;

    #pragma unroll
    for (int it = 0; it < 4; ++it) {
        int l = tid + it * 256;
        int c = l >> 5, il = l & 31;
        int i = r0 + il;
        k_s[c][il] = (i < DI_N) ? dk_b[(size_t)c * DI_N + i] : 0.f;
    }
    __syncthreads();

    const int row = tid >> 3, jl = tid & 7;
    const int i = r0 + row;
    const bool valid = (i < DI_N);
    const int jmax = valid ? ((i / HW_N) + 1) * HW_N : 0;

    float kr[32];
    #pragma unroll
    for (int c = 0; c < 32; ++c) kr[c] = k_s[c][row];

    float m = -3.4e38f, lsum = 0.f;
    float acc[32];
    #pragma unroll
    for (int c = 0; c < 32; ++c) acc[c] = 0.f;

    int last_i = (r0 + 31 < DI_N) ? (r0 + 31) : (DI_N - 1);
    int last = ((last_i / HW_N) + 1) * HW_N;

    for (int jc = 0; jc < last; jc += 84) {
        __syncthreads();
        for (int l = tid; l < 2688; l += 256) {
            int c = l / 84, j = l - c * 84;
            q_s[c][j] = dq_b[(size_t)c * DI_N + jc + j];
            v_s[c][j] = dv_b[(size_t)c * DI_N + jc + j];
        }
        __syncthreads();
        if (valid) {
            for (int j = jl; j < 84; j += 8) {
                int jg = jc + j;
                if (jg >= jmax) break;
                float s = 0.f;
                #pragma unroll
                for (int c = 0; c < 32; ++c) s += kr[c] * q_s[c][j];
                s *= INV_TEMP;
                if (s <= m) {
                    float e = __expf(s - m);
                    lsum += e;
                    #pragma unroll
                    for (int c = 0; c < 32; ++c) acc[c] += e * v_s[c][j];
                } else {
                    float al = __expf(m - s);
                    lsum = lsum * al + 1.f;
                    #pragma unroll
                    for (int c = 0; c < 32; ++c) acc[c] = acc[c] * al + v_s[c][j];
                    m = s;
                }
            }
        }
    }
    // merge 8 lanes of each row (online-softmax state merge)
    #pragma unroll
    for (int o = 1; o < 8; o <<= 1) {
        float mo = __shfl_xor(m, o);
        float lo = __shfl_xor(lsum, o);
        float mn = fmaxf(m, mo);
        float sa = __expf(m - mn);
        float sb = __expf(mo - mn);
        lsum = lsum * sa + lo * sb;
        #pragma unroll
        for (int c = 0; c < 32; ++c) {
            float ao = __shfl_xor(acc[c], o);
            acc[c] = acc[c] * sa + ao * sb;
        }
        m = mn;
    }
    if (valid) {
        float inv = 1.f / lsum;
        #pragma unroll
        for (int cc = 0; cc < 4; ++cc) {
            int c = jl * 4 + cc;
            dva_b[(size_t)c * DI_N + i] = acc[c] * inv;
        }
    }
}

// ---------------- obs attention ----------------
// cat_k = [dk(336) | ok(84)], cat_v = [dv_att(336) | ov(84)]
// S[j][i] = dot_c(cat_k[:,j], oq[:,i]) / TEMP   (j in 0..419, i in 0..83)
// softmax over i per row j; out[c][i] = sum_j cat_v[c][j] * A[j][i]  (NOT normalized per i)
// block: one (b,t,n); loop 5 chunks of 84 j-rows.
__global__ __launch_bounds__(256) void obs_attn_kernel(
    const float* __restrict__ dk, const float* __restrict__ dva,
    const float* __restrict__ oq, const float* __restrict__ okp, const float* __restrict__ ovp,
    float* __restrict__ ova)
{
    __shared__ float q_s[32][85];
    __shared__ float k_s[32][85];
    __shared__ float v_s[32][85];
    __shared__ float A_s[84][85];

    int bid = blockIdx.x;
    int b = bid >> 7; int rem = bid & 127; int t = rem >> 2; int n = rem & 3;

    const float* oq_b = oq + ((size_t)b * FF_N + n * CH_N) * OI_N + t * HW_N;
    const float* ok_b = okp + ((size_t)b * FF_N + n * CH_N) * OI_N + t * HW_N;
    const float* ov_b = ovp + ((size_t)b * FF_N + n * CH_N) * OI_N + t * HW_N;
    const float* dk_b = dk + ((size_t)b * FF_N + n * CH_N) * DI_N;
    const float* dva_b = dva + ((size_t)b * FF_N + n * CH_N) * DI_N;
    float* out_b = ova + (((size_t)b * OT_N + t) * FF_N + n * CH_N) * HW_N;

    const int tid = threadIdx.x;

    for (int l = tid; l < 2688; l += 256) {
        int c = l / 84, i = l - c * 84;
        q_s[c][i] = oq_b[(size_t)c * OI_N + i];
    }

    const int cq = tid >> 5, ig = tid & 31;
    float acc[4][3] = {};

    for (int jc = 0; jc < CAT_N; jc += 84) {
        __syncthreads();
        if (jc < DI_N) {
            for (int l = tid; l < 2688; l += 256) {
                int c = l / 84, j = l - c * 84;
                k_s[c][j] = dk_b[(size_t)c * DI_N + jc + j];
                v_s[c][j] = dva_b[(size_t)c * DI_N + jc + j];
            }
        } else {
            for (int l = tid; l < 2688; l += 256) {
                int c = l / 84, j = l - c * 84;
                k_s[c][j] = ok_b[(size_t)c * OI_N + j];
                v_s[c][j] = ov_b[(size_t)c * OI_N + j];
            }
        }
        __syncthreads();

        // phase A: scores, 4x4 register tiles over 21x21 tile grid
        for (int tile = tid; tile < 441; tile += 256) {
            int tj = tile / 21, ti = tile - tj * 21;
            int j0 = tj * 4, i0 = ti * 4;
            float sacc[4][4] = {};
            #pragma unroll
            for (int c = 0; c < 32; ++c) {
                float kv[4], qv[4];
                #pragma unroll
                for (int u = 0; u < 4; ++u) { kv[u] = k_s[c][j0 + u]; qv[u] = q_s[c][i0 + u]; }
                #pragma unroll
                for (int u = 0; u < 4; ++u)
                    #pragma unroll
                    for (int w = 0; w < 4; ++w)
                        sacc[u][w] += kv[u] * qv[w];
            }
            #pragma unroll
            for (int u = 0; u < 4; ++u)
                #pragma unroll
                for (int w = 0; w < 4; ++w)
                    A_s[j0 + u][i0 + w] = sacc[u][w] * INV_TEMP;
        }
        __syncthreads();

        // phase B: row softmax over i (84), normalized in place
        if (tid < 84) {
            int j = tid;
            float mx = -3.4e38f;
            for (int i2 = 0; i2 < 84; ++i2) mx = fmaxf(mx, A_s[j][i2]);
            float s = 0.f;
            for (int i2 = 0; i2 < 84; ++i2) { float e = __expf(A_s[j][i2] - mx); A_s[j][i2] = e; s += e; }
            float inv = 1.f / s;
            for (int i2 = 0; i2 < 84; ++i2) A_s[j][i2] *= inv;
        }
        __syncthreads();

        // phase C: acc[c][i] += v[c][j] * A[j][i], register-blocked 4c x 3i
        for (int j = 0; j < 84; ++j) {
            float vv[4];
            #pragma unroll
            for (int cc = 0; cc < 4; ++cc) vv[cc] = v_s[cq * 4 + cc][j];
            #pragma unroll
            for (int k2 = 0; k2 < 3; ++k2) {
                int i = ig + 32 * k2;
                float av = (i < 84) ? A_s[j][i] : 0.f;
                #pragma unroll
                for (int cc = 0; cc < 4; ++cc) acc[cc][k2] += vv[cc] * av;
            }
        }
    }

    #pragma unroll
    for (int cc = 0; cc < 4; ++cc)
        #pragma unroll
        for (int k2 = 0; k2 < 3; ++k2) {
            int i = ig + 32 * k2;
            if (i < 84) out_b[(size_t)(cq * 4 + cc) * HW_N + i] = acc[cc][k2];
        }
}

// ---------------- output projection + residual + ReLU ----------------
// obs_out(512x84 per (b,t)) = wo(512x128) * V(128x84); x_obs += relu(obs_out) in place
__global__ __launch_bounds__(256) void outproj_kernel(
    float* __restrict__ x, const float* __restrict__ wo, const float* __restrict__ ova)
{
    __shared__ float As[16][68];
    __shared__ float Bs[16][85];

    int bid = blockIdx.x;
    int b = bid >> 8; int rem = bid & 255; int t = rem >> 3; int mt = rem & 7;
    int o0 = mt * 64;

    const float* V = ova + ((size_t)b * OT_N + t) * FF_N * HW_N;
    const float* Wb = wo + (size_t)o0 * FF_N;

    const int tid = threadIdx.x;
    const int ty = tid >> 4, tx = tid & 15;

    float acc[4][6] = {};

    for (int k0 = 0; k0 < FF_N; k0 += 16) {
        #pragma unroll
        for (int it = 0; it < 4; ++it) {
            int l = tid + it * 256;
            int o = l >> 4, kk = l & 15;
            As[kk][o] = Wb[(size_t)o * FF_N + k0 + kk];
        }
        for (int l = tid; l < 1344; l += 256) {
            int kk = l / 84, i = l - kk * 84;
            Bs[kk][i] = V[(size_t)(k0 + kk) * HW_N + i];
        }
        __syncthreads();
        #pragma unroll
        for (int kk = 0; kk < 16; ++kk) {
            const float4 a4 = *reinterpret_cast<const float4*>(&As[kk][ty * 4]);
            const float ar[4] = {a4.x, a4.y, a4.z, a4.w};
            #pragma unroll
            for (int b2 = 0; b2 < 6; ++b2) {
                int i = tx + 16 * b2;
                float bv = (i < 84) ? Bs[kk][i] : 0.f;
                #pragma unroll
                for (int u = 0; u < 4; ++u) acc[u][b2] += ar[u] * bv;
            }
        }
        __syncthreads();
    }
    #pragma unroll
    for (int u = 0; u < 4; ++u) {
        int o = o0 + ty * 4 + u;
        size_t base = ((size_t)b * D_N + o) * THW_N + (size_t)(DT_N + t) * HW_N;
        #pragma unroll
        for (int b2 = 0; b2 < 6; ++b2) {
            int i = tx + 16 * b2;
            if (i < 84) {
                float val = acc[u][b2];
                x[base + i] = x[base + i] + (val > 0.f ? val : 0.f);
            }
        }
    }
}

// ---------------- BatchNorm ----------------
__global__ __launch_bounds__(256) void bn_stats_kernel(
    const float* __restrict__ x, float* __restrict__ stats)
{
    const int c = blockIdx.x;
    const int tid = threadIdx.x;
    float s = 0.f, ss = 0.f;
    for (int idx = tid; idx < B_N * THW_N; idx += 256) {
        int b = idx / THW_N, p = idx - b * THW_N;
        float v = x[((size_t)b * D_N + c) * THW_N + p];
        s += v; ss += v * v;
    }
    #pragma unroll
    for (int o = 32; o > 0; o >>= 1) { s += __shfl_down(s, o); ss += __shfl_down(ss, o); }
    __shared__ float red[8];
    int wave = tid >> 6;
    if ((tid & 63) == 0) { red[wave] = s; red[4 + wave] = ss; }
    __syncthreads();
    if (tid == 0) {
        float st = red[0] + red[1] + red[2] + red[3];
        float sst = red[4] + red[5] + red[6] + red[7];
        const float invN = 1.f / (float)(B_N * THW_N);
        float mean = st * invN;
        float var = sst * invN - mean * mean;
        stats[c] = mean;
        stats[512 + c] = rsqrtf(var + BN_EPS);
    }
}

__global__ __launch_bounds__(256) void bn_apply_kernel(
    float* __restrict__ x, const float* __restrict__ stats,
    const float* __restrict__ gamma, const float* __restrict__ beta)
{
    int idx = blockIdx.x * 256 + threadIdx.x;  // float4 index; 756 float4 per channel-row
    float4* x4 = (float4*)x;
    int c = (idx / 756) & 511;
    float mean = stats[c], rs = stats[512 + c];
    float g = gamma[c], bb = beta[c];
    float4 v = x4[idx];
    v.x = g * (v.x - mean) * rs + bb;
    v.y = g * (v.y - mean) * rs + bb;
    v.z = g * (v.z - mean) * rs + bb;
    v.w = g * (v.w - mean) * rs + bb;
    x4[idx] = v;
}

// ---------------- launch ----------------
extern "C" void kernel_launch(void* const* d_in, const int* in_sizes, int n_in,
                              void* d_out, int out_size, void* d_ws, size_t ws_size,
                              hipStream_t stream)
{
    const float* inp  = (const float*)d_in[0];
    const float* dwq  = (const float*)d_in[1];
    const float* dwk  = (const float*)d_in[2];
    const float* dwv  = (const float*)d_in[3];
    const float* dwo  = (const float*)d_in[4];
    const float* owq  = (const float*)d_in[5];
    const float* owk  = (const float*)d_in[6];
    const float* owv  = (const float*)d_in[7];
    const float* owo  = (const float*)d_in[8];
    const float* gam  = (const float*)d_in[9];
    const float* bet  = (const float*)d_in[10];
    float* x  = (float*)d_out;
    float* ws = (float*)d_ws;

    hipMemcpyAsync(x, inp, (size_t)B_N * D_N * THW_N * sizeof(float),
                   hipMemcpyDeviceToDevice, stream);

    for (int layer = 0; layer < 2; ++layer) {
        size_t woff = (size_t)layer * FF_N * D_N;   // 65536
        size_t coff = (size_t)layer * D_N;
        proj_kernel<<<2304, 256, 0, stream>>>(
            x, dwq + woff, dwk + woff, dwv + woff,
            owq + woff, owk + woff, owv + woff, ws);
        demo_attn_kernel<<<352, 256, 0, stream>>>(
            ws + WS_DQ, ws + WS_DK, ws + WS_DV, ws + WS_DVA);
        obs_attn_kernel<<<1024, 256, 0, stream>>>(
            ws + WS_DK, ws + WS_DVA, ws + WS_OQ, ws + WS_OK, ws + WS_OV, ws + WS_OVA);
        outproj_kernel<<<2048, 256, 0, stream>>>(x, dwo == nullptr ? owo : (owo + woff), ws + WS_OVA);
        bn_stats_kernel<<<512, 256, 0, stream>>>(x, ws + WS_STATS);
        bn_apply_kernel<<<12096, 256, 0, stream>>>(x, ws + WS_STATS, gam + coff, bet + coff);
    }
    (void)dwo; (void)in_sizes; (void)n_in; (void)out_size; (void)ws_size;
}

// Round 3
// 840.662 us; speedup vs baseline: 1.4208x; 1.4208x over previous
//
#include <hip/hip_runtime.h>

// ---------------- problem constants ----------------
#define B_N 8
#define D_N 512
#define T_N 36
#define HW_N 84
#define THW_N 3024
#define DT_N 4
#define OT_N 32
#define NH_N 4
#define FF_N 128
#define CH_N 32
#define DI_N 336      // demo tokens 4*84
#define OI_N 2688     // obs tokens 32*84
#define CAT_N 420
#define INV_TEMP 0.04419417382415922f   // 1/sqrt(512)
#define BN_EPS 1e-5f

// workspace float offsets
#define WS_DQ   ((size_t)0)
#define WS_DK   ((size_t)344064)
#define WS_DV   ((size_t)688128)
#define WS_DVA  ((size_t)1032192)
#define WS_OQ   ((size_t)1376256)
#define WS_OK   ((size_t)4128768)
#define WS_OV   ((size_t)6881280)
#define WS_OVA  ((size_t)9633792)
#define WS_STATS ((size_t)12386304)

typedef short bf16x8 __attribute__((ext_vector_type(8)));   // 8 bf16 in 4 VGPRs
typedef float f32x4 __attribute__((ext_vector_type(4)));

__device__ __forceinline__ short f2bf(float f) {
    unsigned u = __float_as_uint(f);
    u += 0x7fffu + ((u >> 16) & 1u);          // round-to-nearest-even
    return (short)(u >> 16);
}

// ---------------- fused QKV projection, bf16 MFMA ----------------
// Per block: Y[wt][128 o][48 cols] = W[wt](128x512) * X(512 x 48cols), wt in {q,k,v}
// X tile staged once per k-step, shared by all 3 weight GEMMs.
// grid = 8 b * 63 col-tiles (ct<7 -> demo outputs, else obs outputs)
// LDS A layout: [kc][m][8k] (kc = k-chunk of 8); MFMA A-frag read is As[(q*128+m)*8]
__global__ __launch_bounds__(256) void proj_mfma_kernel(
    const float* __restrict__ x,
    const float* __restrict__ dwq, const float* __restrict__ dwk, const float* __restrict__ dwv,
    const float* __restrict__ owq, const float* __restrict__ owk, const float* __restrict__ owv,
    float* __restrict__ ws)
{
    __shared__ short As[3][4096];   // [wt][(kc*128 + m)*8]
    __shared__ short Bs[1536];      // [(kc*48 + n)*8]

    const int bid = blockIdx.x;
    const int b = bid / 63, ct = bid - b * 63;
    const bool is_demo = (ct < 7);
    const float* W0 = is_demo ? dwq : owq;
    const float* W1 = is_demo ? dwk : owk;
    const float* W2 = is_demo ? dwv : owv;
    const int L = is_demo ? DI_N : OI_N;
    const int colL = is_demo ? ct * 48 : (ct - 7) * 48;
    float* Y0 = ws + (is_demo ? WS_DQ : WS_OQ);
    float* Y1 = ws + (is_demo ? WS_DK : WS_OK);
    float* Y2 = ws + (is_demo ? WS_DV : WS_OV);
    const float* Xb = x + (size_t)b * D_N * THW_N + ct * 48;

    const int tid = threadIdx.x;
    const int lane = tid & 63, wv = tid >> 6;
    const int l15 = lane & 15, q = lane >> 4;

    f32x4 acc[3][2][3] = {};

    for (int k0 = 0; k0 < D_N; k0 += 32) {
        __syncthreads();
        // stage A (3 weight tiles 128x32): global read kc=c&3 (coalesced),
        // LDS write transposed to [kc][m] so frag read As[(q*128+m)*8] is correct
        const float* Wt[3] = {W0, W1, W2};
        #pragma unroll
        for (int wt = 0; wt < 3; ++wt) {
            #pragma unroll
            for (int h = 0; h < 2; ++h) {
                int c = tid + h * 256;
                int kc = c & 3, m = c >> 2;
                const float* src = Wt[wt] + (size_t)m * D_N + k0 + kc * 8;
                float4 f0 = *reinterpret_cast<const float4*>(src);
                float4 f1 = *reinterpret_cast<const float4*>(src + 4);
                bf16x8 pk;
                pk[0] = f2bf(f0.x); pk[1] = f2bf(f0.y); pk[2] = f2bf(f0.z); pk[3] = f2bf(f0.w);
                pk[4] = f2bf(f1.x); pk[5] = f2bf(f1.y); pk[6] = f2bf(f1.z); pk[7] = f2bf(f1.w);
                *reinterpret_cast<bf16x8*>(&As[wt][(kc * 128 + m) * 8]) = pk;
            }
        }
        // stage B (X tile 32k x 48n, n-major within k-chunks)
        if (tid < 192) {
            int n = tid % 48, kc = tid / 48;
            bf16x8 pk;
            #pragma unroll
            for (int p = 0; p < 8; ++p)
                pk[p] = f2bf(Xb[(size_t)(k0 + kc * 8 + p) * THW_N + n]);
            *reinterpret_cast<bf16x8*>(&Bs[(kc * 48 + n) * 8]) = pk;
        }
        __syncthreads();

        bf16x8 bfr[3];
        #pragma unroll
        for (int nt = 0; nt < 3; ++nt)
            bfr[nt] = *reinterpret_cast<const bf16x8*>(&Bs[(q * 48 + nt * 16 + l15) * 8]);
        #pragma unroll
        for (int wt = 0; wt < 3; ++wt) {
            #pragma unroll
            for (int mt2 = 0; mt2 < 2; ++mt2) {
                bf16x8 afr = *reinterpret_cast<const bf16x8*>(
                    &As[wt][(q * 128 + wv * 32 + mt2 * 16 + l15) * 8]);
                #pragma unroll
                for (int nt = 0; nt < 3; ++nt)
                    acc[wt][mt2][nt] = __builtin_amdgcn_mfma_f32_16x16x32_bf16(
                        afr, bfr[nt], acc[wt][mt2][nt], 0, 0, 0);
            }
        }
    }

    // epilogue: D row = q*4+r, col = l15
    float* Yt[3] = {Y0, Y1, Y2};
    #pragma unroll
    for (int wt = 0; wt < 3; ++wt) {
        float* Yb = Yt[wt] + (size_t)b * FF_N * L + colL;
        #pragma unroll
        for (int mt2 = 0; mt2 < 2; ++mt2) {
            int mrow = wv * 32 + mt2 * 16 + q * 4;
            #pragma unroll
            for (int nt = 0; nt < 3; ++nt) {
                int col = nt * 16 + l15;
                #pragma unroll
                for (int r = 0; r < 4; ++r)
                    Yb[(size_t)(mrow + r) * L + col] = acc[wt][mt2][nt][r];
            }
        }
    }
}

// ---------------- demo attention (fp32) ----------------
__global__ __launch_bounds__(256) void demo_attn_kernel(
    const float* __restrict__ dq, const float* __restrict__ dk,
    const float* __restrict__ dv, float* __restrict__ dva)
{
    __shared__ float k_s[32][33];
    __shared__ float q_s[32][85];
    __shared__ float v_s[32][85];

    int bid = blockIdx.x;
    int b = bid / 44; int rem = bid - b * 44; int n = rem / 11; int rt = rem - n * 11;
    int r0 = rt * 32;

    const float* dq_b = dq + ((size_t)b * FF_N + n * CH_N) * DI_N;
    const float* dk_b = dk + ((size_t)b * FF_N + n * CH_N) * DI_N;
    const float* dv_b = dv + ((size_t)b * FF_N + n * CH_N) * DI_N;
    float* dva_b = dva + ((size_t)b * FF_N + n * CH_N) * DI_N;

    const int tid = threadIdx.x;

    #pragma unroll
    for (int it = 0; it < 4; ++it) {
        int l = tid + it * 256;
        int c = l >> 5, il = l & 31;
        int i = r0 + il;
        k_s[c][il] = (i < DI_N) ? dk_b[(size_t)c * DI_N + i] : 0.f;
    }
    __syncthreads();

    const int row = tid >> 3, jl = tid & 7;
    const int i = r0 + row;
    const bool valid = (i < DI_N);
    const int jmax = valid ? ((i / HW_N) + 1) * HW_N : 0;

    float kr[32];
    #pragma unroll
    for (int c = 0; c < 32; ++c) kr[c] = k_s[c][row];

    float m = -3.4e38f, lsum = 0.f;
    float acc[32];
    #pragma unroll
    for (int c = 0; c < 32; ++c) acc[c] = 0.f;

    int last_i = (r0 + 31 < DI_N) ? (r0 + 31) : (DI_N - 1);
    int last = ((last_i / HW_N) + 1) * HW_N;

    for (int jc = 0; jc < last; jc += 84) {
        __syncthreads();
        for (int l = tid; l < 2688; l += 256) {
            int c = l / 84, j = l - c * 84;
            q_s[c][j] = dq_b[(size_t)c * DI_N + jc + j];
            v_s[c][j] = dv_b[(size_t)c * DI_N + jc + j];
        }
        __syncthreads();
        if (valid) {
            for (int j = jl; j < 84; j += 8) {
                int jg = jc + j;
                if (jg >= jmax) break;
                float s = 0.f;
                #pragma unroll
                for (int c = 0; c < 32; ++c) s += kr[c] * q_s[c][j];
                s *= INV_TEMP;
                if (s <= m) {
                    float e = __expf(s - m);
                    lsum += e;
                    #pragma unroll
                    for (int c = 0; c < 32; ++c) acc[c] += e * v_s[c][j];
                } else {
                    float al = __expf(m - s);
                    lsum = lsum * al + 1.f;
                    #pragma unroll
                    for (int c = 0; c < 32; ++c) acc[c] = acc[c] * al + v_s[c][j];
                    m = s;
                }
            }
        }
    }
    #pragma unroll
    for (int o = 1; o < 8; o <<= 1) {
        float mo = __shfl_xor(m, o);
        float lo = __shfl_xor(lsum, o);
        float mn = fmaxf(m, mo);
        float sa = __expf(m - mn);
        float sb = __expf(mo - mn);
        lsum = lsum * sa + lo * sb;
        #pragma unroll
        for (int c = 0; c < 32; ++c) {
            float ao = __shfl_xor(acc[c], o);
            acc[c] = acc[c] * sa + ao * sb;
        }
        m = mn;
    }
    if (valid) {
        float inv = 1.f / lsum;
        #pragma unroll
        for (int cc = 0; cc < 4; ++cc) {
            int c = jl * 4 + cc;
            dva_b[(size_t)c * DI_N + i] = acc[c] * inv;
        }
    }
}

// ---------------- obs attention (fp32) ----------------
__global__ __launch_bounds__(256) void obs_attn_kernel(
    const float* __restrict__ dk, const float* __restrict__ dva,
    const float* __restrict__ oq, const float* __restrict__ okp, const float* __restrict__ ovp,
    float* __restrict__ ova)
{
    __shared__ float q_s[32][85];
    __shared__ float k_s[32][85];
    __shared__ float v_s[32][85];
    __shared__ float A_s[84][85];

    int bid = blockIdx.x;
    int b = bid >> 7; int rem = bid & 127; int t = rem >> 2; int n = rem & 3;

    const float* oq_b = oq + ((size_t)b * FF_N + n * CH_N) * OI_N + t * HW_N;
    const float* ok_b = okp + ((size_t)b * FF_N + n * CH_N) * OI_N + t * HW_N;
    const float* ov_b = ovp + ((size_t)b * FF_N + n * CH_N) * OI_N + t * HW_N;
    const float* dk_b = dk + ((size_t)b * FF_N + n * CH_N) * DI_N;
    const float* dva_b = dva + ((size_t)b * FF_N + n * CH_N) * DI_N;
    float* out_b = ova + (((size_t)b * OT_N + t) * FF_N + n * CH_N) * HW_N;

    const int tid = threadIdx.x;

    for (int l = tid; l < 2688; l += 256) {
        int c = l / 84, i = l - c * 84;
        q_s[c][i] = oq_b[(size_t)c * OI_N + i];
    }

    const int cq = tid >> 5, ig = tid & 31;
    float acc[4][3] = {};

    for (int jc = 0; jc < CAT_N; jc += 84) {
        __syncthreads();
        if (jc < DI_N) {
            for (int l = tid; l < 2688; l += 256) {
                int c = l / 84, j = l - c * 84;
                k_s[c][j] = dk_b[(size_t)c * DI_N + jc + j];
                v_s[c][j] = dva_b[(size_t)c * DI_N + jc + j];
            }
        } else {
            for (int l = tid; l < 2688; l += 256) {
                int c = l / 84, j = l - c * 84;
                k_s[c][j] = ok_b[(size_t)c * OI_N + j];
                v_s[c][j] = ov_b[(size_t)c * OI_N + j];
            }
        }
        __syncthreads();

        for (int tile = tid; tile < 441; tile += 256) {
            int tj = tile / 21, ti = tile - tj * 21;
            int j0 = tj * 4, i0 = ti * 4;
            float sacc[4][4] = {};
            #pragma unroll
            for (int c = 0; c < 32; ++c) {
                float kv[4], qv[4];
                #pragma unroll
                for (int u = 0; u < 4; ++u) { kv[u] = k_s[c][j0 + u]; qv[u] = q_s[c][i0 + u]; }
                #pragma unroll
                for (int u = 0; u < 4; ++u)
                    #pragma unroll
                    for (int w = 0; w < 4; ++w)
                        sacc[u][w] += kv[u] * qv[w];
            }
            #pragma unroll
            for (int u = 0; u < 4; ++u)
                #pragma unroll
                for (int w = 0; w < 4; ++w)
                    A_s[j0 + u][i0 + w] = sacc[u][w] * INV_TEMP;
        }
        __syncthreads();

        if (tid < 84) {
            int j = tid;
            float mx = -3.4e38f;
            for (int i2 = 0; i2 < 84; ++i2) mx = fmaxf(mx, A_s[j][i2]);
            float s = 0.f;
            for (int i2 = 0; i2 < 84; ++i2) { float e = __expf(A_s[j][i2] - mx); A_s[j][i2] = e; s += e; }
            float inv = 1.f / s;
            for (int i2 = 0; i2 < 84; ++i2) A_s[j][i2] *= inv;
        }
        __syncthreads();

        for (int j = 0; j < 84; ++j) {
            float vv[4];
            #pragma unroll
            for (int cc = 0; cc < 4; ++cc) vv[cc] = v_s[cq * 4 + cc][j];
            #pragma unroll
            for (int k2 = 0; k2 < 3; ++k2) {
                int i = ig + 32 * k2;
                float av = (i < 84) ? A_s[j][i] : 0.f;
                #pragma unroll
                for (int cc = 0; cc < 4; ++cc) acc[cc][k2] += vv[cc] * av;
            }
        }
    }

    #pragma unroll
    for (int cc = 0; cc < 4; ++cc)
        #pragma unroll
        for (int k2 = 0; k2 < 3; ++k2) {
            int i = ig + 32 * k2;
            if (i < 84) out_b[(size_t)(cq * 4 + cc) * HW_N + i] = acc[cc][k2];
        }
}

// ---------------- output projection, bf16 MFMA + ReLU + residual ----------------
// Per block: C[128 o][96 i(84 valid)] = wo_tile(128x128) * V(128x84), one (b,t)
// LDS A layout: [kc][m][8k], matching frag read As[(q*128+m)*8]
__global__ __launch_bounds__(256) void outproj_mfma_kernel(
    float* __restrict__ x, const float* __restrict__ wo, const float* __restrict__ ova)
{
    __shared__ short As[4096];  // [(kc*128 + m)*8]
    __shared__ short Bs[3072];  // [(kc*96 + n)*8]

    const int bid = blockIdx.x;
    const int b = bid >> 7, rem = bid & 127, t = rem >> 2, mt = rem & 3;
    const int o0 = mt * 128;
    const float* V = ova + ((size_t)b * OT_N + t) * (FF_N * HW_N);
    const float* Wb = wo + (size_t)o0 * FF_N;

    const int tid = threadIdx.x;
    const int lane = tid & 63, wv = tid >> 6;
    const int l15 = lane & 15, q = lane >> 4;

    f32x4 acc[2][6] = {};

    for (int k0 = 0; k0 < FF_N; k0 += 32) {
        __syncthreads();
        #pragma unroll
        for (int h = 0; h < 2; ++h) {
            int c = tid + h * 256;
            int kc = c & 3, m = c >> 2;
            const float* src = Wb + (size_t)m * FF_N + k0 + kc * 8;
            float4 f0 = *reinterpret_cast<const float4*>(src);
            float4 f1 = *reinterpret_cast<const float4*>(src + 4);
            bf16x8 pk;
            pk[0] = f2bf(f0.x); pk[1] = f2bf(f0.y); pk[2] = f2bf(f0.z); pk[3] = f2bf(f0.w);
            pk[4] = f2bf(f1.x); pk[5] = f2bf(f1.y); pk[6] = f2bf(f1.z); pk[7] = f2bf(f1.w);
            *reinterpret_cast<bf16x8*>(&As[(kc * 128 + m) * 8]) = pk;
        }
        for (int c = tid; c < 384; c += 256) {
            int n = c % 96, kc = c / 96;
            bf16x8 pk;
            #pragma unroll
            for (int p = 0; p < 8; ++p)
                pk[p] = (n < HW_N) ? f2bf(V[(size_t)(k0 + kc * 8 + p) * HW_N + n]) : (short)0;
            *reinterpret_cast<bf16x8*>(&Bs[(kc * 96 + n) * 8]) = pk;
        }
        __syncthreads();

        bf16x8 af[2];
        #pragma unroll
        for (int mt2 = 0; mt2 < 2; ++mt2)
            af[mt2] = *reinterpret_cast<const bf16x8*>(
                &As[(q * 128 + wv * 32 + mt2 * 16 + l15) * 8]);
        #pragma unroll
        for (int nt = 0; nt < 6; ++nt) {
            bf16x8 bf = *reinterpret_cast<const bf16x8*>(&Bs[(q * 96 + nt * 16 + l15) * 8]);
            #pragma unroll
            for (int mt2 = 0; mt2 < 2; ++mt2)
                acc[mt2][nt] = __builtin_amdgcn_mfma_f32_16x16x32_bf16(
                    af[mt2], bf, acc[mt2][nt], 0, 0, 0);
        }
    }

    #pragma unroll
    for (int mt2 = 0; mt2 < 2; ++mt2) {
        #pragma unroll
        for (int nt = 0; nt < 6; ++nt) {
            int i = nt * 16 + l15;
            if (i < HW_N) {
                #pragma unroll
                for (int r = 0; r < 4; ++r) {
                    int o = o0 + wv * 32 + mt2 * 16 + q * 4 + r;
                    size_t addr = ((size_t)b * D_N + o) * THW_N + (size_t)(DT_N + t) * HW_N + i;
                    float val = acc[mt2][nt][r];
                    x[addr] += (val > 0.f ? val : 0.f);
                }
            }
        }
    }
}

// ---------------- BatchNorm ----------------
__global__ __launch_bounds__(256) void bn_stats_kernel(
    const float* __restrict__ x, float* __restrict__ stats)
{
    const int c = blockIdx.x;
    const int tid = threadIdx.x;
    float s = 0.f, ss = 0.f;
    for (int idx = tid; idx < B_N * THW_N; idx += 256) {
        int b = idx / THW_N, p = idx - b * THW_N;
        float v = x[((size_t)b * D_N + c) * THW_N + p];
        s += v; ss += v * v;
    }
    #pragma unroll
    for (int o = 32; o > 0; o >>= 1) { s += __shfl_down(s, o); ss += __shfl_down(ss, o); }
    __shared__ float red[8];
    int wave = tid >> 6;
    if ((tid & 63) == 0) { red[wave] = s; red[4 + wave] = ss; }
    __syncthreads();
    if (tid == 0) {
        float st = red[0] + red[1] + red[2] + red[3];
        float sst = red[4] + red[5] + red[6] + red[7];
        const float invN = 1.f / (float)(B_N * THW_N);
        float mean = st * invN;
        float var = sst * invN - mean * mean;
        stats[c] = mean;
        stats[512 + c] = rsqrtf(var + BN_EPS);
    }
}

__global__ __launch_bounds__(256) void bn_apply_kernel(
    float* __restrict__ x, const float* __restrict__ stats,
    const float* __restrict__ gamma, const float* __restrict__ beta)
{
    int idx = blockIdx.x * 256 + threadIdx.x;
    float4* x4 = (float4*)x;
    int c = (idx / 756) & 511;
    float mean = stats[c], rs = stats[512 + c];
    float g = gamma[c], bb = beta[c];
    float4 v = x4[idx];
    v.x = g * (v.x - mean) * rs + bb;
    v.y = g * (v.y - mean) * rs + bb;
    v.z = g * (v.z - mean) * rs + bb;
    v.w = g * (v.w - mean) * rs + bb;
    x4[idx] = v;
}

// ---------------- launch ----------------
extern "C" void kernel_launch(void* const* d_in, const int* in_sizes, int n_in,
                              void* d_out, int out_size, void* d_ws, size_t ws_size,
                              hipStream_t stream)
{
    const float* inp  = (const float*)d_in[0];
    const float* dwq  = (const float*)d_in[1];
    const float* dwk  = (const float*)d_in[2];
    const float* dwv  = (const float*)d_in[3];
    const float* owq  = (const float*)d_in[5];
    const float* owk  = (const float*)d_in[6];
    const float* owv  = (const float*)d_in[7];
    const float* owo  = (const float*)d_in[8];
    const float* gam  = (const float*)d_in[9];
    const float* bet  = (const float*)d_in[10];
    float* x  = (float*)d_out;
    float* ws = (float*)d_ws;

    hipMemcpyAsync(x, inp, (size_t)B_N * D_N * THW_N * sizeof(float),
                   hipMemcpyDeviceToDevice, stream);

    for (int layer = 0; layer < 2; ++layer) {
        size_t woff = (size_t)layer * FF_N * D_N;   // 65536
        size_t coff = (size_t)layer * D_N;
        proj_mfma_kernel<<<504, 256, 0, stream>>>(
            x, dwq + woff, dwk + woff, dwv + woff,
            owq + woff, owk + woff, owv + woff, ws);
        demo_attn_kernel<<<352, 256, 0, stream>>>(
            ws + WS_DQ, ws + WS_DK, ws + WS_DV, ws + WS_DVA);
        obs_attn_kernel<<<1024, 256, 0, stream>>>(
            ws + WS_DK, ws + WS_DVA, ws + WS_OQ, ws + WS_OK, ws + WS_OV, ws + WS_OVA);
        outproj_mfma_kernel<<<1024, 256, 0, stream>>>(x, owo + woff, ws + WS_OVA);
        bn_stats_kernel<<<512, 256, 0, stream>>>(x, ws + WS_STATS);
        bn_apply_kernel<<<12096, 256, 0, stream>>>(x, ws + WS_STATS, gam + coff, bet + coff);
    }
    (void)in_sizes; (void)n_in; (void)out_size; (void)ws_size;
}

// Round 4
// 580.723 us; speedup vs baseline: 2.0567x; 1.4476x over previous
//
#include <hip/hip_runtime.h>

// ---------------- problem constants ----------------
#define B_N 8
#define D_N 512
#define T_N 36
#define HW_N 84
#define THW_N 3024
#define DT_N 4
#define OT_N 32
#define NH_N 4
#define FF_N 128
#define CH_N 32
#define DI_N 336      // demo tokens 4*84
#define OI_N 2688     // obs tokens 32*84
#define CAT_N 420
#define INV_TEMP 0.04419417382415922f   // 1/sqrt(512)
#define BN_EPS 1e-5f

// workspace float offsets
#define WS_DQ   ((size_t)0)
#define WS_DK   ((size_t)344064)
#define WS_DV   ((size_t)688128)
#define WS_DVA  ((size_t)1032192)
#define WS_OQ   ((size_t)1376256)
#define WS_OK   ((size_t)4128768)
#define WS_OV   ((size_t)6881280)
#define WS_OVA  ((size_t)9633792)
#define WS_STATS ((size_t)12386304)

typedef short bf16x8 __attribute__((ext_vector_type(8)));   // 8 bf16 in 4 VGPRs
typedef float f32x4 __attribute__((ext_vector_type(4)));

__device__ __forceinline__ short f2bf(float f) {
    unsigned u = __float_as_uint(f);
    u += 0x7fffu + ((u >> 16) & 1u);          // round-to-nearest-even
    return (short)(u >> 16);
}

// ---------------- fused QKV projection, bf16 MFMA ----------------
__global__ __launch_bounds__(256) void proj_mfma_kernel(
    const float* __restrict__ x,
    const float* __restrict__ dwq, const float* __restrict__ dwk, const float* __restrict__ dwv,
    const float* __restrict__ owq, const float* __restrict__ owk, const float* __restrict__ owv,
    float* __restrict__ ws)
{
    __shared__ short As[3][4096];   // [wt][(kc*128 + m)*8]
    __shared__ short Bs[1536];      // [(kc*48 + n)*8]

    const int bid = blockIdx.x;
    const int b = bid / 63, ct = bid - b * 63;
    const bool is_demo = (ct < 7);
    const float* W0 = is_demo ? dwq : owq;
    const float* W1 = is_demo ? dwk : owk;
    const float* W2 = is_demo ? dwv : owv;
    const int L = is_demo ? DI_N : OI_N;
    const int colL = is_demo ? ct * 48 : (ct - 7) * 48;
    float* Y0 = ws + (is_demo ? WS_DQ : WS_OQ);
    float* Y1 = ws + (is_demo ? WS_DK : WS_OK);
    float* Y2 = ws + (is_demo ? WS_DV : WS_OV);
    const float* Xb = x + (size_t)b * D_N * THW_N + ct * 48;

    const int tid = threadIdx.x;
    const int lane = tid & 63, wv = tid >> 6;
    const int l15 = lane & 15, q = lane >> 4;

    f32x4 acc[3][2][3] = {};

    for (int k0 = 0; k0 < D_N; k0 += 32) {
        __syncthreads();
        const float* Wt[3] = {W0, W1, W2};
        #pragma unroll
        for (int wt = 0; wt < 3; ++wt) {
            #pragma unroll
            for (int h = 0; h < 2; ++h) {
                int c = tid + h * 256;
                int kc = c & 3, m = c >> 2;
                const float* src = Wt[wt] + (size_t)m * D_N + k0 + kc * 8;
                float4 f0 = *reinterpret_cast<const float4*>(src);
                float4 f1 = *reinterpret_cast<const float4*>(src + 4);
                bf16x8 pk;
                pk[0] = f2bf(f0.x); pk[1] = f2bf(f0.y); pk[2] = f2bf(f0.z); pk[3] = f2bf(f0.w);
                pk[4] = f2bf(f1.x); pk[5] = f2bf(f1.y); pk[6] = f2bf(f1.z); pk[7] = f2bf(f1.w);
                *reinterpret_cast<bf16x8*>(&As[wt][(kc * 128 + m) * 8]) = pk;
            }
        }
        if (tid < 192) {
            int n = tid % 48, kc = tid / 48;
            bf16x8 pk;
            #pragma unroll
            for (int p = 0; p < 8; ++p)
                pk[p] = f2bf(Xb[(size_t)(k0 + kc * 8 + p) * THW_N + n]);
            *reinterpret_cast<bf16x8*>(&Bs[(kc * 48 + n) * 8]) = pk;
        }
        __syncthreads();

        bf16x8 bfr[3];
        #pragma unroll
        for (int nt = 0; nt < 3; ++nt)
            bfr[nt] = *reinterpret_cast<const bf16x8*>(&Bs[(q * 48 + nt * 16 + l15) * 8]);
        #pragma unroll
        for (int wt = 0; wt < 3; ++wt) {
            #pragma unroll
            for (int mt2 = 0; mt2 < 2; ++mt2) {
                bf16x8 afr = *reinterpret_cast<const bf16x8*>(
                    &As[wt][(q * 128 + wv * 32 + mt2 * 16 + l15) * 8]);
                #pragma unroll
                for (int nt = 0; nt < 3; ++nt)
                    acc[wt][mt2][nt] = __builtin_amdgcn_mfma_f32_16x16x32_bf16(
                        afr, bfr[nt], acc[wt][mt2][nt], 0, 0, 0);
            }
        }
    }

    float* Yt[3] = {Y0, Y1, Y2};
    #pragma unroll
    for (int wt = 0; wt < 3; ++wt) {
        float* Yb = Yt[wt] + (size_t)b * FF_N * L + colL;
        #pragma unroll
        for (int mt2 = 0; mt2 < 2; ++mt2) {
            int mrow = wv * 32 + mt2 * 16 + q * 4;
            #pragma unroll
            for (int nt = 0; nt < 3; ++nt) {
                int col = nt * 16 + l15;
                #pragma unroll
                for (int r = 0; r < 4; ++r)
                    Yb[(size_t)(mrow + r) * L + col] = acc[wt][mt2][nt][r];
            }
        }
    }
}

// ---------------- demo attention (fp32) ----------------
__global__ __launch_bounds__(256) void demo_attn_kernel(
    const float* __restrict__ dq, const float* __restrict__ dk,
    const float* __restrict__ dv, float* __restrict__ dva)
{
    __shared__ float k_s[32][33];
    __shared__ float q_s[32][85];
    __shared__ float v_s[32][85];

    int bid = blockIdx.x;
    int b = bid / 44; int rem = bid - b * 44; int n = rem / 11; int rt = rem - n * 11;
    int r0 = rt * 32;

    const float* dq_b = dq + ((size_t)b * FF_N + n * CH_N) * DI_N;
    const float* dk_b = dk + ((size_t)b * FF_N + n * CH_N) * DI_N;
    const float* dv_b = dv + ((size_t)b * FF_N + n * CH_N) * DI_N;
    float* dva_b = dva + ((size_t)b * FF_N + n * CH_N) * DI_N;

    const int tid = threadIdx.x;

    #pragma unroll
    for (int it = 0; it < 4; ++it) {
        int l = tid + it * 256;
        int c = l >> 5, il = l & 31;
        int i = r0 + il;
        k_s[c][il] = (i < DI_N) ? dk_b[(size_t)c * DI_N + i] : 0.f;
    }
    __syncthreads();

    const int row = tid >> 3, jl = tid & 7;
    const int i = r0 + row;
    const bool valid = (i < DI_N);
    const int jmax = valid ? ((i / HW_N) + 1) * HW_N : 0;

    float kr[32];
    #pragma unroll
    for (int c = 0; c < 32; ++c) kr[c] = k_s[c][row];

    float m = -3.4e38f, lsum = 0.f;
    float acc[32];
    #pragma unroll
    for (int c = 0; c < 32; ++c) acc[c] = 0.f;

    int last_i = (r0 + 31 < DI_N) ? (r0 + 31) : (DI_N - 1);
    int last = ((last_i / HW_N) + 1) * HW_N;

    for (int jc = 0; jc < last; jc += 84) {
        __syncthreads();
        for (int l = tid; l < 2688; l += 256) {
            int c = l / 84, j = l - c * 84;
            q_s[c][j] = dq_b[(size_t)c * DI_N + jc + j];
            v_s[c][j] = dv_b[(size_t)c * DI_N + jc + j];
        }
        __syncthreads();
        if (valid) {
            for (int j = jl; j < 84; j += 8) {
                int jg = jc + j;
                if (jg >= jmax) break;
                float s = 0.f;
                #pragma unroll
                for (int c = 0; c < 32; ++c) s += kr[c] * q_s[c][j];
                s *= INV_TEMP;
                if (s <= m) {
                    float e = __expf(s - m);
                    lsum += e;
                    #pragma unroll
                    for (int c = 0; c < 32; ++c) acc[c] += e * v_s[c][j];
                } else {
                    float al = __expf(m - s);
                    lsum = lsum * al + 1.f;
                    #pragma unroll
                    for (int c = 0; c < 32; ++c) acc[c] = acc[c] * al + v_s[c][j];
                    m = s;
                }
            }
        }
    }
    #pragma unroll
    for (int o = 1; o < 8; o <<= 1) {
        float mo = __shfl_xor(m, o);
        float lo = __shfl_xor(lsum, o);
        float mn = fmaxf(m, mo);
        float sa = __expf(m - mn);
        float sb = __expf(mo - mn);
        lsum = lsum * sa + lo * sb;
        #pragma unroll
        for (int c = 0; c < 32; ++c) {
            float ao = __shfl_xor(acc[c], o);
            acc[c] = acc[c] * sa + ao * sb;
        }
        m = mn;
    }
    if (valid) {
        float inv = 1.f / lsum;
        #pragma unroll
        for (int cc = 0; cc < 4; ++cc) {
            int c = jl * 4 + cc;
            dva_b[(size_t)c * DI_N + i] = acc[c] * inv;
        }
    }
}

// ---------------- obs attention, bf16 MFMA ----------------
// Per block: one (b,t,n). cat j (420, pad 448) in 7 chunks of 64.
// Per chunk: S = Kt*Qt (MFMA, m=j, n=i, k=c=32); row-softmax over i (complete
// per chunk since softmax axis is i); P -> LDS transposed [i][j]; PV accumulate
// out[c][i] += V[c][j] P[j][i] (MFMA, m=c, n=i, k=j).
__global__ __launch_bounds__(256, 4) void obs_attn_mfma_kernel(
    const float* __restrict__ dk, const float* __restrict__ dva,
    const float* __restrict__ oq, const float* __restrict__ okp, const float* __restrict__ ovp,
    float* __restrict__ ova)
{
    __shared__ short Qt[96 * 40];   // [i][c], pad 40, INV_TEMP folded, rows>=84 zero
    __shared__ short Kt[64 * 40];   // [j_local][c], pad 40, zero past 420
    __shared__ short Vs[32 * 72];   // [c][j_local], pad 72, zero past 420
    __shared__ short Pt[96 * 72];   // [i][j_local], pad 72

    const int bid = blockIdx.x;
    const int b = bid >> 7, rem = bid & 127, t = rem >> 2, n = rem & 3;

    const float* oq_b = oq + ((size_t)b * FF_N + n * CH_N) * OI_N + t * HW_N;
    const float* ok_b = okp + ((size_t)b * FF_N + n * CH_N) * OI_N + t * HW_N;
    const float* ov_b = ovp + ((size_t)b * FF_N + n * CH_N) * OI_N + t * HW_N;
    const float* dk_b = dk + ((size_t)b * FF_N + n * CH_N) * DI_N;
    const float* dva_b = dva + ((size_t)b * FF_N + n * CH_N) * DI_N;
    float* out_b = ova + (((size_t)b * OT_N + t) * FF_N + n * CH_N) * HW_N;

    const int tid = threadIdx.x;
    const int lane = tid & 63, wv = tid >> 6;
    const int l15 = lane & 15, q = lane >> 4;

    // stage Qt (once)
    for (int l = tid; l < 384; l += 256) {
        int i = l >> 2, c0 = (l & 3) * 8;
        bf16x8 pk;
        #pragma unroll
        for (int p = 0; p < 8; ++p) {
            float v = (i < HW_N) ? oq_b[(size_t)(c0 + p) * OI_N + i] * INV_TEMP : 0.f;
            pk[p] = f2bf(v);
        }
        *reinterpret_cast<bf16x8*>(&Qt[i * 40 + c0]) = pk;
    }

    const int pv_mt = wv & 1;        // c-tile (0..1)
    const int pv_nb = wv >> 1;       // n-tiles pv_nb, pv_nb+2, pv_nb+4
    f32x4 oacc[3] = {};

    for (int jc = 0; jc < 448; jc += 64) {
        __syncthreads();   // prev PV done; Qt ready on first pass
        // stage Kt[64][40]
        {
            int jl = tid >> 2, c0 = (tid & 3) * 8;
            int jg = jc + jl;
            bf16x8 pk;
            #pragma unroll
            for (int p = 0; p < 8; ++p) {
                int c = c0 + p;
                float v = 0.f;
                if (jg < DI_N) v = dk_b[(size_t)c * DI_N + jg];
                else if (jg < CAT_N) v = ok_b[(size_t)c * OI_N + (jg - DI_N)];
                pk[p] = f2bf(v);
            }
            *reinterpret_cast<bf16x8*>(&Kt[jl * 40 + c0]) = pk;
        }
        // stage Vs[32][72]
        {
            int c = tid >> 3, j0 = (tid & 7) * 8;
            bf16x8 pk;
            #pragma unroll
            for (int p = 0; p < 8; ++p) {
                int jg = jc + j0 + p;
                float v = 0.f;
                if (jg < DI_N) v = dva_b[(size_t)c * DI_N + jg];
                else if (jg < CAT_N) v = ov_b[(size_t)c * OI_N + (jg - DI_N)];
                pk[p] = f2bf(v);
            }
            *reinterpret_cast<bf16x8*>(&Vs[c * 72 + j0]) = pk;
        }
        __syncthreads();

        // QK: wave wv -> m-tile wv (16 j-rows), 6 n-tiles of i
        f32x4 s[6];
        bf16x8 afr = *reinterpret_cast<const bf16x8*>(&Kt[(wv * 16 + l15) * 40 + q * 8]);
        #pragma unroll
        for (int nt = 0; nt < 6; ++nt) {
            bf16x8 bfr = *reinterpret_cast<const bf16x8*>(&Qt[(nt * 16 + l15) * 40 + q * 8]);
            f32x4 z = {};
            s[nt] = __builtin_amdgcn_mfma_f32_16x16x32_bf16(afr, bfr, z, 0, 0, 0);
        }
        // softmax over i per row (row j = q*4+r), reduce across l15
        float inv[4];
        #pragma unroll
        for (int r = 0; r < 4; ++r) {
            if (l15 >= 4) s[5][r] = -3.0e38f;     // mask i>=84
            float m2 = s[0][r];
            #pragma unroll
            for (int nt2 = 1; nt2 < 6; ++nt2) m2 = fmaxf(m2, s[nt2][r]);
            #pragma unroll
            for (int o = 1; o < 16; o <<= 1) m2 = fmaxf(m2, __shfl_xor(m2, o));
            float sm = 0.f;
            #pragma unroll
            for (int nt2 = 0; nt2 < 6; ++nt2) { float e = __expf(s[nt2][r] - m2); s[nt2][r] = e; sm += e; }
            #pragma unroll
            for (int o = 1; o < 16; o <<= 1) sm += __shfl_xor(sm, o);
            inv[r] = 1.f / sm;
        }
        // write Pt[i][j_local]
        #pragma unroll
        for (int nt = 0; nt < 6; ++nt) {
            short4 pk4;
            pk4.x = f2bf(s[nt][0] * inv[0]);
            pk4.y = f2bf(s[nt][1] * inv[1]);
            pk4.z = f2bf(s[nt][2] * inv[2]);
            pk4.w = f2bf(s[nt][3] * inv[3]);
            *reinterpret_cast<short4*>(&Pt[(nt * 16 + l15) * 72 + wv * 16 + q * 4]) = pk4;
        }
        __syncthreads();

        // PV accumulate
        #pragma unroll
        for (int kk = 0; kk < 2; ++kk) {
            bf16x8 va = *reinterpret_cast<const bf16x8*>(&Vs[(pv_mt * 16 + l15) * 72 + kk * 32 + q * 8]);
            #pragma unroll
            for (int u = 0; u < 3; ++u) {
                int nt = pv_nb + u * 2;
                bf16x8 pb = *reinterpret_cast<const bf16x8*>(&Pt[(nt * 16 + l15) * 72 + kk * 32 + q * 8]);
                oacc[u] = __builtin_amdgcn_mfma_f32_16x16x32_bf16(va, pb, oacc[u], 0, 0, 0);
            }
        }
    }

    // epilogue: c = pv_mt*16 + q*4 + r, i = nt*16 + l15
    #pragma unroll
    for (int u = 0; u < 3; ++u) {
        int i = (pv_nb + u * 2) * 16 + l15;
        if (i < HW_N) {
            #pragma unroll
            for (int r = 0; r < 4; ++r)
                out_b[(size_t)(pv_mt * 16 + q * 4 + r) * HW_N + i] = oacc[u][r];
        }
    }
}

// ---------------- output projection, bf16 MFMA + ReLU + residual ----------------
__global__ __launch_bounds__(256) void outproj_mfma_kernel(
    float* __restrict__ x, const float* __restrict__ wo, const float* __restrict__ ova)
{
    __shared__ short As[4096];  // [(kc*128 + m)*8]
    __shared__ short Bs[3072];  // [(kc*96 + n)*8]

    const int bid = blockIdx.x;
    const int b = bid >> 7, rem = bid & 127, t = rem >> 2, mt = rem & 3;
    const int o0 = mt * 128;
    const float* V = ova + ((size_t)b * OT_N + t) * (FF_N * HW_N);
    const float* Wb = wo + (size_t)o0 * FF_N;

    const int tid = threadIdx.x;
    const int lane = tid & 63, wv = tid >> 6;
    const int l15 = lane & 15, q = lane >> 4;

    f32x4 acc[2][6] = {};

    for (int k0 = 0; k0 < FF_N; k0 += 32) {
        __syncthreads();
        #pragma unroll
        for (int h = 0; h < 2; ++h) {
            int c = tid + h * 256;
            int kc = c & 3, m = c >> 2;
            const float* src = Wb + (size_t)m * FF_N + k0 + kc * 8;
            float4 f0 = *reinterpret_cast<const float4*>(src);
            float4 f1 = *reinterpret_cast<const float4*>(src + 4);
            bf16x8 pk;
            pk[0] = f2bf(f0.x); pk[1] = f2bf(f0.y); pk[2] = f2bf(f0.z); pk[3] = f2bf(f0.w);
            pk[4] = f2bf(f1.x); pk[5] = f2bf(f1.y); pk[6] = f2bf(f1.z); pk[7] = f2bf(f1.w);
            *reinterpret_cast<bf16x8*>(&As[(kc * 128 + m) * 8]) = pk;
        }
        for (int c = tid; c < 384; c += 256) {
            int n = c % 96, kc = c / 96;
            bf16x8 pk;
            #pragma unroll
            for (int p = 0; p < 8; ++p)
                pk[p] = (n < HW_N) ? f2bf(V[(size_t)(k0 + kc * 8 + p) * HW_N + n]) : (short)0;
            *reinterpret_cast<bf16x8*>(&Bs[(kc * 96 + n) * 8]) = pk;
        }
        __syncthreads();

        bf16x8 af[2];
        #pragma unroll
        for (int mt2 = 0; mt2 < 2; ++mt2)
            af[mt2] = *reinterpret_cast<const bf16x8*>(
                &As[(q * 128 + wv * 32 + mt2 * 16 + l15) * 8]);
        #pragma unroll
        for (int nt = 0; nt < 6; ++nt) {
            bf16x8 bf = *reinterpret_cast<const bf16x8*>(&Bs[(q * 96 + nt * 16 + l15) * 8]);
            #pragma unroll
            for (int mt2 = 0; mt2 < 2; ++mt2)
                acc[mt2][nt] = __builtin_amdgcn_mfma_f32_16x16x32_bf16(
                    af[mt2], bf, acc[mt2][nt], 0, 0, 0);
        }
    }

    #pragma unroll
    for (int mt2 = 0; mt2 < 2; ++mt2) {
        #pragma unroll
        for (int nt = 0; nt < 6; ++nt) {
            int i = nt * 16 + l15;
            if (i < HW_N) {
                #pragma unroll
                for (int r = 0; r < 4; ++r) {
                    int o = o0 + wv * 32 + mt2 * 16 + q * 4 + r;
                    size_t addr = ((size_t)b * D_N + o) * THW_N + (size_t)(DT_N + t) * HW_N + i;
                    float val = acc[mt2][nt][r];
                    x[addr] += (val > 0.f ? val : 0.f);
                }
            }
        }
    }
}

// ---------------- BatchNorm ----------------
__global__ __launch_bounds__(256) void bn_stats_kernel(
    const float* __restrict__ x, float* __restrict__ stats)
{
    const int c = blockIdx.x;
    const int tid = threadIdx.x;
    float s = 0.f, ss = 0.f;
    for (int idx = tid; idx < B_N * THW_N; idx += 256) {
        int b = idx / THW_N, p = idx - b * THW_N;
        float v = x[((size_t)b * D_N + c) * THW_N + p];
        s += v; ss += v * v;
    }
    #pragma unroll
    for (int o = 32; o > 0; o >>= 1) { s += __shfl_down(s, o); ss += __shfl_down(ss, o); }
    __shared__ float red[8];
    int wave = tid >> 6;
    if ((tid & 63) == 0) { red[wave] = s; red[4 + wave] = ss; }
    __syncthreads();
    if (tid == 0) {
        float st = red[0] + red[1] + red[2] + red[3];
        float sst = red[4] + red[5] + red[6] + red[7];
        const float invN = 1.f / (float)(B_N * THW_N);
        float mean = st * invN;
        float var = sst * invN - mean * mean;
        stats[c] = mean;
        stats[512 + c] = rsqrtf(var + BN_EPS);
    }
}

__global__ __launch_bounds__(256) void bn_apply_kernel(
    float* __restrict__ x, const float* __restrict__ stats,
    const float* __restrict__ gamma, const float* __restrict__ beta)
{
    int idx = blockIdx.x * 256 + threadIdx.x;
    float4* x4 = (float4*)x;
    int c = (idx / 756) & 511;
    float mean = stats[c], rs = stats[512 + c];
    float g = gamma[c], bb = beta[c];
    float4 v = x4[idx];
    v.x = g * (v.x - mean) * rs + bb;
    v.y = g * (v.y - mean) * rs + bb;
    v.z = g * (v.z - mean) * rs + bb;
    v.w = g * (v.w - mean) * rs + bb;
    x4[idx] = v;
}

// ---------------- launch ----------------
extern "C" void kernel_launch(void* const* d_in, const int* in_sizes, int n_in,
                              void* d_out, int out_size, void* d_ws, size_t ws_size,
                              hipStream_t stream)
{
    const float* inp  = (const float*)d_in[0];
    const float* dwq  = (const float*)d_in[1];
    const float* dwk  = (const float*)d_in[2];
    const float* dwv  = (const float*)d_in[3];
    const float* owq  = (const float*)d_in[5];
    const float* owk  = (const float*)d_in[6];
    const float* owv  = (const float*)d_in[7];
    const float* owo  = (const float*)d_in[8];
    const float* gam  = (const float*)d_in[9];
    const float* bet  = (const float*)d_in[10];
    float* x  = (float*)d_out;
    float* ws = (float*)d_ws;

    hipMemcpyAsync(x, inp, (size_t)B_N * D_N * THW_N * sizeof(float),
                   hipMemcpyDeviceToDevice, stream);

    for (int layer = 0; layer < 2; ++layer) {
        size_t woff = (size_t)layer * FF_N * D_N;
        size_t coff = (size_t)layer * D_N;
        proj_mfma_kernel<<<504, 256, 0, stream>>>(
            x, dwq + woff, dwk + woff, dwv + woff,
            owq + woff, owk + woff, owv + woff, ws);
        demo_attn_kernel<<<352, 256, 0, stream>>>(
            ws + WS_DQ, ws + WS_DK, ws + WS_DV, ws + WS_DVA);
        obs_attn_mfma_kernel<<<1024, 256, 0, stream>>>(
            ws + WS_DK, ws + WS_DVA, ws + WS_OQ, ws + WS_OK, ws + WS_OV, ws + WS_OVA);
        outproj_mfma_kernel<<<1024, 256, 0, stream>>>(x, owo + woff, ws + WS_OVA);
        bn_stats_kernel<<<512, 256, 0, stream>>>(x, ws + WS_STATS);
        bn_apply_kernel<<<12096, 256, 0, stream>>>(x, ws + WS_STATS, gam + coff, bet + coff);
    }
    (void)in_sizes; (void)n_in; (void)out_size; (void)ws_size;
}

// Round 5
// 558.138 us; speedup vs baseline: 2.1400x; 1.0405x over previous
//
#include <hip/hip_runtime.h>

// ---------------- problem constants ----------------
#define B_N 8
#define D_N 512
#define T_N 36
#define HW_N 84
#define THW_N 3024
#define DT_N 4
#define OT_N 32
#define NH_N 4
#define FF_N 128
#define CH_N 32
#define DI_N 336      // demo tokens 4*84
#define OI_N 2688     // obs tokens 32*84
#define CAT_N 420
#define INV_TEMP 0.04419417382415922f   // 1/sqrt(512)
#define BN_EPS 1e-5f

// workspace float offsets
#define WS_DQ   ((size_t)0)
#define WS_DK   ((size_t)344064)
#define WS_DV   ((size_t)688128)
#define WS_DVA  ((size_t)1032192)
#define WS_OQ   ((size_t)1376256)
#define WS_OK   ((size_t)4128768)
#define WS_OV   ((size_t)6881280)
#define WS_OVA  ((size_t)9633792)
#define WS_STATS ((size_t)12386304)

typedef short bf16x8 __attribute__((ext_vector_type(8)));   // 8 bf16 in 4 VGPRs
typedef float f32x4 __attribute__((ext_vector_type(4)));

__device__ __forceinline__ short f2bf(float f) {
    unsigned u = __float_as_uint(f);
    u += 0x7fffu + ((u >> 16) & 1u);          // round-to-nearest-even
    return (short)(u >> 16);
}

// ---------------- fused QKV projection, bf16 MFMA ----------------
__global__ __launch_bounds__(256) void proj_mfma_kernel(
    const float* __restrict__ x,
    const float* __restrict__ dwq, const float* __restrict__ dwk, const float* __restrict__ dwv,
    const float* __restrict__ owq, const float* __restrict__ owk, const float* __restrict__ owv,
    float* __restrict__ ws)
{
    __shared__ short As[3][4096];   // [wt][(kc*128 + m)*8]
    __shared__ short Bs[1536];      // [(kc*48 + n)*8]

    const int bid = blockIdx.x;
    const int b = bid / 63, ct = bid - b * 63;
    const bool is_demo = (ct < 7);
    const float* W0 = is_demo ? dwq : owq;
    const float* W1 = is_demo ? dwk : owk;
    const float* W2 = is_demo ? dwv : owv;
    const int L = is_demo ? DI_N : OI_N;
    const int colL = is_demo ? ct * 48 : (ct - 7) * 48;
    float* Y0 = ws + (is_demo ? WS_DQ : WS_OQ);
    float* Y1 = ws + (is_demo ? WS_DK : WS_OK);
    float* Y2 = ws + (is_demo ? WS_DV : WS_OV);
    const float* Xb = x + (size_t)b * D_N * THW_N + ct * 48;

    const int tid = threadIdx.x;
    const int lane = tid & 63, wv = tid >> 6;
    const int l15 = lane & 15, q = lane >> 4;

    f32x4 acc[3][2][3] = {};

    for (int k0 = 0; k0 < D_N; k0 += 32) {
        __syncthreads();
        const float* Wt[3] = {W0, W1, W2};
        #pragma unroll
        for (int wt = 0; wt < 3; ++wt) {
            #pragma unroll
            for (int h = 0; h < 2; ++h) {
                int c = tid + h * 256;
                int kc = c & 3, m = c >> 2;
                const float* src = Wt[wt] + (size_t)m * D_N + k0 + kc * 8;
                float4 f0 = *reinterpret_cast<const float4*>(src);
                float4 f1 = *reinterpret_cast<const float4*>(src + 4);
                bf16x8 pk;
                pk[0] = f2bf(f0.x); pk[1] = f2bf(f0.y); pk[2] = f2bf(f0.z); pk[3] = f2bf(f0.w);
                pk[4] = f2bf(f1.x); pk[5] = f2bf(f1.y); pk[6] = f2bf(f1.z); pk[7] = f2bf(f1.w);
                *reinterpret_cast<bf16x8*>(&As[wt][(kc * 128 + m) * 8]) = pk;
            }
        }
        if (tid < 192) {
            int n = tid % 48, kc = tid / 48;
            bf16x8 pk;
            #pragma unroll
            for (int p = 0; p < 8; ++p)
                pk[p] = f2bf(Xb[(size_t)(k0 + kc * 8 + p) * THW_N + n]);
            *reinterpret_cast<bf16x8*>(&Bs[(kc * 48 + n) * 8]) = pk;
        }
        __syncthreads();

        bf16x8 bfr[3];
        #pragma unroll
        for (int nt = 0; nt < 3; ++nt)
            bfr[nt] = *reinterpret_cast<const bf16x8*>(&Bs[(q * 48 + nt * 16 + l15) * 8]);
        #pragma unroll
        for (int wt = 0; wt < 3; ++wt) {
            #pragma unroll
            for (int mt2 = 0; mt2 < 2; ++mt2) {
                bf16x8 afr = *reinterpret_cast<const bf16x8*>(
                    &As[wt][(q * 128 + wv * 32 + mt2 * 16 + l15) * 8]);
                #pragma unroll
                for (int nt = 0; nt < 3; ++nt)
                    acc[wt][mt2][nt] = __builtin_amdgcn_mfma_f32_16x16x32_bf16(
                        afr, bfr[nt], acc[wt][mt2][nt], 0, 0, 0);
            }
        }
    }

    float* Yt[3] = {Y0, Y1, Y2};
    #pragma unroll
    for (int wt = 0; wt < 3; ++wt) {
        float* Yb = Yt[wt] + (size_t)b * FF_N * L + colL;
        #pragma unroll
        for (int mt2 = 0; mt2 < 2; ++mt2) {
            int mrow = wv * 32 + mt2 * 16 + q * 4;
            #pragma unroll
            for (int nt = 0; nt < 3; ++nt) {
                int col = nt * 16 + l15;
                #pragma unroll
                for (int r = 0; r < 4; ++r)
                    Yb[(size_t)(mrow + r) * L + col] = acc[wt][mt2][nt][r];
            }
        }
    }
}

// ---------------- demo attention, bf16 MFMA flash-style ----------------
// S[i][j] = sum_c dk[c][i] dq[c][j] * INV_TEMP; softmax over j (causal frame
// mask: j < (i/84+1)*84); dva[c][i] = sum_j P[i][j] dv[c][j].
// Block = one (b, n, i-frame ti): 96-row i-tile (84 valid), j chunks of 84
// (pad 96), online softmax (m in regs, l/alpha in LDS).
// 128 threads = 2 waves: QK m-tiles {3w..3w+2}; PV c-tile w, 6 n-tiles.
__global__ __launch_bounds__(128) void demo_attn_mfma_kernel(
    const float* __restrict__ dq, const float* __restrict__ dk,
    const float* __restrict__ dv, float* __restrict__ dva)
{
    __shared__ short Qt[96 * 40];   // [i][c]  rows from dk (INV_TEMP folded)
    __shared__ short Kt[96 * 40];   // [j][c]  cols from dq
    __shared__ short Vs[32 * 104];  // [c][j_local]
    __shared__ short Pt[96 * 104];  // [i][j_local]
    __shared__ float alpha_s[96];
    __shared__ float l_s[96];

    const int bid = blockIdx.x;                 // 32 pairs * 4 frames
    const int ti = bid & 3, pn = bid >> 2;
    const int b = pn >> 2, n = pn & 3;

    const float* dq_b = dq + ((size_t)b * FF_N + n * CH_N) * DI_N;
    const float* dk_b = dk + ((size_t)b * FF_N + n * CH_N) * DI_N;
    const float* dv_b = dv + ((size_t)b * FF_N + n * CH_N) * DI_N;
    float* dva_b = dva + ((size_t)b * FF_N + n * CH_N) * DI_N;

    const int tid = threadIdx.x;
    const int lane = tid & 63, wv = tid >> 6;   // wv in {0,1}
    const int l15 = lane & 15, q = lane >> 4;

    // stage Qt once (rows i from dk, scaled)
    for (int u = tid; u < 384; u += 128) {
        int i = u >> 2, c0 = (u & 3) * 8;
        int ig = ti * 84 + i;
        bf16x8 pk;
        #pragma unroll
        for (int p = 0; p < 8; ++p) {
            float v = (i < 84) ? dk_b[(size_t)(c0 + p) * DI_N + ig] * INV_TEMP : 0.f;
            pk[p] = f2bf(v);
        }
        *reinterpret_cast<bf16x8*>(&Qt[i * 40 + c0]) = pk;
    }
    if (tid < 96) l_s[tid] = 0.f;

    float m_r[3][4];
    #pragma unroll
    for (int mt = 0; mt < 3; ++mt)
        #pragma unroll
        for (int r = 0; r < 4; ++r) m_r[mt][r] = -3.0e38f;

    f32x4 oacc[6] = {};

    for (int cj = 0; cj <= ti; ++cj) {
        __syncthreads();   // prev PV done (and Qt/l_s staged on first pass)
        // stage Kt (cols j from dq)
        for (int u = tid; u < 384; u += 128) {
            int j = u >> 2, c0 = (u & 3) * 8;
            int jg = cj * 84 + j;
            bf16x8 pk;
            #pragma unroll
            for (int p = 0; p < 8; ++p) {
                float v = (j < 84) ? dq_b[(size_t)(c0 + p) * DI_N + jg] : 0.f;
                pk[p] = f2bf(v);
            }
            *reinterpret_cast<bf16x8*>(&Kt[j * 40 + c0]) = pk;
        }
        // stage Vs[c][j_local] (96 j, zero pad)
        for (int u = tid; u < 384; u += 128) {
            int c = u / 12, j0 = (u % 12) * 8;
            bf16x8 pk;
            #pragma unroll
            for (int p = 0; p < 8; ++p) {
                int j = j0 + p;
                float v = (j < 84) ? dv_b[(size_t)c * DI_N + cj * 84 + j] : 0.f;
                pk[p] = f2bf(v);
            }
            *reinterpret_cast<bf16x8*>(&Vs[c * 104 + j0]) = pk;
        }
        __syncthreads();

        // QK + online softmax; this wave owns m-tiles 3*wv .. 3*wv+2
        #pragma unroll
        for (int mt = 0; mt < 3; ++mt) {
            int mrow = (wv * 3 + mt) * 16;
            bf16x8 afr = *reinterpret_cast<const bf16x8*>(&Qt[(mrow + l15) * 40 + q * 8]);
            f32x4 s[6];
            #pragma unroll
            for (int nt = 0; nt < 6; ++nt) {
                bf16x8 bfr = *reinterpret_cast<const bf16x8*>(&Kt[(nt * 16 + l15) * 40 + q * 8]);
                f32x4 z = {};
                s[nt] = __builtin_amdgcn_mfma_f32_16x16x32_bf16(afr, bfr, z, 0, 0, 0);
            }
            #pragma unroll
            for (int r = 0; r < 4; ++r) {
                if (l15 >= 4) s[5][r] = -3.0e38f;     // j_local >= 84
                float mx = s[0][r];
                #pragma unroll
                for (int nt = 1; nt < 6; ++nt) mx = fmaxf(mx, s[nt][r]);
                #pragma unroll
                for (int o = 1; o < 16; o <<= 1) mx = fmaxf(mx, __shfl_xor(mx, o));
                float mnew = fmaxf(m_r[mt][r], mx);
                float al = __expf(m_r[mt][r] - mnew);
                m_r[mt][r] = mnew;
                float sm = 0.f;
                #pragma unroll
                for (int nt = 0; nt < 6; ++nt) {
                    float e = __expf(s[nt][r] - mnew);
                    s[nt][r] = e; sm += e;
                }
                #pragma unroll
                for (int o = 1; o < 16; o <<= 1) sm += __shfl_xor(sm, o);
                int i = mrow + q * 4 + r;
                if (l15 == 0) { alpha_s[i] = al; l_s[i] = l_s[i] * al + sm; }
            }
            // write Pt[i][j_local]
            #pragma unroll
            for (int nt = 0; nt < 6; ++nt)
                #pragma unroll
                for (int r = 0; r < 4; ++r)
                    Pt[(mrow + q * 4 + r) * 104 + nt * 16 + l15] = f2bf(s[nt][r]);
        }
        __syncthreads();

        // PV: rescale O by alpha, accumulate chunk
        #pragma unroll
        for (int nt = 0; nt < 6; ++nt) {
            float al = alpha_s[nt * 16 + l15];
            #pragma unroll
            for (int r = 0; r < 4; ++r) oacc[nt][r] *= al;
        }
        #pragma unroll
        for (int kk = 0; kk < 3; ++kk) {
            bf16x8 va = *reinterpret_cast<const bf16x8*>(&Vs[(wv * 16 + l15) * 104 + kk * 32 + q * 8]);
            #pragma unroll
            for (int nt = 0; nt < 6; ++nt) {
                bf16x8 pb = *reinterpret_cast<const bf16x8*>(&Pt[(nt * 16 + l15) * 104 + kk * 32 + q * 8]);
                oacc[nt] = __builtin_amdgcn_mfma_f32_16x16x32_bf16(va, pb, oacc[nt], 0, 0, 0);
            }
        }
    }

    // epilogue: c = wv*16 + q*4 + r, i = nt*16 + l15 (valid < 84)
    #pragma unroll
    for (int nt = 0; nt < 6; ++nt) {
        int il = nt * 16 + l15;
        if (il < 84) {
            float inv = 1.f / l_s[il];
            int ig = ti * 84 + il;
            #pragma unroll
            for (int r = 0; r < 4; ++r)
                dva_b[(size_t)(wv * 16 + q * 4 + r) * DI_N + ig] = oacc[nt][r] * inv;
        }
    }
}

// ---------------- obs attention, bf16 MFMA ----------------
__global__ __launch_bounds__(256, 4) void obs_attn_mfma_kernel(
    const float* __restrict__ dk, const float* __restrict__ dva,
    const float* __restrict__ oq, const float* __restrict__ okp, const float* __restrict__ ovp,
    float* __restrict__ ova)
{
    __shared__ short Qt[96 * 40];   // [i][c], INV_TEMP folded, rows>=84 zero
    __shared__ short Kt[64 * 40];   // [j_local][c]
    __shared__ short Vs[32 * 72];   // [c][j_local]
    __shared__ short Pt[96 * 72];   // [i][j_local]

    const int bid = blockIdx.x;
    const int b = bid >> 7, rem = bid & 127, t = rem >> 2, n = rem & 3;

    const float* oq_b = oq + ((size_t)b * FF_N + n * CH_N) * OI_N + t * HW_N;
    const float* ok_b = okp + ((size_t)b * FF_N + n * CH_N) * OI_N + t * HW_N;
    const float* ov_b = ovp + ((size_t)b * FF_N + n * CH_N) * OI_N + t * HW_N;
    const float* dk_b = dk + ((size_t)b * FF_N + n * CH_N) * DI_N;
    const float* dva_b = dva + ((size_t)b * FF_N + n * CH_N) * DI_N;
    float* out_b = ova + (((size_t)b * OT_N + t) * FF_N + n * CH_N) * HW_N;

    const int tid = threadIdx.x;
    const int lane = tid & 63, wv = tid >> 6;
    const int l15 = lane & 15, q = lane >> 4;

    for (int l = tid; l < 384; l += 256) {
        int i = l >> 2, c0 = (l & 3) * 8;
        bf16x8 pk;
        #pragma unroll
        for (int p = 0; p < 8; ++p) {
            float v = (i < HW_N) ? oq_b[(size_t)(c0 + p) * OI_N + i] * INV_TEMP : 0.f;
            pk[p] = f2bf(v);
        }
        *reinterpret_cast<bf16x8*>(&Qt[i * 40 + c0]) = pk;
    }

    const int pv_mt = wv & 1;
    const int pv_nb = wv >> 1;
    f32x4 oacc[3] = {};

    for (int jc = 0; jc < 448; jc += 64) {
        __syncthreads();
        {
            int jl = tid >> 2, c0 = (tid & 3) * 8;
            int jg = jc + jl;
            bf16x8 pk;
            #pragma unroll
            for (int p = 0; p < 8; ++p) {
                int c = c0 + p;
                float v = 0.f;
                if (jg < DI_N) v = dk_b[(size_t)c * DI_N + jg];
                else if (jg < CAT_N) v = ok_b[(size_t)c * OI_N + (jg - DI_N)];
                pk[p] = f2bf(v);
            }
            *reinterpret_cast<bf16x8*>(&Kt[jl * 40 + c0]) = pk;
        }
        {
            int c = tid >> 3, j0 = (tid & 7) * 8;
            bf16x8 pk;
            #pragma unroll
            for (int p = 0; p < 8; ++p) {
                int jg = jc + j0 + p;
                float v = 0.f;
                if (jg < DI_N) v = dva_b[(size_t)c * DI_N + jg];
                else if (jg < CAT_N) v = ov_b[(size_t)c * OI_N + (jg - DI_N)];
                pk[p] = f2bf(v);
            }
            *reinterpret_cast<bf16x8*>(&Vs[c * 72 + j0]) = pk;
        }
        __syncthreads();

        f32x4 s[6];
        bf16x8 afr = *reinterpret_cast<const bf16x8*>(&Kt[(wv * 16 + l15) * 40 + q * 8]);
        #pragma unroll
        for (int nt = 0; nt < 6; ++nt) {
            bf16x8 bfr = *reinterpret_cast<const bf16x8*>(&Qt[(nt * 16 + l15) * 40 + q * 8]);
            f32x4 z = {};
            s[nt] = __builtin_amdgcn_mfma_f32_16x16x32_bf16(afr, bfr, z, 0, 0, 0);
        }
        float inv[4];
        #pragma unroll
        for (int r = 0; r < 4; ++r) {
            if (l15 >= 4) s[5][r] = -3.0e38f;
            float m2 = s[0][r];
            #pragma unroll
            for (int nt2 = 1; nt2 < 6; ++nt2) m2 = fmaxf(m2, s[nt2][r]);
            #pragma unroll
            for (int o = 1; o < 16; o <<= 1) m2 = fmaxf(m2, __shfl_xor(m2, o));
            float sm = 0.f;
            #pragma unroll
            for (int nt2 = 0; nt2 < 6; ++nt2) { float e = __expf(s[nt2][r] - m2); s[nt2][r] = e; sm += e; }
            #pragma unroll
            for (int o = 1; o < 16; o <<= 1) sm += __shfl_xor(sm, o);
            inv[r] = 1.f / sm;
        }
        #pragma unroll
        for (int nt = 0; nt < 6; ++nt) {
            short4 pk4;
            pk4.x = f2bf(s[nt][0] * inv[0]);
            pk4.y = f2bf(s[nt][1] * inv[1]);
            pk4.z = f2bf(s[nt][2] * inv[2]);
            pk4.w = f2bf(s[nt][3] * inv[3]);
            *reinterpret_cast<short4*>(&Pt[(nt * 16 + l15) * 72 + wv * 16 + q * 4]) = pk4;
        }
        __syncthreads();

        #pragma unroll
        for (int kk = 0; kk < 2; ++kk) {
            bf16x8 va = *reinterpret_cast<const bf16x8*>(&Vs[(pv_mt * 16 + l15) * 72 + kk * 32 + q * 8]);
            #pragma unroll
            for (int u = 0; u < 3; ++u) {
                int nt = pv_nb + u * 2;
                bf16x8 pb = *reinterpret_cast<const bf16x8*>(&Pt[(nt * 16 + l15) * 72 + kk * 32 + q * 8]);
                oacc[u] = __builtin_amdgcn_mfma_f32_16x16x32_bf16(va, pb, oacc[u], 0, 0, 0);
            }
        }
    }

    #pragma unroll
    for (int u = 0; u < 3; ++u) {
        int i = (pv_nb + u * 2) * 16 + l15;
        if (i < HW_N) {
            #pragma unroll
            for (int r = 0; r < 4; ++r)
                out_b[(size_t)(pv_mt * 16 + q * 4 + r) * HW_N + i] = oacc[u][r];
        }
    }
}

// ---------------- output projection, bf16 MFMA + ReLU + residual ----------------
__global__ __launch_bounds__(256) void outproj_mfma_kernel(
    float* __restrict__ x, const float* __restrict__ wo, const float* __restrict__ ova)
{
    __shared__ short As[4096];  // [(kc*128 + m)*8]
    __shared__ short Bs[3072];  // [(kc*96 + n)*8]

    const int bid = blockIdx.x;
    const int b = bid >> 7, rem = bid & 127, t = rem >> 2, mt = rem & 3;
    const int o0 = mt * 128;
    const float* V = ova + ((size_t)b * OT_N + t) * (FF_N * HW_N);
    const float* Wb = wo + (size_t)o0 * FF_N;

    const int tid = threadIdx.x;
    const int lane = tid & 63, wv = tid >> 6;
    const int l15 = lane & 15, q = lane >> 4;

    f32x4 acc[2][6] = {};

    for (int k0 = 0; k0 < FF_N; k0 += 32) {
        __syncthreads();
        #pragma unroll
        for (int h = 0; h < 2; ++h) {
            int c = tid + h * 256;
            int kc = c & 3, m = c >> 2;
            const float* src = Wb + (size_t)m * FF_N + k0 + kc * 8;
            float4 f0 = *reinterpret_cast<const float4*>(src);
            float4 f1 = *reinterpret_cast<const float4*>(src + 4);
            bf16x8 pk;
            pk[0] = f2bf(f0.x); pk[1] = f2bf(f0.y); pk[2] = f2bf(f0.z); pk[3] = f2bf(f0.w);
            pk[4] = f2bf(f1.x); pk[5] = f2bf(f1.y); pk[6] = f2bf(f1.z); pk[7] = f2bf(f1.w);
            *reinterpret_cast<bf16x8*>(&As[(kc * 128 + m) * 8]) = pk;
        }
        for (int c = tid; c < 384; c += 256) {
            int n = c % 96, kc = c / 96;
            bf16x8 pk;
            #pragma unroll
            for (int p = 0; p < 8; ++p)
                pk[p] = (n < HW_N) ? f2bf(V[(size_t)(k0 + kc * 8 + p) * HW_N + n]) : (short)0;
            *reinterpret_cast<bf16x8*>(&Bs[(kc * 96 + n) * 8]) = pk;
        }
        __syncthreads();

        bf16x8 af[2];
        #pragma unroll
        for (int mt2 = 0; mt2 < 2; ++mt2)
            af[mt2] = *reinterpret_cast<const bf16x8*>(
                &As[(q * 128 + wv * 32 + mt2 * 16 + l15) * 8]);
        #pragma unroll
        for (int nt = 0; nt < 6; ++nt) {
            bf16x8 bf = *reinterpret_cast<const bf16x8*>(&Bs[(q * 96 + nt * 16 + l15) * 8]);
            #pragma unroll
            for (int mt2 = 0; mt2 < 2; ++mt2)
                acc[mt2][nt] = __builtin_amdgcn_mfma_f32_16x16x32_bf16(
                    af[mt2], bf, acc[mt2][nt], 0, 0, 0);
        }
    }

    #pragma unroll
    for (int mt2 = 0; mt2 < 2; ++mt2) {
        #pragma unroll
        for (int nt = 0; nt < 6; ++nt) {
            int i = nt * 16 + l15;
            if (i < HW_N) {
                #pragma unroll
                for (int r = 0; r < 4; ++r) {
                    int o = o0 + wv * 32 + mt2 * 16 + q * 4 + r;
                    size_t addr = ((size_t)b * D_N + o) * THW_N + (size_t)(DT_N + t) * HW_N + i;
                    float val = acc[mt2][nt][r];
                    x[addr] += (val > 0.f ? val : 0.f);
                }
            }
        }
    }
}

// ---------------- BatchNorm ----------------
__global__ __launch_bounds__(256) void bn_stats_kernel(
    const float* __restrict__ x, float* __restrict__ stats)
{
    const int c = blockIdx.x;
    const int tid = threadIdx.x;
    float s = 0.f, ss = 0.f;
    for (int idx = tid; idx < B_N * THW_N; idx += 256) {
        int b = idx / THW_N, p = idx - b * THW_N;
        float v = x[((size_t)b * D_N + c) * THW_N + p];
        s += v; ss += v * v;
    }
    #pragma unroll
    for (int o = 32; o > 0; o >>= 1) { s += __shfl_down(s, o); ss += __shfl_down(ss, o); }
    __shared__ float red[8];
    int wave = tid >> 6;
    if ((tid & 63) == 0) { red[wave] = s; red[4 + wave] = ss; }
    __syncthreads();
    if (tid == 0) {
        float st = red[0] + red[1] + red[2] + red[3];
        float sst = red[4] + red[5] + red[6] + red[7];
        const float invN = 1.f / (float)(B_N * THW_N);
        float mean = st * invN;
        float var = sst * invN - mean * mean;
        stats[c] = mean;
        stats[512 + c] = rsqrtf(var + BN_EPS);
    }
}

__global__ __launch_bounds__(256) void bn_apply_kernel(
    float* __restrict__ x, const float* __restrict__ stats,
    const float* __restrict__ gamma, const float* __restrict__ beta)
{
    int idx = blockIdx.x * 256 + threadIdx.x;
    float4* x4 = (float4*)x;
    int c = (idx / 756) & 511;
    float mean = stats[c], rs = stats[512 + c];
    float g = gamma[c], bb = beta[c];
    float4 v = x4[idx];
    v.x = g * (v.x - mean) * rs + bb;
    v.y = g * (v.y - mean) * rs + bb;
    v.z = g * (v.z - mean) * rs + bb;
    v.w = g * (v.w - mean) * rs + bb;
    x4[idx] = v;
}

// ---------------- launch ----------------
extern "C" void kernel_launch(void* const* d_in, const int* in_sizes, int n_in,
                              void* d_out, int out_size, void* d_ws, size_t ws_size,
                              hipStream_t stream)
{
    const float* inp  = (const float*)d_in[0];
    const float* dwq  = (const float*)d_in[1];
    const float* dwk  = (const float*)d_in[2];
    const float* dwv  = (const float*)d_in[3];
    const float* owq  = (const float*)d_in[5];
    const float* owk  = (const float*)d_in[6];
    const float* owv  = (const float*)d_in[7];
    const float* owo  = (const float*)d_in[8];
    const float* gam  = (const float*)d_in[9];
    const float* bet  = (const float*)d_in[10];
    float* x  = (float*)d_out;
    float* ws = (float*)d_ws;

    hipMemcpyAsync(x, inp, (size_t)B_N * D_N * THW_N * sizeof(float),
                   hipMemcpyDeviceToDevice, stream);

    for (int layer = 0; layer < 2; ++layer) {
        size_t woff = (size_t)layer * FF_N * D_N;
        size_t coff = (size_t)layer * D_N;
        proj_mfma_kernel<<<504, 256, 0, stream>>>(
            x, dwq + woff, dwk + woff, dwv + woff,
            owq + woff, owk + woff, owv + woff, ws);
        demo_attn_mfma_kernel<<<128, 128, 0, stream>>>(
            ws + WS_DQ, ws + WS_DK, ws + WS_DV, ws + WS_DVA);
        obs_attn_mfma_kernel<<<1024, 256, 0, stream>>>(
            ws + WS_DK, ws + WS_DVA, ws + WS_OQ, ws + WS_OK, ws + WS_OV, ws + WS_OVA);
        outproj_mfma_kernel<<<1024, 256, 0, stream>>>(x, owo + woff, ws + WS_OVA);
        bn_stats_kernel<<<512, 256, 0, stream>>>(x, ws + WS_STATS);
        bn_apply_kernel<<<12096, 256, 0, stream>>>(x, ws + WS_STATS, gam + coff, bet + coff);
    }
    (void)in_sizes; (void)n_in; (void)out_size; (void)ws_size;
}

// Round 6
// 468.822 us; speedup vs baseline: 2.5477x; 1.1905x over previous
//
#include <hip/hip_runtime.h>

// ---------------- problem constants ----------------
#define B_N 8
#define D_N 512
#define T_N 36
#define HW_N 84
#define THW_N 3024
#define DT_N 4
#define OT_N 32
#define NH_N 4
#define FF_N 128
#define CH_N 32
#define DI_N 336      // demo tokens 4*84
#define OI_N 2688     // obs tokens 32*84
#define CAT_N 420
#define INV_TEMP 0.04419417382415922f   // 1/sqrt(512)
#define BN_EPS 1e-5f

// workspace: float stats[1024] at base, then bf16 (short) arena at +4096B.
// short offsets within arena:
#define SW_DWQ 0
#define SW_DWK 131072
#define SW_DWV 262144
#define SW_OWQ 393216
#define SW_OWK 524288
#define SW_OWV 655360
#define SW_OWO 786432
#define S_DQ   917504     // [b][336][128] token-major (INV_TEMP folded)
#define S_DK   1261568    // [b][336][128] token-major
#define S_DV   1605632    // [b][128][336] channel-major
#define S_DVA  1949696    // [b][128][336] channel-major
#define S_OQ   2293760    // [b][2688][128] token-major (INV_TEMP folded)
#define S_OK   5046272    // [b][2688][128] token-major
#define S_OV   7798784    // [b][128][2688] channel-major
#define S_OVA  10551296   // [b][32][84][128] token-major

typedef short bf16x8 __attribute__((ext_vector_type(8)));   // 8 bf16 in 4 VGPRs
typedef float f32x4 __attribute__((ext_vector_type(4)));

__device__ __forceinline__ short f2bf(float f) {
    unsigned u = __float_as_uint(f);
    u += 0x7fffu + ((u >> 16) & 1u);          // round-to-nearest-even
    return (short)(u >> 16);
}

// ---------------- weight conversion (once per launch) ----------------
__global__ __launch_bounds__(256) void cvt_w_kernel(
    const float* __restrict__ s0, const float* __restrict__ s1,
    const float* __restrict__ s2, const float* __restrict__ s3,
    const float* __restrict__ s4, const float* __restrict__ s5,
    const float* __restrict__ s6, short* __restrict__ dst)
{
    const int bid = blockIdx.x;
    const int a = bid >> 6, blk = bid & 63;
    const float* src;
    switch (a) {
        case 0: src = s0; break; case 1: src = s1; break;
        case 2: src = s2; break; case 3: src = s3; break;
        case 4: src = s4; break; case 5: src = s5; break;
        default: src = s6;
    }
    const int idx = (blk * 256 + (int)threadIdx.x) * 8;   // 131072 elems / array
    float4 f0 = *reinterpret_cast<const float4*>(src + idx);
    float4 f1 = *reinterpret_cast<const float4*>(src + idx + 4);
    bf16x8 pk;
    pk[0] = f2bf(f0.x); pk[1] = f2bf(f0.y); pk[2] = f2bf(f0.z); pk[3] = f2bf(f0.w);
    pk[4] = f2bf(f1.x); pk[5] = f2bf(f1.y); pk[6] = f2bf(f1.z); pk[7] = f2bf(f1.w);
    *reinterpret_cast<bf16x8*>(dst + (size_t)a * 131072 + idx) = pk;
}

// ---------------- fused QKV projection, bf16 MFMA ----------------
// Y[wt][128 o][48 cols] = W[wt](128x512) * X(512 x 48cols), wt in {q,k,v}
// q/k outputs token-major bf16 (q scaled by INV_TEMP); v channel-major bf16.
__global__ __launch_bounds__(256) void proj_mfma_kernel(
    const float* __restrict__ x, short* __restrict__ ws, int layer)
{
    __shared__ short As[3][4096];   // [wt][(kc*128 + m)*8]
    __shared__ short Bs[1536];      // [(kc*48 + n)*8]

    const int bid = blockIdx.x;
    const int b = bid / 63, ct = bid - b * 63;
    const bool is_demo = (ct < 7);
    const int woff = layer * 65536;
    const short* W0 = ws + (is_demo ? SW_DWQ : SW_OWQ) + woff;
    const short* W1 = ws + (is_demo ? SW_DWK : SW_OWK) + woff;
    const short* W2 = ws + (is_demo ? SW_DWV : SW_OWV) + woff;
    const int Ltok = is_demo ? DI_N : OI_N;
    const int colL = is_demo ? ct * 48 : (ct - 7) * 48;
    short* Yq = ws + (is_demo ? S_DQ : S_OQ);
    short* Yk = ws + (is_demo ? S_DK : S_OK);
    short* Yv = ws + (is_demo ? S_DV : S_OV);
    const float* Xb = x + (size_t)b * D_N * THW_N + ct * 48;

    const int tid = threadIdx.x;
    const int lane = tid & 63, wv = tid >> 6;
    const int l15 = lane & 15, q = lane >> 4;

    f32x4 acc[3][2][3] = {};

    for (int k0 = 0; k0 < D_N; k0 += 32) {
        __syncthreads();
        const short* Wt[3] = {W0, W1, W2};
        #pragma unroll
        for (int wt = 0; wt < 3; ++wt) {
            #pragma unroll
            for (int h = 0; h < 2; ++h) {
                int c = tid + h * 256;
                int kc = c & 3, m = c >> 2;
                bf16x8 pk = *reinterpret_cast<const bf16x8*>(
                    Wt[wt] + (size_t)m * D_N + k0 + kc * 8);
                *reinterpret_cast<bf16x8*>(&As[wt][(kc * 128 + m) * 8]) = pk;
            }
        }
        if (tid < 192) {
            int n = tid % 48, kc = tid / 48;
            bf16x8 pk;
            #pragma unroll
            for (int p = 0; p < 8; ++p)
                pk[p] = f2bf(Xb[(size_t)(k0 + kc * 8 + p) * THW_N + n]);
            *reinterpret_cast<bf16x8*>(&Bs[(kc * 48 + n) * 8]) = pk;
        }
        __syncthreads();

        bf16x8 bfr[3];
        #pragma unroll
        for (int nt = 0; nt < 3; ++nt)
            bfr[nt] = *reinterpret_cast<const bf16x8*>(&Bs[(q * 48 + nt * 16 + l15) * 8]);
        #pragma unroll
        for (int wt = 0; wt < 3; ++wt) {
            #pragma unroll
            for (int mt2 = 0; mt2 < 2; ++mt2) {
                bf16x8 afr = *reinterpret_cast<const bf16x8*>(
                    &As[wt][(q * 128 + wv * 32 + mt2 * 16 + l15) * 8]);
                #pragma unroll
                for (int nt = 0; nt < 3; ++nt)
                    acc[wt][mt2][nt] = __builtin_amdgcn_mfma_f32_16x16x32_bf16(
                        afr, bfr[nt], acc[wt][mt2][nt], 0, 0, 0);
            }
        }
    }

    // epilogue
    #pragma unroll
    for (int mt2 = 0; mt2 < 2; ++mt2) {
        int mrow = wv * 32 + mt2 * 16 + q * 4;
        #pragma unroll
        for (int nt = 0; nt < 3; ++nt) {
            int token = colL + nt * 16 + l15;
            // q (scaled) token-major
            f32x4 aq = acc[0][mt2][nt] * INV_TEMP;
            short4 s4;
            s4.x = f2bf(aq[0]); s4.y = f2bf(aq[1]); s4.z = f2bf(aq[2]); s4.w = f2bf(aq[3]);
            *reinterpret_cast<short4*>(Yq + ((size_t)b * Ltok + token) * 128 + mrow) = s4;
            // k token-major
            f32x4 ak = acc[1][mt2][nt];
            s4.x = f2bf(ak[0]); s4.y = f2bf(ak[1]); s4.z = f2bf(ak[2]); s4.w = f2bf(ak[3]);
            *reinterpret_cast<short4*>(Yk + ((size_t)b * Ltok + token) * 128 + mrow) = s4;
            // v channel-major
            #pragma unroll
            for (int r = 0; r < 4; ++r)
                Yv[((size_t)b * FF_N + mrow + r) * Ltok + token] = f2bf(acc[2][mt2][nt][r]);
        }
    }
}

// ---------------- demo attention, bf16 MFMA flash-style ----------------
__global__ __launch_bounds__(128) void demo_attn_mfma_kernel(const short* __restrict__ ws)
{
    __shared__ short Qt[96 * 40];   // [i][c]  rows from dk
    __shared__ short Kt[96 * 40];   // [j][c]  cols from dq (scale folded)
    __shared__ short Vs[32 * 104];  // [c][j_local]
    __shared__ short Pt[96 * 104];  // [i][j_local]
    __shared__ float alpha_s[96];
    __shared__ float l_s[96];

    const short* dqS = ws + S_DQ;
    const short* dkS = ws + S_DK;
    const short* dvS = ws + S_DV;
    short* dvaS = const_cast<short*>(ws) + S_DVA;

    const int bid = blockIdx.x;
    const int ti = bid & 3, pn = bid >> 2;
    const int b = pn >> 2, n = pn & 3;

    const int tid = threadIdx.x;
    const int lane = tid & 63, wv = tid >> 6;
    const int l15 = lane & 15, q = lane >> 4;

    // stage Qt once (rows i from dk token-major)
    for (int u = tid; u < 384; u += 128) {
        int i = u >> 2, c0 = (u & 3) * 8;
        bf16x8 pk = {0,0,0,0,0,0,0,0};
        if (i < 84)
            pk = *reinterpret_cast<const bf16x8*>(
                dkS + ((size_t)b * DI_N + ti * 84 + i) * 128 + n * 32 + c0);
        *reinterpret_cast<bf16x8*>(&Qt[i * 40 + c0]) = pk;
    }
    if (tid < 96) l_s[tid] = 0.f;

    float m_r[3][4];
    #pragma unroll
    for (int mt = 0; mt < 3; ++mt)
        #pragma unroll
        for (int r = 0; r < 4; ++r) m_r[mt][r] = -3.0e38f;

    f32x4 oacc[6] = {};

    for (int cj = 0; cj <= ti; ++cj) {
        __syncthreads();
        // Kt: cols j from dq token-major
        for (int u = tid; u < 384; u += 128) {
            int j = u >> 2, c0 = (u & 3) * 8;
            bf16x8 pk = {0,0,0,0,0,0,0,0};
            if (j < 84)
                pk = *reinterpret_cast<const bf16x8*>(
                    dqS + ((size_t)b * DI_N + cj * 84 + j) * 128 + n * 32 + c0);
            *reinterpret_cast<bf16x8*>(&Kt[j * 40 + c0]) = pk;
        }
        // Vs: [c][j] from dv channel-major (8B-aligned short4 pairs)
        for (int u = tid; u < 384; u += 128) {
            int c = u / 12, j0 = (u % 12) * 8;
            const short* row = dvS + ((size_t)b * FF_N + n * 32 + c) * DI_N + cj * 84;
            bf16x8 pk;
            if (j0 + 8 <= 84) {
                short4 lo = *reinterpret_cast<const short4*>(row + j0);
                short4 hi = *reinterpret_cast<const short4*>(row + j0 + 4);
                pk[0]=lo.x; pk[1]=lo.y; pk[2]=lo.z; pk[3]=lo.w;
                pk[4]=hi.x; pk[5]=hi.y; pk[6]=hi.z; pk[7]=hi.w;
            } else {
                #pragma unroll
                for (int p = 0; p < 8; ++p) {
                    int j = j0 + p;
                    pk[p] = (j < 84) ? row[j] : (short)0;
                }
            }
            *reinterpret_cast<bf16x8*>(&Vs[c * 104 + j0]) = pk;
        }
        __syncthreads();

        #pragma unroll
        for (int mt = 0; mt < 3; ++mt) {
            int mrow = (wv * 3 + mt) * 16;
            bf16x8 afr = *reinterpret_cast<const bf16x8*>(&Qt[(mrow + l15) * 40 + q * 8]);
            f32x4 s[6];
            #pragma unroll
            for (int nt = 0; nt < 6; ++nt) {
                bf16x8 bfr = *reinterpret_cast<const bf16x8*>(&Kt[(nt * 16 + l15) * 40 + q * 8]);
                f32x4 z = {};
                s[nt] = __builtin_amdgcn_mfma_f32_16x16x32_bf16(afr, bfr, z, 0, 0, 0);
            }
            #pragma unroll
            for (int r = 0; r < 4; ++r) {
                if (l15 >= 4) s[5][r] = -3.0e38f;
                float mx = s[0][r];
                #pragma unroll
                for (int nt = 1; nt < 6; ++nt) mx = fmaxf(mx, s[nt][r]);
                #pragma unroll
                for (int o = 1; o < 16; o <<= 1) mx = fmaxf(mx, __shfl_xor(mx, o));
                float mnew = fmaxf(m_r[mt][r], mx);
                float al = __expf(m_r[mt][r] - mnew);
                m_r[mt][r] = mnew;
                float sm = 0.f;
                #pragma unroll
                for (int nt = 0; nt < 6; ++nt) {
                    float e = __expf(s[nt][r] - mnew);
                    s[nt][r] = e; sm += e;
                }
                #pragma unroll
                for (int o = 1; o < 16; o <<= 1) sm += __shfl_xor(sm, o);
                int i = mrow + q * 4 + r;
                if (l15 == 0) { alpha_s[i] = al; l_s[i] = l_s[i] * al + sm; }
            }
            #pragma unroll
            for (int nt = 0; nt < 6; ++nt)
                #pragma unroll
                for (int r = 0; r < 4; ++r)
                    Pt[(mrow + q * 4 + r) * 104 + nt * 16 + l15] = f2bf(s[nt][r]);
        }
        __syncthreads();

        #pragma unroll
        for (int nt = 0; nt < 6; ++nt) {
            float al = alpha_s[nt * 16 + l15];
            #pragma unroll
            for (int r = 0; r < 4; ++r) oacc[nt][r] *= al;
        }
        #pragma unroll
        for (int kk = 0; kk < 3; ++kk) {
            bf16x8 va = *reinterpret_cast<const bf16x8*>(&Vs[(wv * 16 + l15) * 104 + kk * 32 + q * 8]);
            #pragma unroll
            for (int nt = 0; nt < 6; ++nt) {
                bf16x8 pb = *reinterpret_cast<const bf16x8*>(&Pt[(nt * 16 + l15) * 104 + kk * 32 + q * 8]);
                oacc[nt] = __builtin_amdgcn_mfma_f32_16x16x32_bf16(va, pb, oacc[nt], 0, 0, 0);
            }
        }
    }

    // epilogue: dva channel-major bf16
    #pragma unroll
    for (int nt = 0; nt < 6; ++nt) {
        int il = nt * 16 + l15;
        if (il < 84) {
            float inv = 1.f / l_s[il];
            int ig = ti * 84 + il;
            #pragma unroll
            for (int r = 0; r < 4; ++r)
                dvaS[((size_t)b * FF_N + n * 32 + wv * 16 + q * 4 + r) * DI_N + ig] =
                    f2bf(oacc[nt][r] * inv);
        }
    }
}

// ---------------- obs attention, bf16 MFMA ----------------
__global__ __launch_bounds__(256, 4) void obs_attn_mfma_kernel(const short* __restrict__ ws)
{
    __shared__ short Qt[96 * 40];   // [i][c]
    __shared__ short Kt[64 * 40];   // [j_local][c]
    __shared__ short Vs[32 * 72];   // [c][j_local]
    __shared__ short Pt[96 * 72];   // [i][j_local]

    const short* dkS = ws + S_DK;
    const short* dvaS = ws + S_DVA;
    const short* oqS = ws + S_OQ;
    const short* okS = ws + S_OK;
    const short* ovS = ws + S_OV;
    short* ovaS = const_cast<short*>(ws) + S_OVA;

    const int bid = blockIdx.x;
    const int b = bid >> 7, rem = bid & 127, t = rem >> 2, n = rem & 3;

    const int tid = threadIdx.x;
    const int lane = tid & 63, wv = tid >> 6;
    const int l15 = lane & 15, q = lane >> 4;

    for (int l = tid; l < 384; l += 256) {
        int i = l >> 2, c0 = (l & 3) * 8;
        bf16x8 pk = {0,0,0,0,0,0,0,0};
        if (i < HW_N)
            pk = *reinterpret_cast<const bf16x8*>(
                oqS + ((size_t)b * OI_N + t * 84 + i) * 128 + n * 32 + c0);
        *reinterpret_cast<bf16x8*>(&Qt[i * 40 + c0]) = pk;
    }

    const int pv_mt = wv & 1;
    const int pv_nb = wv >> 1;
    f32x4 oacc[3] = {};

    for (int jc = 0; jc < 448; jc += 64) {
        __syncthreads();
        // Kt from dk/ok token-major
        {
            int jl = tid >> 2, c0 = (tid & 3) * 8;
            int jg = jc + jl;
            bf16x8 pk = {0,0,0,0,0,0,0,0};
            if (jg < DI_N)
                pk = *reinterpret_cast<const bf16x8*>(
                    dkS + ((size_t)b * DI_N + jg) * 128 + n * 32 + c0);
            else if (jg < CAT_N)
                pk = *reinterpret_cast<const bf16x8*>(
                    okS + ((size_t)b * OI_N + t * 84 + (jg - DI_N)) * 128 + n * 32 + c0);
            *reinterpret_cast<bf16x8*>(&Kt[jl * 40 + c0]) = pk;
        }
        // Vs from dva/ov channel-major
        {
            int c = tid >> 3, j0 = (tid & 7) * 8;
            int jg0 = jc + j0;
            const short* dvaRow = dvaS + ((size_t)b * FF_N + n * 32 + c) * DI_N;
            const short* ovRow = ovS + ((size_t)b * FF_N + n * 32 + c) * OI_N + t * 84;
            bf16x8 pk;
            if (jg0 + 8 <= DI_N) {
                pk = *reinterpret_cast<const bf16x8*>(dvaRow + jg0);
            } else if (jg0 >= DI_N && jg0 + 8 <= CAT_N) {
                short4 lo = *reinterpret_cast<const short4*>(ovRow + (jg0 - DI_N));
                short4 hi = *reinterpret_cast<const short4*>(ovRow + (jg0 - DI_N) + 4);
                pk[0]=lo.x; pk[1]=lo.y; pk[2]=lo.z; pk[3]=lo.w;
                pk[4]=hi.x; pk[5]=hi.y; pk[6]=hi.z; pk[7]=hi.w;
            } else {
                #pragma unroll
                for (int p = 0; p < 8; ++p) {
                    int jg = jg0 + p;
                    pk[p] = (jg < DI_N) ? dvaRow[jg]
                          : ((jg < CAT_N) ? ovRow[jg - DI_N] : (short)0);
                }
            }
            *reinterpret_cast<bf16x8*>(&Vs[c * 72 + j0]) = pk;
        }
        __syncthreads();

        f32x4 s[6];
        bf16x8 afr = *reinterpret_cast<const bf16x8*>(&Kt[(wv * 16 + l15) * 40 + q * 8]);
        #pragma unroll
        for (int nt = 0; nt < 6; ++nt) {
            bf16x8 bfr = *reinterpret_cast<const bf16x8*>(&Qt[(nt * 16 + l15) * 40 + q * 8]);
            f32x4 z = {};
            s[nt] = __builtin_amdgcn_mfma_f32_16x16x32_bf16(afr, bfr, z, 0, 0, 0);
        }
        float inv[4];
        #pragma unroll
        for (int r = 0; r < 4; ++r) {
            if (l15 >= 4) s[5][r] = -3.0e38f;
            float m2 = s[0][r];
            #pragma unroll
            for (int nt2 = 1; nt2 < 6; ++nt2) m2 = fmaxf(m2, s[nt2][r]);
            #pragma unroll
            for (int o = 1; o < 16; o <<= 1) m2 = fmaxf(m2, __shfl_xor(m2, o));
            float sm = 0.f;
            #pragma unroll
            for (int nt2 = 0; nt2 < 6; ++nt2) { float e = __expf(s[nt2][r] - m2); s[nt2][r] = e; sm += e; }
            #pragma unroll
            for (int o = 1; o < 16; o <<= 1) sm += __shfl_xor(sm, o);
            inv[r] = 1.f / sm;
        }
        #pragma unroll
        for (int nt = 0; nt < 6; ++nt) {
            short4 pk4;
            pk4.x = f2bf(s[nt][0] * inv[0]);
            pk4.y = f2bf(s[nt][1] * inv[1]);
            pk4.z = f2bf(s[nt][2] * inv[2]);
            pk4.w = f2bf(s[nt][3] * inv[3]);
            *reinterpret_cast<short4*>(&Pt[(nt * 16 + l15) * 72 + wv * 16 + q * 4]) = pk4;
        }
        __syncthreads();

        #pragma unroll
        for (int kk = 0; kk < 2; ++kk) {
            bf16x8 va = *reinterpret_cast<const bf16x8*>(&Vs[(pv_mt * 16 + l15) * 72 + kk * 32 + q * 8]);
            #pragma unroll
            for (int u = 0; u < 3; ++u) {
                int nt = pv_nb + u * 2;
                bf16x8 pb = *reinterpret_cast<const bf16x8*>(&Pt[(nt * 16 + l15) * 72 + kk * 32 + q * 8]);
                oacc[u] = __builtin_amdgcn_mfma_f32_16x16x32_bf16(va, pb, oacc[u], 0, 0, 0);
            }
        }
    }

    // epilogue: ova token-major bf16 [(b,t)][i][128]
    #pragma unroll
    for (int u = 0; u < 3; ++u) {
        int i = (pv_nb + u * 2) * 16 + l15;
        if (i < HW_N) {
            short4 st;
            st.x = f2bf(oacc[u][0]); st.y = f2bf(oacc[u][1]);
            st.z = f2bf(oacc[u][2]); st.w = f2bf(oacc[u][3]);
            *reinterpret_cast<short4*>(
                ovaS + (((size_t)b * OT_N + t) * 84 + i) * 128 + n * 32 + pv_mt * 16 + q * 4) = st;
        }
    }
}

// ---------------- output projection, bf16 MFMA + ReLU + residual ----------------
__global__ __launch_bounds__(256) void outproj_mfma_kernel(
    float* __restrict__ x, const short* __restrict__ ws, int layer)
{
    __shared__ short As[4096];  // [(kc*128 + m)*8]
    __shared__ short Bs[3072];  // [(kc*96 + n)*8]

    const int bid = blockIdx.x;
    const int b = bid >> 7, rem = bid & 127, t = rem >> 2, mt = rem & 3;
    const int o0 = mt * 128;
    const short* WoS = ws + SW_OWO + layer * 65536 + (size_t)o0 * FF_N;
    const short* ovaS = ws + S_OVA + (((size_t)b * OT_N + t) * 84) * 128;

    const int tid = threadIdx.x;
    const int lane = tid & 63, wv = tid >> 6;
    const int l15 = lane & 15, q = lane >> 4;

    f32x4 acc[2][6] = {};

    for (int k0 = 0; k0 < FF_N; k0 += 32) {
        __syncthreads();
        #pragma unroll
        for (int h = 0; h < 2; ++h) {
            int c = tid + h * 256;
            int kc = c & 3, m = c >> 2;
            bf16x8 pk = *reinterpret_cast<const bf16x8*>(WoS + (size_t)m * FF_N + k0 + kc * 8);
            *reinterpret_cast<bf16x8*>(&As[(kc * 128 + m) * 8]) = pk;
        }
        for (int c = tid; c < 384; c += 256) {
            int n2 = c % 96, kc = c / 96;
            bf16x8 pk = {0,0,0,0,0,0,0,0};
            if (n2 < HW_N)
                pk = *reinterpret_cast<const bf16x8*>(ovaS + (size_t)n2 * 128 + k0 + kc * 8);
            *reinterpret_cast<bf16x8*>(&Bs[(kc * 96 + n2) * 8]) = pk;
        }
        __syncthreads();

        bf16x8 af[2];
        #pragma unroll
        for (int mt2 = 0; mt2 < 2; ++mt2)
            af[mt2] = *reinterpret_cast<const bf16x8*>(
                &As[(q * 128 + wv * 32 + mt2 * 16 + l15) * 8]);
        #pragma unroll
        for (int nt = 0; nt < 6; ++nt) {
            bf16x8 bf = *reinterpret_cast<const bf16x8*>(&Bs[(q * 96 + nt * 16 + l15) * 8]);
            #pragma unroll
            for (int mt2 = 0; mt2 < 2; ++mt2)
                acc[mt2][nt] = __builtin_amdgcn_mfma_f32_16x16x32_bf16(
                    af[mt2], bf, acc[mt2][nt], 0, 0, 0);
        }
    }

    #pragma unroll
    for (int mt2 = 0; mt2 < 2; ++mt2) {
        #pragma unroll
        for (int nt = 0; nt < 6; ++nt) {
            int i = nt * 16 + l15;
            if (i < HW_N) {
                #pragma unroll
                for (int r = 0; r < 4; ++r) {
                    int o = o0 + wv * 32 + mt2 * 16 + q * 4 + r;
                    size_t addr = ((size_t)b * D_N + o) * THW_N + (size_t)(DT_N + t) * HW_N + i;
                    float val = acc[mt2][nt][r];
                    x[addr] += (val > 0.f ? val : 0.f);
                }
            }
        }
    }
}

// ---------------- BatchNorm ----------------
__global__ __launch_bounds__(256) void bn_stats_kernel(
    const float* __restrict__ x, float* __restrict__ stats)
{
    const int c = blockIdx.x;
    const int tid = threadIdx.x;
    float s = 0.f, ss = 0.f;
    for (int idx = tid; idx < B_N * THW_N; idx += 256) {
        int b = idx / THW_N, p = idx - b * THW_N;
        float v = x[((size_t)b * D_N + c) * THW_N + p];
        s += v; ss += v * v;
    }
    #pragma unroll
    for (int o = 32; o > 0; o >>= 1) { s += __shfl_down(s, o); ss += __shfl_down(ss, o); }
    __shared__ float red[8];
    int wave = tid >> 6;
    if ((tid & 63) == 0) { red[wave] = s; red[4 + wave] = ss; }
    __syncthreads();
    if (tid == 0) {
        float st = red[0] + red[1] + red[2] + red[3];
        float sst = red[4] + red[5] + red[6] + red[7];
        const float invN = 1.f / (float)(B_N * THW_N);
        float mean = st * invN;
        float var = sst * invN - mean * mean;
        stats[c] = mean;
        stats[512 + c] = rsqrtf(var + BN_EPS);
    }
}

__global__ __launch_bounds__(256) void bn_apply_kernel(
    float* __restrict__ x, const float* __restrict__ stats,
    const float* __restrict__ gamma, const float* __restrict__ beta)
{
    int idx = blockIdx.x * 256 + threadIdx.x;
    float4* x4 = (float4*)x;
    int c = (idx / 756) & 511;
    float mean = stats[c], rs = stats[512 + c];
    float g = gamma[c], bb = beta[c];
    float4 v = x4[idx];
    v.x = g * (v.x - mean) * rs + bb;
    v.y = g * (v.y - mean) * rs + bb;
    v.z = g * (v.z - mean) * rs + bb;
    v.w = g * (v.w - mean) * rs + bb;
    x4[idx] = v;
}

// ---------------- launch ----------------
extern "C" void kernel_launch(void* const* d_in, const int* in_sizes, int n_in,
                              void* d_out, int out_size, void* d_ws, size_t ws_size,
                              hipStream_t stream)
{
    const float* inp  = (const float*)d_in[0];
    const float* dwq  = (const float*)d_in[1];
    const float* dwk  = (const float*)d_in[2];
    const float* dwv  = (const float*)d_in[3];
    const float* owq  = (const float*)d_in[5];
    const float* owk  = (const float*)d_in[6];
    const float* owv  = (const float*)d_in[7];
    const float* owo  = (const float*)d_in[8];
    const float* gam  = (const float*)d_in[9];
    const float* bet  = (const float*)d_in[10];
    float* x  = (float*)d_out;
    float* stats = (float*)d_ws;
    short* wsS = (short*)(stats + 1024);

    cvt_w_kernel<<<448, 256, 0, stream>>>(dwq, dwk, dwv, owq, owk, owv, owo, wsS);

    hipMemcpyAsync(x, inp, (size_t)B_N * D_N * THW_N * sizeof(float),
                   hipMemcpyDeviceToDevice, stream);

    for (int layer = 0; layer < 2; ++layer) {
        size_t coff = (size_t)layer * D_N;
        proj_mfma_kernel<<<504, 256, 0, stream>>>(x, wsS, layer);
        demo_attn_mfma_kernel<<<128, 128, 0, stream>>>(wsS);
        obs_attn_mfma_kernel<<<1024, 256, 0, stream>>>(wsS);
        outproj_mfma_kernel<<<1024, 256, 0, stream>>>(x, wsS, layer);
        bn_stats_kernel<<<512, 256, 0, stream>>>(x, stats);
        bn_apply_kernel<<<12096, 256, 0, stream>>>(x, stats, gam + coff, bet + coff);
    }
    (void)in_sizes; (void)n_in; (void)out_size; (void)ws_size;
}

// Round 7
// 467.751 us; speedup vs baseline: 2.5535x; 1.0023x over previous
//
#include <hip/hip_runtime.h>

// ---------------- problem constants ----------------
#define B_N 8
#define D_N 512
#define T_N 36
#define HW_N 84
#define THW_N 3024
#define DT_N 4
#define OT_N 32
#define NH_N 4
#define FF_N 128
#define CH_N 32
#define DI_N 336      // demo tokens 4*84
#define OI_N 2688     // obs tokens 32*84
#define CAT_N 420
#define INV_TEMP 0.04419417382415922f   // 1/sqrt(512)
#define BN_EPS 1e-5f

// workspace: float stats[1024] at base, then bf16 (short) arena at +4096B.
#define SW_DWQ 0
#define SW_DWK 131072
#define SW_DWV 262144
#define SW_OWQ 393216
#define SW_OWK 524288
#define SW_OWV 655360
#define SW_OWO 786432
#define S_DQ   917504     // [b][336][128] token-major (INV_TEMP folded)
#define S_DK   1261568    // [b][336][128] token-major
#define S_DV   1605632    // [b][128][336] channel-major
#define S_DVA  1949696    // [b][128][336] channel-major
#define S_OQ   2293760    // [b][2688][128] token-major (INV_TEMP folded)
#define S_OK   5046272    // [b][2688][128] token-major
#define S_OV   7798784    // [b][128][2688] channel-major
#define S_OVA  10551296   // [b][32][84][128] token-major
#define S_XBF  13303808   // [b][3024][512] token-major bf16 copy of x

typedef short bf16x8 __attribute__((ext_vector_type(8)));   // 8 bf16 in 4 VGPRs
typedef float f32x4 __attribute__((ext_vector_type(4)));

__device__ __forceinline__ short f2bf(float f) {
    unsigned u = __float_as_uint(f);
    u += 0x7fffu + ((u >> 16) & 1u);          // round-to-nearest-even
    return (short)(u >> 16);
}

// ---------------- weight conversion (once per launch) ----------------
__global__ __launch_bounds__(256) void cvt_w_kernel(
    const float* __restrict__ s0, const float* __restrict__ s1,
    const float* __restrict__ s2, const float* __restrict__ s3,
    const float* __restrict__ s4, const float* __restrict__ s5,
    const float* __restrict__ s6, short* __restrict__ dst)
{
    const int bid = blockIdx.x;
    const int a = bid >> 6, blk = bid & 63;
    const float* src;
    switch (a) {
        case 0: src = s0; break; case 1: src = s1; break;
        case 2: src = s2; break; case 3: src = s3; break;
        case 4: src = s4; break; case 5: src = s5; break;
        default: src = s6;
    }
    const int idx = (blk * 256 + (int)threadIdx.x) * 8;
    float4 f0 = *reinterpret_cast<const float4*>(src + idx);
    float4 f1 = *reinterpret_cast<const float4*>(src + idx + 4);
    bf16x8 pk;
    pk[0] = f2bf(f0.x); pk[1] = f2bf(f0.y); pk[2] = f2bf(f0.z); pk[3] = f2bf(f0.w);
    pk[4] = f2bf(f1.x); pk[5] = f2bf(f1.y); pk[6] = f2bf(f1.z); pk[7] = f2bf(f1.w);
    *reinterpret_cast<bf16x8*>(dst + (size_t)a * 131072 + idx) = pk;
}

// ---------------- x staging: copy/BN fp32 x + emit bf16 token-major copy ----
// mode 0: out_f = in_f (copy), emit xbf.  mode 1: out_f = BN(in_f), emit xbf.
// mode 2: out_f = BN(in_f) only.
// Tile: 48 tokens x 64 channels; grid = 8b * 63 tokTiles * 8 cTiles = 4032.
__global__ __launch_bounds__(256) void x_stage_kernel(
    const float* __restrict__ in_f, float* __restrict__ out_f,
    short* __restrict__ xbf, const float* __restrict__ stats,
    const float* __restrict__ gamma, const float* __restrict__ beta, int mode)
{
    __shared__ short tile[48][65];

    const int bid = blockIdx.x;
    const int b = bid / 504, rem = bid % 504, tt = rem >> 3, cblk = rem & 7;
    const int t0 = tt * 48, c0 = cblk * 64;
    const int tid = threadIdx.x;

    #pragma unroll
    for (int l0 = 0; l0 < 768; l0 += 256) {
        int l = l0 + tid;
        int cc = l / 12, tg = l % 12;
        int c = c0 + cc;
        size_t addr = ((size_t)b * D_N + c) * THW_N + t0 + tg * 4;
        float4 v = *reinterpret_cast<const float4*>(in_f + addr);
        if (mode != 0) {
            float mean = stats[c], rs = stats[512 + c];
            float g = gamma[c], bb = beta[c];
            v.x = g * (v.x - mean) * rs + bb;
            v.y = g * (v.y - mean) * rs + bb;
            v.z = g * (v.z - mean) * rs + bb;
            v.w = g * (v.w - mean) * rs + bb;
        }
        *reinterpret_cast<float4*>(out_f + addr) = v;
        tile[tg * 4 + 0][cc] = f2bf(v.x);
        tile[tg * 4 + 1][cc] = f2bf(v.y);
        tile[tg * 4 + 2][cc] = f2bf(v.z);
        tile[tg * 4 + 3][cc] = f2bf(v.w);
    }
    if (mode == 2) return;
    __syncthreads();
    #pragma unroll
    for (int l0 = 0; l0 < 768; l0 += 256) {
        int l = l0 + tid;
        int tk = l >> 4, cg = l & 15;
        short4 s4;
        s4.x = tile[tk][cg * 4 + 0];
        s4.y = tile[tk][cg * 4 + 1];
        s4.z = tile[tk][cg * 4 + 2];
        s4.w = tile[tk][cg * 4 + 3];
        *reinterpret_cast<short4*>(
            xbf + ((size_t)b * THW_N + t0 + tk) * 512 + c0 + cg * 4) = s4;
    }
}

// ---------------- fused QKV projection, bf16 MFMA ----------------
// q/k outputs token-major bf16 (q scaled by INV_TEMP); v channel-major bf16.
// X input: xbf token-major bf16 (pre-converted).
__global__ __launch_bounds__(256) void proj_mfma_kernel(
    const short* __restrict__ xbf, short* __restrict__ ws, int layer)
{
    __shared__ short As[3][4096];   // [wt][(kc*128 + m)*8]
    __shared__ short Bs[1536];      // [(kc*48 + n)*8]

    const int bid = blockIdx.x;
    const int b = bid / 63, ct = bid - b * 63;
    const bool is_demo = (ct < 7);
    const int woff = layer * 65536;
    const short* W0 = ws + (is_demo ? SW_DWQ : SW_OWQ) + woff;
    const short* W1 = ws + (is_demo ? SW_DWK : SW_OWK) + woff;
    const short* W2 = ws + (is_demo ? SW_DWV : SW_OWV) + woff;
    const int Ltok = is_demo ? DI_N : OI_N;
    const int colL = is_demo ? ct * 48 : (ct - 7) * 48;
    short* Yq = ws + (is_demo ? S_DQ : S_OQ);
    short* Yk = ws + (is_demo ? S_DK : S_OK);
    short* Yv = ws + (is_demo ? S_DV : S_OV);
    const short* Xb = xbf + ((size_t)b * THW_N + ct * 48) * 512;

    const int tid = threadIdx.x;
    const int lane = tid & 63, wv = tid >> 6;
    const int l15 = lane & 15, q = lane >> 4;

    f32x4 acc[3][2][3] = {};

    for (int k0 = 0; k0 < D_N; k0 += 32) {
        __syncthreads();
        const short* Wt[3] = {W0, W1, W2};
        #pragma unroll
        for (int wt = 0; wt < 3; ++wt) {
            #pragma unroll
            for (int h = 0; h < 2; ++h) {
                int c = tid + h * 256;
                int kc = c & 3, m = c >> 2;
                bf16x8 pk = *reinterpret_cast<const bf16x8*>(
                    Wt[wt] + (size_t)m * D_N + k0 + kc * 8);
                *reinterpret_cast<bf16x8*>(&As[wt][(kc * 128 + m) * 8]) = pk;
            }
        }
        if (tid < 192) {
            int n = tid % 48, kc = tid / 48;
            bf16x8 pk = *reinterpret_cast<const bf16x8*>(
                Xb + (size_t)n * 512 + k0 + kc * 8);
            *reinterpret_cast<bf16x8*>(&Bs[(kc * 48 + n) * 8]) = pk;
        }
        __syncthreads();

        bf16x8 bfr[3];
        #pragma unroll
        for (int nt = 0; nt < 3; ++nt)
            bfr[nt] = *reinterpret_cast<const bf16x8*>(&Bs[(q * 48 + nt * 16 + l15) * 8]);
        #pragma unroll
        for (int wt = 0; wt < 3; ++wt) {
            #pragma unroll
            for (int mt2 = 0; mt2 < 2; ++mt2) {
                bf16x8 afr = *reinterpret_cast<const bf16x8*>(
                    &As[wt][(q * 128 + wv * 32 + mt2 * 16 + l15) * 8]);
                #pragma unroll
                for (int nt = 0; nt < 3; ++nt)
                    acc[wt][mt2][nt] = __builtin_amdgcn_mfma_f32_16x16x32_bf16(
                        afr, bfr[nt], acc[wt][mt2][nt], 0, 0, 0);
            }
        }
    }

    #pragma unroll
    for (int mt2 = 0; mt2 < 2; ++mt2) {
        int mrow = wv * 32 + mt2 * 16 + q * 4;
        #pragma unroll
        for (int nt = 0; nt < 3; ++nt) {
            int token = colL + nt * 16 + l15;
            f32x4 aq = acc[0][mt2][nt] * INV_TEMP;
            short4 s4;
            s4.x = f2bf(aq[0]); s4.y = f2bf(aq[1]); s4.z = f2bf(aq[2]); s4.w = f2bf(aq[3]);
            *reinterpret_cast<short4*>(Yq + ((size_t)b * Ltok + token) * 128 + mrow) = s4;
            f32x4 ak = acc[1][mt2][nt];
            s4.x = f2bf(ak[0]); s4.y = f2bf(ak[1]); s4.z = f2bf(ak[2]); s4.w = f2bf(ak[3]);
            *reinterpret_cast<short4*>(Yk + ((size_t)b * Ltok + token) * 128 + mrow) = s4;
            #pragma unroll
            for (int r = 0; r < 4; ++r)
                Yv[((size_t)b * FF_N + mrow + r) * Ltok + token] = f2bf(acc[2][mt2][nt][r]);
        }
    }
}

// ---------------- demo attention, bf16 MFMA flash-style ----------------
__global__ __launch_bounds__(128) void demo_attn_mfma_kernel(const short* __restrict__ ws)
{
    __shared__ short Qt[96 * 40];
    __shared__ short Kt[96 * 40];
    __shared__ short Vs[32 * 104];
    __shared__ short Pt[96 * 104];
    __shared__ float alpha_s[96];
    __shared__ float l_s[96];

    const short* dqS = ws + S_DQ;
    const short* dkS = ws + S_DK;
    const short* dvS = ws + S_DV;
    short* dvaS = const_cast<short*>(ws) + S_DVA;

    const int bid = blockIdx.x;
    const int ti = bid & 3, pn = bid >> 2;
    const int b = pn >> 2, n = pn & 3;

    const int tid = threadIdx.x;
    const int lane = tid & 63, wv = tid >> 6;
    const int l15 = lane & 15, q = lane >> 4;

    for (int u = tid; u < 384; u += 128) {
        int i = u >> 2, c0 = (u & 3) * 8;
        bf16x8 pk = {0,0,0,0,0,0,0,0};
        if (i < 84)
            pk = *reinterpret_cast<const bf16x8*>(
                dkS + ((size_t)b * DI_N + ti * 84 + i) * 128 + n * 32 + c0);
        *reinterpret_cast<bf16x8*>(&Qt[i * 40 + c0]) = pk;
    }
    if (tid < 96) l_s[tid] = 0.f;

    float m_r[3][4];
    #pragma unroll
    for (int mt = 0; mt < 3; ++mt)
        #pragma unroll
        for (int r = 0; r < 4; ++r) m_r[mt][r] = -3.0e38f;

    f32x4 oacc[6] = {};

    for (int cj = 0; cj <= ti; ++cj) {
        __syncthreads();
        for (int u = tid; u < 384; u += 128) {
            int j = u >> 2, c0 = (u & 3) * 8;
            bf16x8 pk = {0,0,0,0,0,0,0,0};
            if (j < 84)
                pk = *reinterpret_cast<const bf16x8*>(
                    dqS + ((size_t)b * DI_N + cj * 84 + j) * 128 + n * 32 + c0);
            *reinterpret_cast<bf16x8*>(&Kt[j * 40 + c0]) = pk;
        }
        for (int u = tid; u < 384; u += 128) {
            int c = u / 12, j0 = (u % 12) * 8;
            const short* row = dvS + ((size_t)b * FF_N + n * 32 + c) * DI_N + cj * 84;
            bf16x8 pk;
            if (j0 + 8 <= 84) {
                short4 lo = *reinterpret_cast<const short4*>(row + j0);
                short4 hi = *reinterpret_cast<const short4*>(row + j0 + 4);
                pk[0]=lo.x; pk[1]=lo.y; pk[2]=lo.z; pk[3]=lo.w;
                pk[4]=hi.x; pk[5]=hi.y; pk[6]=hi.z; pk[7]=hi.w;
            } else {
                #pragma unroll
                for (int p = 0; p < 8; ++p) {
                    int j = j0 + p;
                    pk[p] = (j < 84) ? row[j] : (short)0;
                }
            }
            *reinterpret_cast<bf16x8*>(&Vs[c * 104 + j0]) = pk;
        }
        __syncthreads();

        #pragma unroll
        for (int mt = 0; mt < 3; ++mt) {
            int mrow = (wv * 3 + mt) * 16;
            bf16x8 afr = *reinterpret_cast<const bf16x8*>(&Qt[(mrow + l15) * 40 + q * 8]);
            f32x4 s[6];
            #pragma unroll
            for (int nt = 0; nt < 6; ++nt) {
                bf16x8 bfr = *reinterpret_cast<const bf16x8*>(&Kt[(nt * 16 + l15) * 40 + q * 8]);
                f32x4 z = {};
                s[nt] = __builtin_amdgcn_mfma_f32_16x16x32_bf16(afr, bfr, z, 0, 0, 0);
            }
            #pragma unroll
            for (int r = 0; r < 4; ++r) {
                if (l15 >= 4) s[5][r] = -3.0e38f;
                float mx = s[0][r];
                #pragma unroll
                for (int nt = 1; nt < 6; ++nt) mx = fmaxf(mx, s[nt][r]);
                #pragma unroll
                for (int o = 1; o < 16; o <<= 1) mx = fmaxf(mx, __shfl_xor(mx, o));
                float mnew = fmaxf(m_r[mt][r], mx);
                float al = __expf(m_r[mt][r] - mnew);
                m_r[mt][r] = mnew;
                float sm = 0.f;
                #pragma unroll
                for (int nt = 0; nt < 6; ++nt) {
                    float e = __expf(s[nt][r] - mnew);
                    s[nt][r] = e; sm += e;
                }
                #pragma unroll
                for (int o = 1; o < 16; o <<= 1) sm += __shfl_xor(sm, o);
                int i = mrow + q * 4 + r;
                if (l15 == 0) { alpha_s[i] = al; l_s[i] = l_s[i] * al + sm; }
            }
            #pragma unroll
            for (int nt = 0; nt < 6; ++nt)
                #pragma unroll
                for (int r = 0; r < 4; ++r)
                    Pt[(mrow + q * 4 + r) * 104 + nt * 16 + l15] = f2bf(s[nt][r]);
        }
        __syncthreads();

        #pragma unroll
        for (int nt = 0; nt < 6; ++nt) {
            float al = alpha_s[nt * 16 + l15];
            #pragma unroll
            for (int r = 0; r < 4; ++r) oacc[nt][r] *= al;
        }
        #pragma unroll
        for (int kk = 0; kk < 3; ++kk) {
            bf16x8 va = *reinterpret_cast<const bf16x8*>(&Vs[(wv * 16 + l15) * 104 + kk * 32 + q * 8]);
            #pragma unroll
            for (int nt = 0; nt < 6; ++nt) {
                bf16x8 pb = *reinterpret_cast<const bf16x8*>(&Pt[(nt * 16 + l15) * 104 + kk * 32 + q * 8]);
                oacc[nt] = __builtin_amdgcn_mfma_f32_16x16x32_bf16(va, pb, oacc[nt], 0, 0, 0);
            }
        }
    }

    #pragma unroll
    for (int nt = 0; nt < 6; ++nt) {
        int il = nt * 16 + l15;
        if (il < 84) {
            float inv = 1.f / l_s[il];
            int ig = ti * 84 + il;
            #pragma unroll
            for (int r = 0; r < 4; ++r)
                dvaS[((size_t)b * FF_N + n * 32 + wv * 16 + q * 4 + r) * DI_N + ig] =
                    f2bf(oacc[nt][r] * inv);
        }
    }
}

// ---------------- obs attention, bf16 MFMA ----------------
__global__ __launch_bounds__(256, 4) void obs_attn_mfma_kernel(const short* __restrict__ ws)
{
    __shared__ short Qt[96 * 40];
    __shared__ short Kt[64 * 40];
    __shared__ short Vs[32 * 72];
    __shared__ short Pt[96 * 72];

    const short* dkS = ws + S_DK;
    const short* dvaS = ws + S_DVA;
    const short* oqS = ws + S_OQ;
    const short* okS = ws + S_OK;
    const short* ovS = ws + S_OV;
    short* ovaS = const_cast<short*>(ws) + S_OVA;

    const int bid = blockIdx.x;
    const int b = bid >> 7, rem = bid & 127, t = rem >> 2, n = rem & 3;

    const int tid = threadIdx.x;
    const int lane = tid & 63, wv = tid >> 6;
    const int l15 = lane & 15, q = lane >> 4;

    for (int l = tid; l < 384; l += 256) {
        int i = l >> 2, c0 = (l & 3) * 8;
        bf16x8 pk = {0,0,0,0,0,0,0,0};
        if (i < HW_N)
            pk = *reinterpret_cast<const bf16x8*>(
                oqS + ((size_t)b * OI_N + t * 84 + i) * 128 + n * 32 + c0);
        *reinterpret_cast<bf16x8*>(&Qt[i * 40 + c0]) = pk;
    }

    const int pv_mt = wv & 1;
    const int pv_nb = wv >> 1;
    f32x4 oacc[3] = {};

    for (int jc = 0; jc < 448; jc += 64) {
        __syncthreads();
        {
            int jl = tid >> 2, c0 = (tid & 3) * 8;
            int jg = jc + jl;
            bf16x8 pk = {0,0,0,0,0,0,0,0};
            if (jg < DI_N)
                pk = *reinterpret_cast<const bf16x8*>(
                    dkS + ((size_t)b * DI_N + jg) * 128 + n * 32 + c0);
            else if (jg < CAT_N)
                pk = *reinterpret_cast<const bf16x8*>(
                    okS + ((size_t)b * OI_N + t * 84 + (jg - DI_N)) * 128 + n * 32 + c0);
            *reinterpret_cast<bf16x8*>(&Kt[jl * 40 + c0]) = pk;
        }
        {
            int c = tid >> 3, j0 = (tid & 7) * 8;
            int jg0 = jc + j0;
            const short* dvaRow = dvaS + ((size_t)b * FF_N + n * 32 + c) * DI_N;
            const short* ovRow = ovS + ((size_t)b * FF_N + n * 32 + c) * OI_N + t * 84;
            bf16x8 pk;
            if (jg0 + 8 <= DI_N) {
                pk = *reinterpret_cast<const bf16x8*>(dvaRow + jg0);
            } else if (jg0 >= DI_N && jg0 + 8 <= CAT_N) {
                short4 lo = *reinterpret_cast<const short4*>(ovRow + (jg0 - DI_N));
                short4 hi = *reinterpret_cast<const short4*>(ovRow + (jg0 - DI_N) + 4);
                pk[0]=lo.x; pk[1]=lo.y; pk[2]=lo.z; pk[3]=lo.w;
                pk[4]=hi.x; pk[5]=hi.y; pk[6]=hi.z; pk[7]=hi.w;
            } else {
                #pragma unroll
                for (int p = 0; p < 8; ++p) {
                    int jg = jg0 + p;
                    pk[p] = (jg < DI_N) ? dvaRow[jg]
                          : ((jg < CAT_N) ? ovRow[jg - DI_N] : (short)0);
                }
            }
            *reinterpret_cast<bf16x8*>(&Vs[c * 72 + j0]) = pk;
        }
        __syncthreads();

        f32x4 s[6];
        bf16x8 afr = *reinterpret_cast<const bf16x8*>(&Kt[(wv * 16 + l15) * 40 + q * 8]);
        #pragma unroll
        for (int nt = 0; nt < 6; ++nt) {
            bf16x8 bfr = *reinterpret_cast<const bf16x8*>(&Qt[(nt * 16 + l15) * 40 + q * 8]);
            f32x4 z = {};
            s[nt] = __builtin_amdgcn_mfma_f32_16x16x32_bf16(afr, bfr, z, 0, 0, 0);
        }
        float inv[4];
        #pragma unroll
        for (int r = 0; r < 4; ++r) {
            if (l15 >= 4) s[5][r] = -3.0e38f;
            float m2 = s[0][r];
            #pragma unroll
            for (int nt2 = 1; nt2 < 6; ++nt2) m2 = fmaxf(m2, s[nt2][r]);
            #pragma unroll
            for (int o = 1; o < 16; o <<= 1) m2 = fmaxf(m2, __shfl_xor(m2, o));
            float sm = 0.f;
            #pragma unroll
            for (int nt2 = 0; nt2 < 6; ++nt2) { float e = __expf(s[nt2][r] - m2); s[nt2][r] = e; sm += e; }
            #pragma unroll
            for (int o = 1; o < 16; o <<= 1) sm += __shfl_xor(sm, o);
            inv[r] = 1.f / sm;
        }
        #pragma unroll
        for (int nt = 0; nt < 6; ++nt) {
            short4 pk4;
            pk4.x = f2bf(s[nt][0] * inv[0]);
            pk4.y = f2bf(s[nt][1] * inv[1]);
            pk4.z = f2bf(s[nt][2] * inv[2]);
            pk4.w = f2bf(s[nt][3] * inv[3]);
            *reinterpret_cast<short4*>(&Pt[(nt * 16 + l15) * 72 + wv * 16 + q * 4]) = pk4;
        }
        __syncthreads();

        #pragma unroll
        for (int kk = 0; kk < 2; ++kk) {
            bf16x8 va = *reinterpret_cast<const bf16x8*>(&Vs[(pv_mt * 16 + l15) * 72 + kk * 32 + q * 8]);
            #pragma unroll
            for (int u = 0; u < 3; ++u) {
                int nt = pv_nb + u * 2;
                bf16x8 pb = *reinterpret_cast<const bf16x8*>(&Pt[(nt * 16 + l15) * 72 + kk * 32 + q * 8]);
                oacc[u] = __builtin_amdgcn_mfma_f32_16x16x32_bf16(va, pb, oacc[u], 0, 0, 0);
            }
        }
    }

    #pragma unroll
    for (int u = 0; u < 3; ++u) {
        int i = (pv_nb + u * 2) * 16 + l15;
        if (i < HW_N) {
            short4 st;
            st.x = f2bf(oacc[u][0]); st.y = f2bf(oacc[u][1]);
            st.z = f2bf(oacc[u][2]); st.w = f2bf(oacc[u][3]);
            *reinterpret_cast<short4*>(
                ovaS + (((size_t)b * OT_N + t) * 84 + i) * 128 + n * 32 + pv_mt * 16 + q * 4) = st;
        }
    }
}

// ---------------- output projection, bf16 MFMA + ReLU + residual ----------------
__global__ __launch_bounds__(256) void outproj_mfma_kernel(
    float* __restrict__ x, const short* __restrict__ ws, int layer)
{
    __shared__ short As[4096];
    __shared__ short Bs[3072];

    const int bid = blockIdx.x;
    const int b = bid >> 7, rem = bid & 127, t = rem >> 2, mt = rem & 3;
    const int o0 = mt * 128;
    const short* WoS = ws + SW_OWO + layer * 65536 + (size_t)o0 * FF_N;
    const short* ovaS = ws + S_OVA + (((size_t)b * OT_N + t) * 84) * 128;

    const int tid = threadIdx.x;
    const int lane = tid & 63, wv = tid >> 6;
    const int l15 = lane & 15, q = lane >> 4;

    f32x4 acc[2][6] = {};

    for (int k0 = 0; k0 < FF_N; k0 += 32) {
        __syncthreads();
        #pragma unroll
        for (int h = 0; h < 2; ++h) {
            int c = tid + h * 256;
            int kc = c & 3, m = c >> 2;
            bf16x8 pk = *reinterpret_cast<const bf16x8*>(WoS + (size_t)m * FF_N + k0 + kc * 8);
            *reinterpret_cast<bf16x8*>(&As[(kc * 128 + m) * 8]) = pk;
        }
        for (int c = tid; c < 384; c += 256) {
            int n2 = c % 96, kc = c / 96;
            bf16x8 pk = {0,0,0,0,0,0,0,0};
            if (n2 < HW_N)
                pk = *reinterpret_cast<const bf16x8*>(ovaS + (size_t)n2 * 128 + k0 + kc * 8);
            *reinterpret_cast<bf16x8*>(&Bs[(kc * 96 + n2) * 8]) = pk;
        }
        __syncthreads();

        bf16x8 af[2];
        #pragma unroll
        for (int mt2 = 0; mt2 < 2; ++mt2)
            af[mt2] = *reinterpret_cast<const bf16x8*>(
                &As[(q * 128 + wv * 32 + mt2 * 16 + l15) * 8]);
        #pragma unroll
        for (int nt = 0; nt < 6; ++nt) {
            bf16x8 bf = *reinterpret_cast<const bf16x8*>(&Bs[(q * 96 + nt * 16 + l15) * 8]);
            #pragma unroll
            for (int mt2 = 0; mt2 < 2; ++mt2)
                acc[mt2][nt] = __builtin_amdgcn_mfma_f32_16x16x32_bf16(
                    af[mt2], bf, acc[mt2][nt], 0, 0, 0);
        }
    }

    #pragma unroll
    for (int mt2 = 0; mt2 < 2; ++mt2) {
        #pragma unroll
        for (int nt = 0; nt < 6; ++nt) {
            int i = nt * 16 + l15;
            if (i < HW_N) {
                #pragma unroll
                for (int r = 0; r < 4; ++r) {
                    int o = o0 + wv * 32 + mt2 * 16 + q * 4 + r;
                    size_t addr = ((size_t)b * D_N + o) * THW_N + (size_t)(DT_N + t) * HW_N + i;
                    float val = acc[mt2][nt][r];
                    x[addr] += (val > 0.f ? val : 0.f);
                }
            }
        }
    }
}

// ---------------- BatchNorm stats ----------------
__global__ __launch_bounds__(256) void bn_stats_kernel(
    const float* __restrict__ x, float* __restrict__ stats)
{
    const int c = blockIdx.x;
    const int tid = threadIdx.x;
    float s = 0.f, ss = 0.f;
    for (int idx = tid; idx < B_N * THW_N; idx += 256) {
        int b = idx / THW_N, p = idx - b * THW_N;
        float v = x[((size_t)b * D_N + c) * THW_N + p];
        s += v; ss += v * v;
    }
    #pragma unroll
    for (int o = 32; o > 0; o >>= 1) { s += __shfl_down(s, o); ss += __shfl_down(ss, o); }
    __shared__ float red[8];
    int wave = tid >> 6;
    if ((tid & 63) == 0) { red[wave] = s; red[4 + wave] = ss; }
    __syncthreads();
    if (tid == 0) {
        float st = red[0] + red[1] + red[2] + red[3];
        float sst = red[4] + red[5] + red[6] + red[7];
        const float invN = 1.f / (float)(B_N * THW_N);
        float mean = st * invN;
        float var = sst * invN - mean * mean;
        stats[c] = mean;
        stats[512 + c] = rsqrtf(var + BN_EPS);
    }
}

// ---------------- launch ----------------
extern "C" void kernel_launch(void* const* d_in, const int* in_sizes, int n_in,
                              void* d_out, int out_size, void* d_ws, size_t ws_size,
                              hipStream_t stream)
{
    const float* inp  = (const float*)d_in[0];
    const float* dwq  = (const float*)d_in[1];
    const float* dwk  = (const float*)d_in[2];
    const float* dwv  = (const float*)d_in[3];
    const float* owq  = (const float*)d_in[5];
    const float* owk  = (const float*)d_in[6];
    const float* owv  = (const float*)d_in[7];
    const float* owo  = (const float*)d_in[8];
    const float* gam  = (const float*)d_in[9];
    const float* bet  = (const float*)d_in[10];
    float* x  = (float*)d_out;
    float* stats = (float*)d_ws;
    short* wsS = (short*)(stats + 1024);
    short* xbf = wsS + S_XBF;

    cvt_w_kernel<<<448, 256, 0, stream>>>(dwq, dwk, dwv, owq, owk, owv, owo, wsS);
    // copy inp -> x (fp32) and emit xbf (bf16 token-major)
    x_stage_kernel<<<4032, 256, 0, stream>>>(inp, x, xbf, stats, gam, bet, 0);

    for (int layer = 0; layer < 2; ++layer) {
        size_t coff = (size_t)layer * D_N;
        proj_mfma_kernel<<<504, 256, 0, stream>>>(xbf, wsS, layer);
        demo_attn_mfma_kernel<<<128, 128, 0, stream>>>(wsS);
        obs_attn_mfma_kernel<<<1024, 256, 0, stream>>>(wsS);
        outproj_mfma_kernel<<<1024, 256, 0, stream>>>(x, wsS, layer);
        bn_stats_kernel<<<512, 256, 0, stream>>>(x, stats);
        // BN in place; emit xbf for next layer's proj (skip on last layer)
        x_stage_kernel<<<4032, 256, 0, stream>>>(
            x, x, xbf, stats, gam + coff, bet + coff, layer == 0 ? 1 : 2);
    }
    (void)in_sizes; (void)n_in; (void)out_size; (void)ws_size;
}

// Round 8
// 406.802 us; speedup vs baseline: 2.9361x; 1.1498x over previous
//
#include <hip/hip_runtime.h>

// ---------------- problem constants ----------------
#define B_N 8
#define D_N 512
#define T_N 36
#define HW_N 84
#define THW_N 3024
#define DT_N 4
#define OT_N 32
#define NH_N 4
#define FF_N 128
#define CH_N 32
#define DI_N 336      // demo tokens 4*84
#define OI_N 2688     // obs tokens 32*84
#define CAT_N 420
#define INV_TEMP 0.04419417382415922f   // 1/sqrt(512)
#define BN_EPS 1e-5f
#define INV_CNT (1.0f / 24192.0f)       // 1/(B*THW)

// workspace: float stats[2][1024] at base (sum[512], sumsq[512] per layer),
// then bf16 (short) arena at +8192B.
#define SW_DWQ 0
#define SW_DWK 131072
#define SW_DWV 262144
#define SW_OWQ 393216
#define SW_OWK 524288
#define SW_OWV 655360
#define SW_OWO 786432
#define S_DQ   917504     // [b][336][128] token-major (INV_TEMP folded)
#define S_DK   1261568    // [b][336][128] token-major
#define S_DV   1605632    // [b][128][336] channel-major
#define S_DVA  1949696    // [b][128][336] channel-major
#define S_OQ   2293760    // [b][2688][128] token-major (INV_TEMP folded)
#define S_OK   5046272    // [b][2688][128] token-major
#define S_OV   7798784    // [b][128][2688] channel-major
#define S_OVA  10551296   // [b][32][84][128] token-major
#define S_XBF  13303808   // [b][3024][512] token-major bf16 x

typedef short bf16x8 __attribute__((ext_vector_type(8)));   // 8 bf16 in 4 VGPRs
typedef float f32x4 __attribute__((ext_vector_type(4)));

__device__ __forceinline__ short f2bf(float f) {
    unsigned u = __float_as_uint(f);
    u += 0x7fffu + ((u >> 16) & 1u);          // round-to-nearest-even
    return (short)(u >> 16);
}
__device__ __forceinline__ float bf2f(short s) {
    return __uint_as_float(((unsigned)(unsigned short)s) << 16);
}

// ---------------- weight conversion + stats zero (once per launch) --------
__global__ __launch_bounds__(256) void cvt_w_kernel(
    const float* __restrict__ s0, const float* __restrict__ s1,
    const float* __restrict__ s2, const float* __restrict__ s3,
    const float* __restrict__ s4, const float* __restrict__ s5,
    const float* __restrict__ s6, short* __restrict__ dst,
    float* __restrict__ stats)
{
    const int bid = blockIdx.x;
    if (bid == 0) {   // zero both layers' stats accumulators (2048 floats)
        #pragma unroll
        for (int k = 0; k < 8; ++k) stats[threadIdx.x * 8 + k] = 0.f;
    }
    const int a = bid >> 6, blk = bid & 63;
    const float* src;
    switch (a) {
        case 0: src = s0; break; case 1: src = s1; break;
        case 2: src = s2; break; case 3: src = s3; break;
        case 4: src = s4; break; case 5: src = s5; break;
        default: src = s6;
    }
    const int idx = (blk * 256 + (int)threadIdx.x) * 8;
    float4 f0 = *reinterpret_cast<const float4*>(src + idx);
    float4 f1 = *reinterpret_cast<const float4*>(src + idx + 4);
    bf16x8 pk;
    pk[0] = f2bf(f0.x); pk[1] = f2bf(f0.y); pk[2] = f2bf(f0.z); pk[3] = f2bf(f0.w);
    pk[4] = f2bf(f1.x); pk[5] = f2bf(f1.y); pk[6] = f2bf(f1.z); pk[7] = f2bf(f1.w);
    *reinterpret_cast<bf16x8*>(dst + (size_t)a * 131072 + idx) = pk;
}

// ---------------- input staging: fp32 ch-major -> bf16 token-major -------
// + demo-slice stats atomics (layer 0). Tile 48 tok x 64 ch; demo = tiles tt<7.
__global__ __launch_bounds__(256) void xin_kernel(
    const float* __restrict__ in_f, short* __restrict__ xbf,
    float* __restrict__ stats0)
{
    __shared__ short tile[48][65];
    __shared__ float red_s[16][64];
    __shared__ float red_q[16][64];

    const int bid = blockIdx.x;
    const int b = bid / 504, rem = bid % 504, tt = rem >> 3, cblk = rem & 7;
    const int t0 = tt * 48, c0 = cblk * 64;
    const int tid = threadIdx.x;
    const bool is_demo = (tt < 7);

    #pragma unroll
    for (int l0 = 0; l0 < 768; l0 += 256) {
        int l = l0 + tid;
        int cc = l / 12, tg = l % 12;
        size_t addr = ((size_t)b * D_N + c0 + cc) * THW_N + t0 + tg * 4;
        float4 v = *reinterpret_cast<const float4*>(in_f + addr);
        tile[tg * 4 + 0][cc] = f2bf(v.x);
        tile[tg * 4 + 1][cc] = f2bf(v.y);
        tile[tg * 4 + 2][cc] = f2bf(v.z);
        tile[tg * 4 + 3][cc] = f2bf(v.w);
    }
    __syncthreads();
    float psum[4] = {}, psq[4] = {};
    const int cg = tid & 15;
    #pragma unroll
    for (int l0 = 0; l0 < 768; l0 += 256) {
        int l = l0 + tid;
        int tk = l >> 4;
        short4 s4;
        s4.x = tile[tk][cg * 4 + 0];
        s4.y = tile[tk][cg * 4 + 1];
        s4.z = tile[tk][cg * 4 + 2];
        s4.w = tile[tk][cg * 4 + 3];
        *reinterpret_cast<short4*>(
            xbf + ((size_t)b * THW_N + t0 + tk) * 512 + c0 + cg * 4) = s4;
        if (is_demo) {
            float v0 = bf2f(s4.x), v1 = bf2f(s4.y), v2 = bf2f(s4.z), v3 = bf2f(s4.w);
            psum[0] += v0; psum[1] += v1; psum[2] += v2; psum[3] += v3;
            psq[0] += v0 * v0; psq[1] += v1 * v1; psq[2] += v2 * v2; psq[3] += v3 * v3;
        }
    }
    if (!is_demo) return;
    __syncthreads();
    #pragma unroll
    for (int j = 0; j < 4; ++j) {
        red_s[tid >> 4][cg * 4 + j] = psum[j];
        red_q[tid >> 4][cg * 4 + j] = psq[j];
    }
    __syncthreads();
    if (tid < 64) {
        float s = 0.f, q = 0.f;
        #pragma unroll
        for (int r = 0; r < 16; ++r) { s += red_s[r][tid]; q += red_q[r][tid]; }
        atomicAdd(&stats0[c0 + tid], s);
        atomicAdd(&stats0[512 + c0 + tid], q);
    }
}

// ---------------- fused QKV projection, bf16 MFMA ----------------
__global__ __launch_bounds__(256) void proj_mfma_kernel(
    const short* __restrict__ xbf, short* __restrict__ ws, int layer)
{
    __shared__ short As[3][4096];   // [wt][(kc*128 + m)*8]
    __shared__ short Bs[1536];      // [(kc*48 + n)*8]

    const int bid = blockIdx.x;
    const int b = bid / 63, ct = bid - b * 63;
    const bool is_demo = (ct < 7);
    const int woff = layer * 65536;
    const short* W0 = ws + (is_demo ? SW_DWQ : SW_OWQ) + woff;
    const short* W1 = ws + (is_demo ? SW_DWK : SW_OWK) + woff;
    const short* W2 = ws + (is_demo ? SW_DWV : SW_OWV) + woff;
    const int Ltok = is_demo ? DI_N : OI_N;
    const int colL = is_demo ? ct * 48 : (ct - 7) * 48;
    short* Yq = ws + (is_demo ? S_DQ : S_OQ);
    short* Yk = ws + (is_demo ? S_DK : S_OK);
    short* Yv = ws + (is_demo ? S_DV : S_OV);
    const short* Xb = xbf + ((size_t)b * THW_N + (is_demo ? 0 : DI_N) + colL) * 512;

    const int tid = threadIdx.x;
    const int lane = tid & 63, wv = tid >> 6;
    const int l15 = lane & 15, q = lane >> 4;

    f32x4 acc[3][2][3] = {};

    for (int k0 = 0; k0 < D_N; k0 += 32) {
        __syncthreads();
        const short* Wt[3] = {W0, W1, W2};
        #pragma unroll
        for (int wt = 0; wt < 3; ++wt) {
            #pragma unroll
            for (int h = 0; h < 2; ++h) {
                int c = tid + h * 256;
                int kc = c & 3, m = c >> 2;
                bf16x8 pk = *reinterpret_cast<const bf16x8*>(
                    Wt[wt] + (size_t)m * D_N + k0 + kc * 8);
                *reinterpret_cast<bf16x8*>(&As[wt][(kc * 128 + m) * 8]) = pk;
            }
        }
        if (tid < 192) {
            int n = tid % 48, kc = tid / 48;
            bf16x8 pk = *reinterpret_cast<const bf16x8*>(
                Xb + (size_t)n * 512 + k0 + kc * 8);
            *reinterpret_cast<bf16x8*>(&Bs[(kc * 48 + n) * 8]) = pk;
        }
        __syncthreads();

        bf16x8 bfr[3];
        #pragma unroll
        for (int nt = 0; nt < 3; ++nt)
            bfr[nt] = *reinterpret_cast<const bf16x8*>(&Bs[(q * 48 + nt * 16 + l15) * 8]);
        #pragma unroll
        for (int wt = 0; wt < 3; ++wt) {
            #pragma unroll
            for (int mt2 = 0; mt2 < 2; ++mt2) {
                bf16x8 afr = *reinterpret_cast<const bf16x8*>(
                    &As[wt][(q * 128 + wv * 32 + mt2 * 16 + l15) * 8]);
                #pragma unroll
                for (int nt = 0; nt < 3; ++nt)
                    acc[wt][mt2][nt] = __builtin_amdgcn_mfma_f32_16x16x32_bf16(
                        afr, bfr[nt], acc[wt][mt2][nt], 0, 0, 0);
            }
        }
    }

    #pragma unroll
    for (int mt2 = 0; mt2 < 2; ++mt2) {
        int mrow = wv * 32 + mt2 * 16 + q * 4;
        #pragma unroll
        for (int nt = 0; nt < 3; ++nt) {
            int token = colL + nt * 16 + l15;
            f32x4 aq = acc[0][mt2][nt] * INV_TEMP;
            short4 s4;
            s4.x = f2bf(aq[0]); s4.y = f2bf(aq[1]); s4.z = f2bf(aq[2]); s4.w = f2bf(aq[3]);
            *reinterpret_cast<short4*>(Yq + ((size_t)b * Ltok + token) * 128 + mrow) = s4;
            f32x4 ak = acc[1][mt2][nt];
            s4.x = f2bf(ak[0]); s4.y = f2bf(ak[1]); s4.z = f2bf(ak[2]); s4.w = f2bf(ak[3]);
            *reinterpret_cast<short4*>(Yk + ((size_t)b * Ltok + token) * 128 + mrow) = s4;
            #pragma unroll
            for (int r = 0; r < 4; ++r)
                Yv[((size_t)b * FF_N + mrow + r) * Ltok + token] = f2bf(acc[2][mt2][nt][r]);
        }
    }
}

// ---------------- demo attention, bf16 MFMA flash-style ----------------
__global__ __launch_bounds__(128) void demo_attn_mfma_kernel(const short* __restrict__ ws)
{
    __shared__ short Qt[96 * 40];
    __shared__ short Kt[96 * 40];
    __shared__ short Vs[32 * 104];
    __shared__ short Pt[96 * 104];
    __shared__ float alpha_s[96];
    __shared__ float l_s[96];

    const short* dqS = ws + S_DQ;
    const short* dkS = ws + S_DK;
    const short* dvS = ws + S_DV;
    short* dvaS = const_cast<short*>(ws) + S_DVA;

    const int bid = blockIdx.x;
    const int ti = bid & 3, pn = bid >> 2;
    const int b = pn >> 2, n = pn & 3;

    const int tid = threadIdx.x;
    const int lane = tid & 63, wv = tid >> 6;
    const int l15 = lane & 15, q = lane >> 4;

    for (int u = tid; u < 384; u += 128) {
        int i = u >> 2, c0 = (u & 3) * 8;
        bf16x8 pk = {0,0,0,0,0,0,0,0};
        if (i < 84)
            pk = *reinterpret_cast<const bf16x8*>(
                dkS + ((size_t)b * DI_N + ti * 84 + i) * 128 + n * 32 + c0);
        *reinterpret_cast<bf16x8*>(&Qt[i * 40 + c0]) = pk;
    }
    if (tid < 96) l_s[tid] = 0.f;

    float m_r[3][4];
    #pragma unroll
    for (int mt = 0; mt < 3; ++mt)
        #pragma unroll
        for (int r = 0; r < 4; ++r) m_r[mt][r] = -3.0e38f;

    f32x4 oacc[6] = {};

    for (int cj = 0; cj <= ti; ++cj) {
        __syncthreads();
        for (int u = tid; u < 384; u += 128) {
            int j = u >> 2, c0 = (u & 3) * 8;
            bf16x8 pk = {0,0,0,0,0,0,0,0};
            if (j < 84)
                pk = *reinterpret_cast<const bf16x8*>(
                    dqS + ((size_t)b * DI_N + cj * 84 + j) * 128 + n * 32 + c0);
            *reinterpret_cast<bf16x8*>(&Kt[j * 40 + c0]) = pk;
        }
        for (int u = tid; u < 384; u += 128) {
            int c = u / 12, j0 = (u % 12) * 8;
            const short* row = dvS + ((size_t)b * FF_N + n * 32 + c) * DI_N + cj * 84;
            bf16x8 pk;
            if (j0 + 8 <= 84) {
                short4 lo = *reinterpret_cast<const short4*>(row + j0);
                short4 hi = *reinterpret_cast<const short4*>(row + j0 + 4);
                pk[0]=lo.x; pk[1]=lo.y; pk[2]=lo.z; pk[3]=lo.w;
                pk[4]=hi.x; pk[5]=hi.y; pk[6]=hi.z; pk[7]=hi.w;
            } else {
                #pragma unroll
                for (int p = 0; p < 8; ++p) {
                    int j = j0 + p;
                    pk[p] = (j < 84) ? row[j] : (short)0;
                }
            }
            *reinterpret_cast<bf16x8*>(&Vs[c * 104 + j0]) = pk;
        }
        __syncthreads();

        #pragma unroll
        for (int mt = 0; mt < 3; ++mt) {
            int mrow = (wv * 3 + mt) * 16;
            bf16x8 afr = *reinterpret_cast<const bf16x8*>(&Qt[(mrow + l15) * 40 + q * 8]);
            f32x4 s[6];
            #pragma unroll
            for (int nt = 0; nt < 6; ++nt) {
                bf16x8 bfr = *reinterpret_cast<const bf16x8*>(&Kt[(nt * 16 + l15) * 40 + q * 8]);
                f32x4 z = {};
                s[nt] = __builtin_amdgcn_mfma_f32_16x16x32_bf16(afr, bfr, z, 0, 0, 0);
            }
            #pragma unroll
            for (int r = 0; r < 4; ++r) {
                if (l15 >= 4) s[5][r] = -3.0e38f;
                float mx = s[0][r];
                #pragma unroll
                for (int nt = 1; nt < 6; ++nt) mx = fmaxf(mx, s[nt][r]);
                #pragma unroll
                for (int o = 1; o < 16; o <<= 1) mx = fmaxf(mx, __shfl_xor(mx, o));
                float mnew = fmaxf(m_r[mt][r], mx);
                float al = __expf(m_r[mt][r] - mnew);
                m_r[mt][r] = mnew;
                float sm = 0.f;
                #pragma unroll
                for (int nt = 0; nt < 6; ++nt) {
                    float e = __expf(s[nt][r] - mnew);
                    s[nt][r] = e; sm += e;
                }
                #pragma unroll
                for (int o = 1; o < 16; o <<= 1) sm += __shfl_xor(sm, o);
                int i = mrow + q * 4 + r;
                if (l15 == 0) { alpha_s[i] = al; l_s[i] = l_s[i] * al + sm; }
            }
            #pragma unroll
            for (int nt = 0; nt < 6; ++nt)
                #pragma unroll
                for (int r = 0; r < 4; ++r)
                    Pt[(mrow + q * 4 + r) * 104 + nt * 16 + l15] = f2bf(s[nt][r]);
        }
        __syncthreads();

        #pragma unroll
        for (int nt = 0; nt < 6; ++nt) {
            float al = alpha_s[nt * 16 + l15];
            #pragma unroll
            for (int r = 0; r < 4; ++r) oacc[nt][r] *= al;
        }
        #pragma unroll
        for (int kk = 0; kk < 3; ++kk) {
            bf16x8 va = *reinterpret_cast<const bf16x8*>(&Vs[(wv * 16 + l15) * 104 + kk * 32 + q * 8]);
            #pragma unroll
            for (int nt = 0; nt < 6; ++nt) {
                bf16x8 pb = *reinterpret_cast<const bf16x8*>(&Pt[(nt * 16 + l15) * 104 + kk * 32 + q * 8]);
                oacc[nt] = __builtin_amdgcn_mfma_f32_16x16x32_bf16(va, pb, oacc[nt], 0, 0, 0);
            }
        }
    }

    #pragma unroll
    for (int nt = 0; nt < 6; ++nt) {
        int il = nt * 16 + l15;
        if (il < 84) {
            float inv = 1.f / l_s[il];
            int ig = ti * 84 + il;
            #pragma unroll
            for (int r = 0; r < 4; ++r)
                dvaS[((size_t)b * FF_N + n * 32 + wv * 16 + q * 4 + r) * DI_N + ig] =
                    f2bf(oacc[nt][r] * inv);
        }
    }
}

// ---------------- obs attention, bf16 MFMA ----------------
__global__ __launch_bounds__(256, 4) void obs_attn_mfma_kernel(const short* __restrict__ ws)
{
    __shared__ short Qt[96 * 40];
    __shared__ short Kt[64 * 40];
    __shared__ short Vs[32 * 72];
    __shared__ short Pt[96 * 72];

    const short* dkS = ws + S_DK;
    const short* dvaS = ws + S_DVA;
    const short* oqS = ws + S_OQ;
    const short* okS = ws + S_OK;
    const short* ovS = ws + S_OV;
    short* ovaS = const_cast<short*>(ws) + S_OVA;

    const int bid = blockIdx.x;
    const int b = bid >> 7, rem = bid & 127, t = rem >> 2, n = rem & 3;

    const int tid = threadIdx.x;
    const int lane = tid & 63, wv = tid >> 6;
    const int l15 = lane & 15, q = lane >> 4;

    for (int l = tid; l < 384; l += 256) {
        int i = l >> 2, c0 = (l & 3) * 8;
        bf16x8 pk = {0,0,0,0,0,0,0,0};
        if (i < HW_N)
            pk = *reinterpret_cast<const bf16x8*>(
                oqS + ((size_t)b * OI_N + t * 84 + i) * 128 + n * 32 + c0);
        *reinterpret_cast<bf16x8*>(&Qt[i * 40 + c0]) = pk;
    }

    const int pv_mt = wv & 1;
    const int pv_nb = wv >> 1;
    f32x4 oacc[3] = {};

    for (int jc = 0; jc < 448; jc += 64) {
        __syncthreads();
        {
            int jl = tid >> 2, c0 = (tid & 3) * 8;
            int jg = jc + jl;
            bf16x8 pk = {0,0,0,0,0,0,0,0};
            if (jg < DI_N)
                pk = *reinterpret_cast<const bf16x8*>(
                    dkS + ((size_t)b * DI_N + jg) * 128 + n * 32 + c0);
            else if (jg < CAT_N)
                pk = *reinterpret_cast<const bf16x8*>(
                    okS + ((size_t)b * OI_N + t * 84 + (jg - DI_N)) * 128 + n * 32 + c0);
            *reinterpret_cast<bf16x8*>(&Kt[jl * 40 + c0]) = pk;
        }
        {
            int c = tid >> 3, j0 = (tid & 7) * 8;
            int jg0 = jc + j0;
            const short* dvaRow = dvaS + ((size_t)b * FF_N + n * 32 + c) * DI_N;
            const short* ovRow = ovS + ((size_t)b * FF_N + n * 32 + c) * OI_N + t * 84;
            bf16x8 pk;
            if (jg0 + 8 <= DI_N) {
                pk = *reinterpret_cast<const bf16x8*>(dvaRow + jg0);
            } else if (jg0 >= DI_N && jg0 + 8 <= CAT_N) {
                short4 lo = *reinterpret_cast<const short4*>(ovRow + (jg0 - DI_N));
                short4 hi = *reinterpret_cast<const short4*>(ovRow + (jg0 - DI_N) + 4);
                pk[0]=lo.x; pk[1]=lo.y; pk[2]=lo.z; pk[3]=lo.w;
                pk[4]=hi.x; pk[5]=hi.y; pk[6]=hi.z; pk[7]=hi.w;
            } else {
                #pragma unroll
                for (int p = 0; p < 8; ++p) {
                    int jg = jg0 + p;
                    pk[p] = (jg < DI_N) ? dvaRow[jg]
                          : ((jg < CAT_N) ? ovRow[jg - DI_N] : (short)0);
                }
            }
            *reinterpret_cast<bf16x8*>(&Vs[c * 72 + j0]) = pk;
        }
        __syncthreads();

        f32x4 s[6];
        bf16x8 afr = *reinterpret_cast<const bf16x8*>(&Kt[(wv * 16 + l15) * 40 + q * 8]);
        #pragma unroll
        for (int nt = 0; nt < 6; ++nt) {
            bf16x8 bfr = *reinterpret_cast<const bf16x8*>(&Qt[(nt * 16 + l15) * 40 + q * 8]);
            f32x4 z = {};
            s[nt] = __builtin_amdgcn_mfma_f32_16x16x32_bf16(afr, bfr, z, 0, 0, 0);
        }
        float inv[4];
        #pragma unroll
        for (int r = 0; r < 4; ++r) {
            if (l15 >= 4) s[5][r] = -3.0e38f;
            float m2 = s[0][r];
            #pragma unroll
            for (int nt2 = 1; nt2 < 6; ++nt2) m2 = fmaxf(m2, s[nt2][r]);
            #pragma unroll
            for (int o = 1; o < 16; o <<= 1) m2 = fmaxf(m2, __shfl_xor(m2, o));
            float sm = 0.f;
            #pragma unroll
            for (int nt2 = 0; nt2 < 6; ++nt2) { float e = __expf(s[nt2][r] - m2); s[nt2][r] = e; sm += e; }
            #pragma unroll
            for (int o = 1; o < 16; o <<= 1) sm += __shfl_xor(sm, o);
            inv[r] = 1.f / sm;
        }
        #pragma unroll
        for (int nt = 0; nt < 6; ++nt) {
            short4 pk4;
            pk4.x = f2bf(s[nt][0] * inv[0]);
            pk4.y = f2bf(s[nt][1] * inv[1]);
            pk4.z = f2bf(s[nt][2] * inv[2]);
            pk4.w = f2bf(s[nt][3] * inv[3]);
            *reinterpret_cast<short4*>(&Pt[(nt * 16 + l15) * 72 + wv * 16 + q * 4]) = pk4;
        }
        __syncthreads();

        #pragma unroll
        for (int kk = 0; kk < 2; ++kk) {
            bf16x8 va = *reinterpret_cast<const bf16x8*>(&Vs[(pv_mt * 16 + l15) * 72 + kk * 32 + q * 8]);
            #pragma unroll
            for (int u = 0; u < 3; ++u) {
                int nt = pv_nb + u * 2;
                bf16x8 pb = *reinterpret_cast<const bf16x8*>(&Pt[(nt * 16 + l15) * 72 + kk * 32 + q * 8]);
                oacc[u] = __builtin_amdgcn_mfma_f32_16x16x32_bf16(va, pb, oacc[u], 0, 0, 0);
            }
        }
    }

    #pragma unroll
    for (int u = 0; u < 3; ++u) {
        int i = (pv_nb + u * 2) * 16 + l15;
        if (i < HW_N) {
            short4 st;
            st.x = f2bf(oacc[u][0]); st.y = f2bf(oacc[u][1]);
            st.z = f2bf(oacc[u][2]); st.w = f2bf(oacc[u][3]);
            *reinterpret_cast<short4*>(
                ovaS + (((size_t)b * OT_N + t) * 84 + i) * 128 + n * 32 + pv_mt * 16 + q * 4) = st;
        }
    }
}

// ---------------- output projection + ReLU + residual (bf16 x) + stats ----
__global__ __launch_bounds__(256) void outproj_mfma_kernel(
    short* __restrict__ xbf, const short* __restrict__ ws, int layer,
    float* __restrict__ stats)
{
    __shared__ short As[4096];
    __shared__ short Bs[3072];

    const int bid = blockIdx.x;
    const int b = bid >> 7, rem = bid & 127, t = rem >> 2, mt = rem & 3;
    const int o0 = mt * 128;
    const short* WoS = ws + SW_OWO + layer * 65536 + (size_t)o0 * FF_N;
    const short* ovaS = ws + S_OVA + (((size_t)b * OT_N + t) * 84) * 128;

    const int tid = threadIdx.x;
    const int lane = tid & 63, wv = tid >> 6;
    const int l15 = lane & 15, q = lane >> 4;

    f32x4 acc[2][6] = {};

    for (int k0 = 0; k0 < FF_N; k0 += 32) {
        __syncthreads();
        #pragma unroll
        for (int h = 0; h < 2; ++h) {
            int c = tid + h * 256;
            int kc = c & 3, m = c >> 2;
            bf16x8 pk = *reinterpret_cast<const bf16x8*>(WoS + (size_t)m * FF_N + k0 + kc * 8);
            *reinterpret_cast<bf16x8*>(&As[(kc * 128 + m) * 8]) = pk;
        }
        for (int c = tid; c < 384; c += 256) {
            int n2 = c % 96, kc = c / 96;
            bf16x8 pk = {0,0,0,0,0,0,0,0};
            if (n2 < HW_N)
                pk = *reinterpret_cast<const bf16x8*>(ovaS + (size_t)n2 * 128 + k0 + kc * 8);
            *reinterpret_cast<bf16x8*>(&Bs[(kc * 96 + n2) * 8]) = pk;
        }
        __syncthreads();

        bf16x8 af[2];
        #pragma unroll
        for (int mt2 = 0; mt2 < 2; ++mt2)
            af[mt2] = *reinterpret_cast<const bf16x8*>(
                &As[(q * 128 + wv * 32 + mt2 * 16 + l15) * 8]);
        #pragma unroll
        for (int nt = 0; nt < 6; ++nt) {
            bf16x8 bf = *reinterpret_cast<const bf16x8*>(&Bs[(q * 96 + nt * 16 + l15) * 8]);
            #pragma unroll
            for (int mt2 = 0; mt2 < 2; ++mt2)
                acc[mt2][nt] = __builtin_amdgcn_mfma_f32_16x16x32_bf16(
                    af[mt2], bf, acc[mt2][nt], 0, 0, 0);
        }
    }

    // epilogue: RMW bf16 xbf token-major + per-channel stats (obs slice)
    float csum[2][4] = {}, csq[2][4] = {};
    #pragma unroll
    for (int mt2 = 0; mt2 < 2; ++mt2) {
        const int och = o0 + wv * 32 + mt2 * 16 + q * 4;
        #pragma unroll
        for (int nt = 0; nt < 6; ++nt) {
            int i = nt * 16 + l15;
            if (i < HW_N) {
                short* p = xbf + ((size_t)b * THW_N + (size_t)(DT_N + t) * HW_N + i) * 512 + och;
                short4 old4 = *reinterpret_cast<short4*>(p);
                short4 nw;
                float ov[4] = {bf2f(old4.x), bf2f(old4.y), bf2f(old4.z), bf2f(old4.w)};
                short* nwp = &nw.x;
                #pragma unroll
                for (int r = 0; r < 4; ++r) {
                    float v = acc[mt2][nt][r];
                    float y = ov[r] + (v > 0.f ? v : 0.f);
                    short ybf = f2bf(y);
                    nwp[r] = ybf;
                    float yr = bf2f(ybf);
                    csum[mt2][r] += yr;
                    csq[mt2][r] += yr * yr;
                }
                *reinterpret_cast<short4*>(p) = nw;
            }
        }
    }
    #pragma unroll
    for (int mt2 = 0; mt2 < 2; ++mt2) {
        #pragma unroll
        for (int r = 0; r < 4; ++r) {
            float s = csum[mt2][r], qq = csq[mt2][r];
            #pragma unroll
            for (int o = 1; o < 16; o <<= 1) {
                s += __shfl_xor(s, o);
                qq += __shfl_xor(qq, o);
            }
            if (l15 == 0) {
                int ch = o0 + wv * 32 + mt2 * 16 + q * 4 + r;
                atomicAdd(&stats[ch], s);
                atomicAdd(&stats[512 + ch], qq);
            }
        }
    }
}

// ---------------- BN in place on bf16 xbf + demo-stats for next layer -----
// Tile: 48 tok x 512 ch; grid 8*63 = 504. Demo tiles tt<7 accumulate next stats.
__global__ __launch_bounds__(256) void bn_mid_kernel(
    short* __restrict__ xbf, const float* __restrict__ stats,
    const float* __restrict__ gamma, const float* __restrict__ beta,
    float* __restrict__ stats_next)
{
    __shared__ float red_s[4][512];
    __shared__ float red_q[4][512];

    const int bid = blockIdx.x;
    const int b = bid / 63, tt = bid % 63;
    const int t0 = tt * 48;
    const bool is_demo = (tt < 7);
    const int tid = threadIdx.x;
    const int chg = tid & 63;            // fixed 8-channel group
    const int trow = tid >> 6;           // 0..3

    // per-thread channel constants
    float mean[8], rs[8], g[8], bb[8];
    #pragma unroll
    for (int j = 0; j < 8; ++j) {
        int c = chg * 8 + j;
        float m = stats[c] * INV_CNT;
        float var = stats[512 + c] * INV_CNT - m * m;
        mean[j] = m;
        rs[j] = rsqrtf(var + BN_EPS);
        g[j] = gamma[c];
        bb[j] = beta[c];
    }

    float psum[8] = {}, psq[8] = {};
    #pragma unroll
    for (int it = 0; it < 12; ++it) {
        int tok = t0 + it * 4 + trow;
        short* p = xbf + ((size_t)b * THW_N + tok) * 512 + chg * 8;
        bf16x8 v = *reinterpret_cast<bf16x8*>(p);
        bf16x8 w;
        #pragma unroll
        for (int j = 0; j < 8; ++j) {
            float y = g[j] * (bf2f(v[j]) - mean[j]) * rs[j] + bb[j];
            short yb = f2bf(y);
            w[j] = yb;
            if (is_demo) {
                float yr = bf2f(yb);
                psum[j] += yr; psq[j] += yr * yr;
            }
        }
        *reinterpret_cast<bf16x8*>(p) = w;
    }
    if (!is_demo) return;
    #pragma unroll
    for (int j = 0; j < 8; ++j) {
        red_s[trow][chg * 8 + j] = psum[j];
        red_q[trow][chg * 8 + j] = psq[j];
    }
    __syncthreads();
    #pragma unroll
    for (int h = 0; h < 2; ++h) {
        int c = tid + h * 256;
        float s = red_s[0][c] + red_s[1][c] + red_s[2][c] + red_s[3][c];
        float qq = red_q[0][c] + red_q[1][c] + red_q[2][c] + red_q[3][c];
        atomicAdd(&stats_next[c], s);
        atomicAdd(&stats_next[512 + c], qq);
    }
}

// ---------------- final BN -> fp32 channel-major d_out --------------------
// Tile 48 tok x 64 ch; grid 8*63*8 = 4032.
__global__ __launch_bounds__(256) void bn_out_kernel(
    const short* __restrict__ xbf, float* __restrict__ out_f,
    const float* __restrict__ stats,
    const float* __restrict__ gamma, const float* __restrict__ beta)
{
    __shared__ float tile[48][65];

    const int bid = blockIdx.x;
    const int b = bid / 504, rem = bid % 504, tt = rem >> 3, cblk = rem & 7;
    const int t0 = tt * 48, c0 = cblk * 64;
    const int tid = threadIdx.x;
    const int cg = tid & 15;   // fixed short4 group

    float mean[4], rs[4], g[4], bb[4];
    #pragma unroll
    for (int j = 0; j < 4; ++j) {
        int c = c0 + cg * 4 + j;
        float m = stats[c] * INV_CNT;
        float var = stats[512 + c] * INV_CNT - m * m;
        mean[j] = m; rs[j] = rsqrtf(var + BN_EPS);
        g[j] = gamma[c]; bb[j] = beta[c];
    }

    #pragma unroll
    for (int l0 = 0; l0 < 768; l0 += 256) {
        int l = l0 + tid;
        int tok = l >> 4;
        short4 v = *reinterpret_cast<const short4*>(
            xbf + ((size_t)b * THW_N + t0 + tok) * 512 + c0 + cg * 4);
        tile[tok][cg * 4 + 0] = g[0] * (bf2f(v.x) - mean[0]) * rs[0] + bb[0];
        tile[tok][cg * 4 + 1] = g[1] * (bf2f(v.y) - mean[1]) * rs[1] + bb[1];
        tile[tok][cg * 4 + 2] = g[2] * (bf2f(v.z) - mean[2]) * rs[2] + bb[2];
        tile[tok][cg * 4 + 3] = g[3] * (bf2f(v.w) - mean[3]) * rs[3] + bb[3];
    }
    __syncthreads();
    #pragma unroll
    for (int l0 = 0; l0 < 768; l0 += 256) {
        int l = l0 + tid;
        int cc = l / 12, tg = l % 12;
        float4 o;
        o.x = tile[tg * 4 + 0][cc];
        o.y = tile[tg * 4 + 1][cc];
        o.z = tile[tg * 4 + 2][cc];
        o.w = tile[tg * 4 + 3][cc];
        *reinterpret_cast<float4*>(
            out_f + ((size_t)b * D_N + c0 + cc) * THW_N + t0 + tg * 4) = o;
    }
}

// ---------------- launch ----------------
extern "C" void kernel_launch(void* const* d_in, const int* in_sizes, int n_in,
                              void* d_out, int out_size, void* d_ws, size_t ws_size,
                              hipStream_t stream)
{
    const float* inp  = (const float*)d_in[0];
    const float* dwq  = (const float*)d_in[1];
    const float* dwk  = (const float*)d_in[2];
    const float* dwv  = (const float*)d_in[3];
    const float* owq  = (const float*)d_in[5];
    const float* owk  = (const float*)d_in[6];
    const float* owv  = (const float*)d_in[7];
    const float* owo  = (const float*)d_in[8];
    const float* gam  = (const float*)d_in[9];
    const float* bet  = (const float*)d_in[10];
    float* x  = (float*)d_out;
    float* stats = (float*)d_ws;          // [2][1024]
    short* wsS = (short*)(stats + 2048);
    short* xbf = wsS + S_XBF;

    cvt_w_kernel<<<448, 256, 0, stream>>>(dwq, dwk, dwv, owq, owk, owv, owo, wsS, stats);
    xin_kernel<<<4032, 256, 0, stream>>>(inp, xbf, stats);

    for (int layer = 0; layer < 2; ++layer) {
        float* stL = stats + layer * 1024;
        size_t coff = (size_t)layer * D_N;
        proj_mfma_kernel<<<504, 256, 0, stream>>>(xbf, wsS, layer);
        demo_attn_mfma_kernel<<<128, 128, 0, stream>>>(wsS);
        obs_attn_mfma_kernel<<<1024, 256, 0, stream>>>(wsS);
        outproj_mfma_kernel<<<1024, 256, 0, stream>>>(xbf, wsS, layer, stL);
        if (layer == 0) {
            bn_mid_kernel<<<504, 256, 0, stream>>>(
                xbf, stL, gam + coff, bet + coff, stats + 1024);
        } else {
            bn_out_kernel<<<4032, 256, 0, stream>>>(
                xbf, x, stL, gam + coff, bet + coff);
        }
    }
    (void)in_sizes; (void)n_in; (void)out_size; (void)ws_size;
}

// Round 9
// 348.630 us; speedup vs baseline: 3.4260x; 1.1669x over previous
//
#include <hip/hip_runtime.h>

// ---------------- problem constants ----------------
#define B_N 8
#define D_N 512
#define T_N 36
#define HW_N 84
#define THW_N 3024
#define DT_N 4
#define OT_N 32
#define NH_N 4
#define FF_N 128
#define CH_N 32
#define DI_N 336      // demo tokens 4*84
#define OI_N 2688     // obs tokens 32*84
#define CAT_N 420
#define INV_TEMP 0.04419417382415922f   // 1/sqrt(512)
#define BN_EPS 1e-5f
#define INV_CNT (1.0f / 24192.0f)       // 1/(B*THW)

// workspace: float stats[2][1024] at base (sum[512], sumsq[512] per layer),
// then bf16 (short) arena at +8192B.
#define SW_DWQ 0
#define SW_DWK 131072
#define SW_DWV 262144
#define SW_OWQ 393216
#define SW_OWK 524288
#define SW_OWV 655360
#define SW_OWO 786432
#define S_DQ   917504     // [b][336][128] token-major (INV_TEMP folded)
#define S_DK   1261568    // [b][336][128] token-major
#define S_DV   1605632    // [b][128][336] channel-major
#define S_DVA  1949696    // [b][128][336] channel-major
#define S_OQ   2293760    // [b][2688][128] token-major (INV_TEMP folded)
#define S_OK   5046272    // [b][2688][128] token-major
#define S_OV   7798784    // [b][128][2688] channel-major
#define S_OVA  10551296   // [b][32][84][128] token-major
#define S_XBF  13303808   // [b][3024][512] token-major bf16 x

typedef short bf16x8 __attribute__((ext_vector_type(8)));   // 8 bf16 in 4 VGPRs
typedef float f32x4 __attribute__((ext_vector_type(4)));

__device__ __forceinline__ short f2bf(float f) {
    unsigned u = __float_as_uint(f);
    u += 0x7fffu + ((u >> 16) & 1u);          // round-to-nearest-even
    return (short)(u >> 16);
}
__device__ __forceinline__ float bf2f(short s) {
    return __uint_as_float(((unsigned)(unsigned short)s) << 16);
}

// ---------------- weight conversion + stats zero (once per launch) --------
__global__ __launch_bounds__(256) void cvt_w_kernel(
    const float* __restrict__ s0, const float* __restrict__ s1,
    const float* __restrict__ s2, const float* __restrict__ s3,
    const float* __restrict__ s4, const float* __restrict__ s5,
    const float* __restrict__ s6, short* __restrict__ dst,
    float* __restrict__ stats)
{
    const int bid = blockIdx.x;
    if (bid == 0) {   // zero both layers' stats accumulators (2048 floats)
        #pragma unroll
        for (int k = 0; k < 8; ++k) stats[threadIdx.x * 8 + k] = 0.f;
    }
    const int a = bid >> 6, blk = bid & 63;
    const float* src;
    switch (a) {
        case 0: src = s0; break; case 1: src = s1; break;
        case 2: src = s2; break; case 3: src = s3; break;
        case 4: src = s4; break; case 5: src = s5; break;
        default: src = s6;
    }
    const int idx = (blk * 256 + (int)threadIdx.x) * 8;
    float4 f0 = *reinterpret_cast<const float4*>(src + idx);
    float4 f1 = *reinterpret_cast<const float4*>(src + idx + 4);
    bf16x8 pk;
    pk[0] = f2bf(f0.x); pk[1] = f2bf(f0.y); pk[2] = f2bf(f0.z); pk[3] = f2bf(f0.w);
    pk[4] = f2bf(f1.x); pk[5] = f2bf(f1.y); pk[6] = f2bf(f1.z); pk[7] = f2bf(f1.w);
    *reinterpret_cast<bf16x8*>(dst + (size_t)a * 131072 + idx) = pk;
}

// ---------------- input staging: fp32 ch-major -> bf16 token-major -------
__global__ __launch_bounds__(256) void xin_kernel(
    const float* __restrict__ in_f, short* __restrict__ xbf,
    float* __restrict__ stats0)
{
    __shared__ short tile[48][65];
    __shared__ float red_s[16][64];
    __shared__ float red_q[16][64];

    const int bid = blockIdx.x;
    const int b = bid / 504, rem = bid % 504, tt = rem >> 3, cblk = rem & 7;
    const int t0 = tt * 48, c0 = cblk * 64;
    const int tid = threadIdx.x;
    const bool is_demo = (tt < 7);

    #pragma unroll
    for (int l0 = 0; l0 < 768; l0 += 256) {
        int l = l0 + tid;
        int cc = l / 12, tg = l % 12;
        size_t addr = ((size_t)b * D_N + c0 + cc) * THW_N + t0 + tg * 4;
        float4 v = *reinterpret_cast<const float4*>(in_f + addr);
        tile[tg * 4 + 0][cc] = f2bf(v.x);
        tile[tg * 4 + 1][cc] = f2bf(v.y);
        tile[tg * 4 + 2][cc] = f2bf(v.z);
        tile[tg * 4 + 3][cc] = f2bf(v.w);
    }
    __syncthreads();
    float psum[4] = {}, psq[4] = {};
    const int cg = tid & 15;
    #pragma unroll
    for (int l0 = 0; l0 < 768; l0 += 256) {
        int l = l0 + tid;
        int tk = l >> 4;
        short4 s4;
        s4.x = tile[tk][cg * 4 + 0];
        s4.y = tile[tk][cg * 4 + 1];
        s4.z = tile[tk][cg * 4 + 2];
        s4.w = tile[tk][cg * 4 + 3];
        *reinterpret_cast<short4*>(
            xbf + ((size_t)b * THW_N + t0 + tk) * 512 + c0 + cg * 4) = s4;
        if (is_demo) {
            float v0 = bf2f(s4.x), v1 = bf2f(s4.y), v2 = bf2f(s4.z), v3 = bf2f(s4.w);
            psum[0] += v0; psum[1] += v1; psum[2] += v2; psum[3] += v3;
            psq[0] += v0 * v0; psq[1] += v1 * v1; psq[2] += v2 * v2; psq[3] += v3 * v3;
        }
    }
    if (!is_demo) return;
    __syncthreads();
    #pragma unroll
    for (int j = 0; j < 4; ++j) {
        red_s[tid >> 4][cg * 4 + j] = psum[j];
        red_q[tid >> 4][cg * 4 + j] = psq[j];
    }
    __syncthreads();
    if (tid < 64) {
        float s = 0.f, q = 0.f;
        #pragma unroll
        for (int r = 0; r < 16; ++r) { s += red_s[r][tid]; q += red_q[r][tid]; }
        atomicAdd(&stats0[c0 + tid], s);
        atomicAdd(&stats0[512 + c0 + tid], q);
    }
}

// ---------------- fused QKV projection, bf16 MFMA ----------------
__global__ __launch_bounds__(256) void proj_mfma_kernel(
    const short* __restrict__ xbf, short* __restrict__ ws, int layer)
{
    __shared__ short As[3][4096];   // [wt][(kc*128 + m)*8]
    __shared__ short Bs[1536];      // [(kc*48 + n)*8]

    const int bid = blockIdx.x;
    const int b = bid / 63, ct = bid - b * 63;
    const bool is_demo = (ct < 7);
    const int woff = layer * 65536;
    const short* W0 = ws + (is_demo ? SW_DWQ : SW_OWQ) + woff;
    const short* W1 = ws + (is_demo ? SW_DWK : SW_OWK) + woff;
    const short* W2 = ws + (is_demo ? SW_DWV : SW_OWV) + woff;
    const int Ltok = is_demo ? DI_N : OI_N;
    const int colL = is_demo ? ct * 48 : (ct - 7) * 48;
    short* Yq = ws + (is_demo ? S_DQ : S_OQ);
    short* Yk = ws + (is_demo ? S_DK : S_OK);
    short* Yv = ws + (is_demo ? S_DV : S_OV);
    const short* Xb = xbf + ((size_t)b * THW_N + (is_demo ? 0 : DI_N) + colL) * 512;

    const int tid = threadIdx.x;
    const int lane = tid & 63, wv = tid >> 6;
    const int l15 = lane & 15, q = lane >> 4;

    f32x4 acc[3][2][3] = {};

    for (int k0 = 0; k0 < D_N; k0 += 32) {
        __syncthreads();
        const short* Wt[3] = {W0, W1, W2};
        #pragma unroll
        for (int wt = 0; wt < 3; ++wt) {
            #pragma unroll
            for (int h = 0; h < 2; ++h) {
                int c = tid + h * 256;
                int kc = c & 3, m = c >> 2;
                bf16x8 pk = *reinterpret_cast<const bf16x8*>(
                    Wt[wt] + (size_t)m * D_N + k0 + kc * 8);
                *reinterpret_cast<bf16x8*>(&As[wt][(kc * 128 + m) * 8]) = pk;
            }
        }
        if (tid < 192) {
            int n = tid % 48, kc = tid / 48;
            bf16x8 pk = *reinterpret_cast<const bf16x8*>(
                Xb + (size_t)n * 512 + k0 + kc * 8);
            *reinterpret_cast<bf16x8*>(&Bs[(kc * 48 + n) * 8]) = pk;
        }
        __syncthreads();

        bf16x8 bfr[3];
        #pragma unroll
        for (int nt = 0; nt < 3; ++nt)
            bfr[nt] = *reinterpret_cast<const bf16x8*>(&Bs[(q * 48 + nt * 16 + l15) * 8]);
        #pragma unroll
        for (int wt = 0; wt < 3; ++wt) {
            #pragma unroll
            for (int mt2 = 0; mt2 < 2; ++mt2) {
                bf16x8 afr = *reinterpret_cast<const bf16x8*>(
                    &As[wt][(q * 128 + wv * 32 + mt2 * 16 + l15) * 8]);
                #pragma unroll
                for (int nt = 0; nt < 3; ++nt)
                    acc[wt][mt2][nt] = __builtin_amdgcn_mfma_f32_16x16x32_bf16(
                        afr, bfr[nt], acc[wt][mt2][nt], 0, 0, 0);
            }
        }
    }

    #pragma unroll
    for (int mt2 = 0; mt2 < 2; ++mt2) {
        int mrow = wv * 32 + mt2 * 16 + q * 4;
        #pragma unroll
        for (int nt = 0; nt < 3; ++nt) {
            int token = colL + nt * 16 + l15;
            f32x4 aq = acc[0][mt2][nt] * INV_TEMP;
            short4 s4;
            s4.x = f2bf(aq[0]); s4.y = f2bf(aq[1]); s4.z = f2bf(aq[2]); s4.w = f2bf(aq[3]);
            *reinterpret_cast<short4*>(Yq + ((size_t)b * Ltok + token) * 128 + mrow) = s4;
            f32x4 ak = acc[1][mt2][nt];
            s4.x = f2bf(ak[0]); s4.y = f2bf(ak[1]); s4.z = f2bf(ak[2]); s4.w = f2bf(ak[3]);
            *reinterpret_cast<short4*>(Yk + ((size_t)b * Ltok + token) * 128 + mrow) = s4;
            #pragma unroll
            for (int r = 0; r < 4; ++r)
                Yv[((size_t)b * FF_N + mrow + r) * Ltok + token] = f2bf(acc[2][mt2][nt][r]);
        }
    }
}

// ---------------- demo attention, single-pass bf16 MFMA -------------------
// Block = (b, n, ti, i-half). 192 threads = 3 waves; wave w -> i-tile w of the
// 48-row half. Q/K/V fragments loaded DIRECT from global (token-major dk/dq,
// channel-major dv). Scores for all j (<= 21 tiles, templated) in registers;
// single-pass softmax; one LDS buffer (Pt) + one barrier; PV direct-V.
template<int NT>
__device__ __forceinline__ void demo_core(
    const short* __restrict__ dqS, const short* __restrict__ dkS,
    const short* __restrict__ dvS, short* __restrict__ dvaS,
    short* __restrict__ Pt, int b, int n, int ti, int ih)
{
    constexpr int NTP = (NT + 1) & ~1;        // k-padded tile count for PV
    const int tid = threadIdx.x;
    const int lane = tid & 63, w = tid >> 6;  // w in 0..2
    const int l15 = lane & 15, q = lane >> 4;
    const int jmax = (ti + 1) * 84;

    // QK: A-frag rows i from dk (clamp out-of-frame rows -> finite scores)
    const int irow = ih * 48 + w * 16 + l15;
    const int tokA = ti * 84 + (irow < 84 ? irow : 83);
    bf16x8 afr = *reinterpret_cast<const bf16x8*>(
        dkS + ((size_t)b * DI_N + tokA) * 128 + n * 32 + q * 8);

    f32x4 s[NT];
    #pragma unroll
    for (int nt = 0; nt < NT; ++nt) {
        bf16x8 bfr = *reinterpret_cast<const bf16x8*>(
            dqS + ((size_t)b * DI_N + nt * 16 + l15) * 128 + n * 32 + q * 8);
        f32x4 z = {};
        s[nt] = __builtin_amdgcn_mfma_f32_16x16x32_bf16(afr, bfr, z, 0, 0, 0);
    }

    // softmax over j per row r (rows i = base + q*4 + r, cols l15 within tile)
    const int mstart = jmax - (NT - 1) * 16;  // mask l15 >= mstart in last tile
    #pragma unroll
    for (int r = 0; r < 4; ++r) {
        if (l15 >= mstart) s[NT - 1][r] = -3.0e38f;
        float mx = s[0][r];
        #pragma unroll
        for (int nt = 1; nt < NT; ++nt) mx = fmaxf(mx, s[nt][r]);
        #pragma unroll
        for (int o = 1; o < 16; o <<= 1) mx = fmaxf(mx, __shfl_xor(mx, o));
        float sm = 0.f;
        #pragma unroll
        for (int nt = 0; nt < NT; ++nt) {
            float e = __expf(s[nt][r] - mx);
            s[nt][r] = e; sm += e;
        }
        #pragma unroll
        for (int o = 1; o < 16; o <<= 1) sm += __shfl_xor(sm, o);
        float inv = 1.f / sm;
        #pragma unroll
        for (int nt = 0; nt < NT; ++nt) s[nt][r] *= inv;
    }

    // write normalized P to Pt[i_local][j] (stride 360 -> 2-way-free banks)
    #pragma unroll
    for (int nt = 0; nt < NT; ++nt)
        #pragma unroll
        for (int r = 0; r < 4; ++r)
            Pt[(w * 16 + q * 4 + r) * 360 + nt * 16 + l15] = f2bf(s[nt][r]);
    if (NTP != NT) {   // zero k-pad tile
        #pragma unroll
        for (int r = 0; r < 4; ++r)
            Pt[(w * 16 + q * 4 + r) * 360 + NT * 16 + l15] = 0;
    }
    __syncthreads();

    // PV: wave w -> n-tile it=w (its own 16 i-cols), ct in {0,1} (c-tiles)
    f32x4 oacc[2] = {};
    #pragma unroll
    for (int kk = 0; kk < NTP / 2; ++kk) {
        bf16x8 pb = *reinterpret_cast<const bf16x8*>(
            &Pt[(w * 16 + l15) * 360 + kk * 32 + q * 8]);
        #pragma unroll
        for (int ct = 0; ct < 2; ++ct) {
            bf16x8 va = *reinterpret_cast<const bf16x8*>(
                dvS + ((size_t)b * FF_N + n * 32 + ct * 16 + l15) * DI_N + kk * 32 + q * 8);
            oacc[ct] = __builtin_amdgcn_mfma_f32_16x16x32_bf16(va, pb, oacc[ct], 0, 0, 0);
        }
    }

    // epilogue: c = ct*16 + q*4 + r, i = ih*48 + w*16 + l15
    const int ig = ih * 48 + w * 16 + l15;
    if (ig < 84) {
        #pragma unroll
        for (int ct = 0; ct < 2; ++ct)
            #pragma unroll
            for (int r = 0; r < 4; ++r)
                dvaS[((size_t)b * FF_N + n * 32 + ct * 16 + q * 4 + r) * DI_N + ti * 84 + ig] =
                    f2bf(oacc[ct][r]);
    }
}

__global__ __launch_bounds__(192) void demo_attn_mfma_kernel(const short* __restrict__ ws)
{
    __shared__ short Pt[48 * 360];   // 34.56 KB

    const short* dqS = ws + S_DQ;
    const short* dkS = ws + S_DK;
    const short* dvS = ws + S_DV;
    short* dvaS = const_cast<short*>(ws) + S_DVA;

    const int bid = blockIdx.x;      // ((b*4 + n)*4 + ti)*2 + ih
    const int ih = bid & 1, ti = (bid >> 1) & 3;
    const int n = (bid >> 3) & 3, b = bid >> 5;

    switch (ti) {
        case 0: demo_core<6>(dqS, dkS, dvS, dvaS, Pt, b, n, ti, ih); break;
        case 1: demo_core<11>(dqS, dkS, dvS, dvaS, Pt, b, n, ti, ih); break;
        case 2: demo_core<16>(dqS, dkS, dvS, dvaS, Pt, b, n, ti, ih); break;
        default: demo_core<21>(dqS, dkS, dvS, dvaS, Pt, b, n, ti, ih); break;
    }
}

// ---------------- obs attention, bf16 MFMA ----------------
__global__ __launch_bounds__(256, 4) void obs_attn_mfma_kernel(const short* __restrict__ ws)
{
    __shared__ short Qt[96 * 40];
    __shared__ short Kt[64 * 40];
    __shared__ short Vs[32 * 72];
    __shared__ short Pt[96 * 72];

    const short* dkS = ws + S_DK;
    const short* dvaS = ws + S_DVA;
    const short* oqS = ws + S_OQ;
    const short* okS = ws + S_OK;
    const short* ovS = ws + S_OV;
    short* ovaS = const_cast<short*>(ws) + S_OVA;

    const int bid = blockIdx.x;
    const int b = bid >> 7, rem = bid & 127, t = rem >> 2, n = rem & 3;

    const int tid = threadIdx.x;
    const int lane = tid & 63, wv = tid >> 6;
    const int l15 = lane & 15, q = lane >> 4;

    for (int l = tid; l < 384; l += 256) {
        int i = l >> 2, c0 = (l & 3) * 8;
        bf16x8 pk = {0,0,0,0,0,0,0,0};
        if (i < HW_N)
            pk = *reinterpret_cast<const bf16x8*>(
                oqS + ((size_t)b * OI_N + t * 84 + i) * 128 + n * 32 + c0);
        *reinterpret_cast<bf16x8*>(&Qt[i * 40 + c0]) = pk;
    }

    const int pv_mt = wv & 1;
    const int pv_nb = wv >> 1;
    f32x4 oacc[3] = {};

    for (int jc = 0; jc < 448; jc += 64) {
        __syncthreads();
        {
            int jl = tid >> 2, c0 = (tid & 3) * 8;
            int jg = jc + jl;
            bf16x8 pk = {0,0,0,0,0,0,0,0};
            if (jg < DI_N)
                pk = *reinterpret_cast<const bf16x8*>(
                    dkS + ((size_t)b * DI_N + jg) * 128 + n * 32 + c0);
            else if (jg < CAT_N)
                pk = *reinterpret_cast<const bf16x8*>(
                    okS + ((size_t)b * OI_N + t * 84 + (jg - DI_N)) * 128 + n * 32 + c0);
            *reinterpret_cast<bf16x8*>(&Kt[jl * 40 + c0]) = pk;
        }
        {
            int c = tid >> 3, j0 = (tid & 7) * 8;
            int jg0 = jc + j0;
            const short* dvaRow = dvaS + ((size_t)b * FF_N + n * 32 + c) * DI_N;
            const short* ovRow = ovS + ((size_t)b * FF_N + n * 32 + c) * OI_N + t * 84;
            bf16x8 pk;
            if (jg0 + 8 <= DI_N) {
                pk = *reinterpret_cast<const bf16x8*>(dvaRow + jg0);
            } else if (jg0 >= DI_N && jg0 + 8 <= CAT_N) {
                short4 lo = *reinterpret_cast<const short4*>(ovRow + (jg0 - DI_N));
                short4 hi = *reinterpret_cast<const short4*>(ovRow + (jg0 - DI_N) + 4);
                pk[0]=lo.x; pk[1]=lo.y; pk[2]=lo.z; pk[3]=lo.w;
                pk[4]=hi.x; pk[5]=hi.y; pk[6]=hi.z; pk[7]=hi.w;
            } else {
                #pragma unroll
                for (int p = 0; p < 8; ++p) {
                    int jg = jg0 + p;
                    pk[p] = (jg < DI_N) ? dvaRow[jg]
                          : ((jg < CAT_N) ? ovRow[jg - DI_N] : (short)0);
                }
            }
            *reinterpret_cast<bf16x8*>(&Vs[c * 72 + j0]) = pk;
        }
        __syncthreads();

        f32x4 s[6];
        bf16x8 afr = *reinterpret_cast<const bf16x8*>(&Kt[(wv * 16 + l15) * 40 + q * 8]);
        #pragma unroll
        for (int nt = 0; nt < 6; ++nt) {
            bf16x8 bfr = *reinterpret_cast<const bf16x8*>(&Qt[(nt * 16 + l15) * 40 + q * 8]);
            f32x4 z = {};
            s[nt] = __builtin_amdgcn_mfma_f32_16x16x32_bf16(afr, bfr, z, 0, 0, 0);
        }
        float inv[4];
        #pragma unroll
        for (int r = 0; r < 4; ++r) {
            if (l15 >= 4) s[5][r] = -3.0e38f;
            float m2 = s[0][r];
            #pragma unroll
            for (int nt2 = 1; nt2 < 6; ++nt2) m2 = fmaxf(m2, s[nt2][r]);
            #pragma unroll
            for (int o = 1; o < 16; o <<= 1) m2 = fmaxf(m2, __shfl_xor(m2, o));
            float sm = 0.f;
            #pragma unroll
            for (int nt2 = 0; nt2 < 6; ++nt2) { float e = __expf(s[nt2][r] - m2); s[nt2][r] = e; sm += e; }
            #pragma unroll
            for (int o = 1; o < 16; o <<= 1) sm += __shfl_xor(sm, o);
            inv[r] = 1.f / sm;
        }
        #pragma unroll
        for (int nt = 0; nt < 6; ++nt) {
            short4 pk4;
            pk4.x = f2bf(s[nt][0] * inv[0]);
            pk4.y = f2bf(s[nt][1] * inv[1]);
            pk4.z = f2bf(s[nt][2] * inv[2]);
            pk4.w = f2bf(s[nt][3] * inv[3]);
            *reinterpret_cast<short4*>(&Pt[(nt * 16 + l15) * 72 + wv * 16 + q * 4]) = pk4;
        }
        __syncthreads();

        #pragma unroll
        for (int kk = 0; kk < 2; ++kk) {
            bf16x8 va = *reinterpret_cast<const bf16x8*>(&Vs[(pv_mt * 16 + l15) * 72 + kk * 32 + q * 8]);
            #pragma unroll
            for (int u = 0; u < 3; ++u) {
                int nt = pv_nb + u * 2;
                bf16x8 pb = *reinterpret_cast<const bf16x8*>(&Pt[(nt * 16 + l15) * 72 + kk * 32 + q * 8]);
                oacc[u] = __builtin_amdgcn_mfma_f32_16x16x32_bf16(va, pb, oacc[u], 0, 0, 0);
            }
        }
    }

    #pragma unroll
    for (int u = 0; u < 3; ++u) {
        int i = (pv_nb + u * 2) * 16 + l15;
        if (i < HW_N) {
            short4 st;
            st.x = f2bf(oacc[u][0]); st.y = f2bf(oacc[u][1]);
            st.z = f2bf(oacc[u][2]); st.w = f2bf(oacc[u][3]);
            *reinterpret_cast<short4*>(
                ovaS + (((size_t)b * OT_N + t) * 84 + i) * 128 + n * 32 + pv_mt * 16 + q * 4) = st;
        }
    }
}

// ---------------- output projection + ReLU + residual (bf16 x) + stats ----
__global__ __launch_bounds__(256) void outproj_mfma_kernel(
    short* __restrict__ xbf, const short* __restrict__ ws, int layer,
    float* __restrict__ stats)
{
    __shared__ short As[4096];
    __shared__ short Bs[3072];

    const int bid = blockIdx.x;
    const int b = bid >> 7, rem = bid & 127, t = rem >> 2, mt = rem & 3;
    const int o0 = mt * 128;
    const short* WoS = ws + SW_OWO + layer * 65536 + (size_t)o0 * FF_N;
    const short* ovaS = ws + S_OVA + (((size_t)b * OT_N + t) * 84) * 128;

    const int tid = threadIdx.x;
    const int lane = tid & 63, wv = tid >> 6;
    const int l15 = lane & 15, q = lane >> 4;

    f32x4 acc[2][6] = {};

    for (int k0 = 0; k0 < FF_N; k0 += 32) {
        __syncthreads();
        #pragma unroll
        for (int h = 0; h < 2; ++h) {
            int c = tid + h * 256;
            int kc = c & 3, m = c >> 2;
            bf16x8 pk = *reinterpret_cast<const bf16x8*>(WoS + (size_t)m * FF_N + k0 + kc * 8);
            *reinterpret_cast<bf16x8*>(&As[(kc * 128 + m) * 8]) = pk;
        }
        for (int c = tid; c < 384; c += 256) {
            int n2 = c % 96, kc = c / 96;
            bf16x8 pk = {0,0,0,0,0,0,0,0};
            if (n2 < HW_N)
                pk = *reinterpret_cast<const bf16x8*>(ovaS + (size_t)n2 * 128 + k0 + kc * 8);
            *reinterpret_cast<bf16x8*>(&Bs[(kc * 96 + n2) * 8]) = pk;
        }
        __syncthreads();

        bf16x8 af[2];
        #pragma unroll
        for (int mt2 = 0; mt2 < 2; ++mt2)
            af[mt2] = *reinterpret_cast<const bf16x8*>(
                &As[(q * 128 + wv * 32 + mt2 * 16 + l15) * 8]);
        #pragma unroll
        for (int nt = 0; nt < 6; ++nt) {
            bf16x8 bf = *reinterpret_cast<const bf16x8*>(&Bs[(q * 96 + nt * 16 + l15) * 8]);
            #pragma unroll
            for (int mt2 = 0; mt2 < 2; ++mt2)
                acc[mt2][nt] = __builtin_amdgcn_mfma_f32_16x16x32_bf16(
                    af[mt2], bf, acc[mt2][nt], 0, 0, 0);
        }
    }

    float csum[2][4] = {}, csq[2][4] = {};
    #pragma unroll
    for (int mt2 = 0; mt2 < 2; ++mt2) {
        const int och = o0 + wv * 32 + mt2 * 16 + q * 4;
        #pragma unroll
        for (int nt = 0; nt < 6; ++nt) {
            int i = nt * 16 + l15;
            if (i < HW_N) {
                short* p = xbf + ((size_t)b * THW_N + (size_t)(DT_N + t) * HW_N + i) * 512 + och;
                short4 old4 = *reinterpret_cast<short4*>(p);
                short4 nw;
                float ov[4] = {bf2f(old4.x), bf2f(old4.y), bf2f(old4.z), bf2f(old4.w)};
                short* nwp = &nw.x;
                #pragma unroll
                for (int r = 0; r < 4; ++r) {
                    float v = acc[mt2][nt][r];
                    float y = ov[r] + (v > 0.f ? v : 0.f);
                    short ybf = f2bf(y);
                    nwp[r] = ybf;
                    float yr = bf2f(ybf);
                    csum[mt2][r] += yr;
                    csq[mt2][r] += yr * yr;
                }
                *reinterpret_cast<short4*>(p) = nw;
            }
        }
    }
    #pragma unroll
    for (int mt2 = 0; mt2 < 2; ++mt2) {
        #pragma unroll
        for (int r = 0; r < 4; ++r) {
            float s = csum[mt2][r], qq = csq[mt2][r];
            #pragma unroll
            for (int o = 1; o < 16; o <<= 1) {
                s += __shfl_xor(s, o);
                qq += __shfl_xor(qq, o);
            }
            if (l15 == 0) {
                int ch = o0 + wv * 32 + mt2 * 16 + q * 4 + r;
                atomicAdd(&stats[ch], s);
                atomicAdd(&stats[512 + ch], qq);
            }
        }
    }
}

// ---------------- BN in place on bf16 xbf + demo-stats for next layer -----
__global__ __launch_bounds__(256) void bn_mid_kernel(
    short* __restrict__ xbf, const float* __restrict__ stats,
    const float* __restrict__ gamma, const float* __restrict__ beta,
    float* __restrict__ stats_next)
{
    __shared__ float red_s[4][512];
    __shared__ float red_q[4][512];

    const int bid = blockIdx.x;
    const int b = bid / 63, tt = bid % 63;
    const int t0 = tt * 48;
    const bool is_demo = (tt < 7);
    const int tid = threadIdx.x;
    const int chg = tid & 63;
    const int trow = tid >> 6;

    float mean[8], rs[8], g[8], bb[8];
    #pragma unroll
    for (int j = 0; j < 8; ++j) {
        int c = chg * 8 + j;
        float m = stats[c] * INV_CNT;
        float var = stats[512 + c] * INV_CNT - m * m;
        mean[j] = m;
        rs[j] = rsqrtf(var + BN_EPS);
        g[j] = gamma[c];
        bb[j] = beta[c];
    }

    float psum[8] = {}, psq[8] = {};
    #pragma unroll
    for (int it = 0; it < 12; ++it) {
        int tok = t0 + it * 4 + trow;
        short* p = xbf + ((size_t)b * THW_N + tok) * 512 + chg * 8;
        bf16x8 v = *reinterpret_cast<bf16x8*>(p);
        bf16x8 w;
        #pragma unroll
        for (int j = 0; j < 8; ++j) {
            float y = g[j] * (bf2f(v[j]) - mean[j]) * rs[j] + bb[j];
            short yb = f2bf(y);
            w[j] = yb;
            if (is_demo) {
                float yr = bf2f(yb);
                psum[j] += yr; psq[j] += yr * yr;
            }
        }
        *reinterpret_cast<bf16x8*>(p) = w;
    }
    if (!is_demo) return;
    #pragma unroll
    for (int j = 0; j < 8; ++j) {
        red_s[trow][chg * 8 + j] = psum[j];
        red_q[trow][chg * 8 + j] = psq[j];
    }
    __syncthreads();
    #pragma unroll
    for (int h = 0; h < 2; ++h) {
        int c = tid + h * 256;
        float s = red_s[0][c] + red_s[1][c] + red_s[2][c] + red_s[3][c];
        float qq = red_q[0][c] + red_q[1][c] + red_q[2][c] + red_q[3][c];
        atomicAdd(&stats_next[c], s);
        atomicAdd(&stats_next[512 + c], qq);
    }
}

// ---------------- final BN -> fp32 channel-major d_out --------------------
__global__ __launch_bounds__(256) void bn_out_kernel(
    const short* __restrict__ xbf, float* __restrict__ out_f,
    const float* __restrict__ stats,
    const float* __restrict__ gamma, const float* __restrict__ beta)
{
    __shared__ float tile[48][65];

    const int bid = blockIdx.x;
    const int b = bid / 504, rem = bid % 504, tt = rem >> 3, cblk = rem & 7;
    const int t0 = tt * 48, c0 = cblk * 64;
    const int tid = threadIdx.x;
    const int cg = tid & 15;

    float mean[4], rs[4], g[4], bb[4];
    #pragma unroll
    for (int j = 0; j < 4; ++j) {
        int c = c0 + cg * 4 + j;
        float m = stats[c] * INV_CNT;
        float var = stats[512 + c] * INV_CNT - m * m;
        mean[j] = m; rs[j] = rsqrtf(var + BN_EPS);
        g[j] = gamma[c]; bb[j] = beta[c];
    }

    #pragma unroll
    for (int l0 = 0; l0 < 768; l0 += 256) {
        int l = l0 + tid;
        int tok = l >> 4;
        short4 v = *reinterpret_cast<const short4*>(
            xbf + ((size_t)b * THW_N + t0 + tok) * 512 + c0 + cg * 4);
        tile[tok][cg * 4 + 0] = g[0] * (bf2f(v.x) - mean[0]) * rs[0] + bb[0];
        tile[tok][cg * 4 + 1] = g[1] * (bf2f(v.y) - mean[1]) * rs[1] + bb[1];
        tile[tok][cg * 4 + 2] = g[2] * (bf2f(v.z) - mean[2]) * rs[2] + bb[2];
        tile[tok][cg * 4 + 3] = g[3] * (bf2f(v.w) - mean[3]) * rs[3] + bb[3];
    }
    __syncthreads();
    #pragma unroll
    for (int l0 = 0; l0 < 768; l0 += 256) {
        int l = l0 + tid;
        int cc = l / 12, tg = l % 12;
        float4 o;
        o.x = tile[tg * 4 + 0][cc];
        o.y = tile[tg * 4 + 1][cc];
        o.z = tile[tg * 4 + 2][cc];
        o.w = tile[tg * 4 + 3][cc];
        *reinterpret_cast<float4*>(
            out_f + ((size_t)b * D_N + c0 + cc) * THW_N + t0 + tg * 4) = o;
    }
}

// ---------------- launch ----------------
extern "C" void kernel_launch(void* const* d_in, const int* in_sizes, int n_in,
                              void* d_out, int out_size, void* d_ws, size_t ws_size,
                              hipStream_t stream)
{
    const float* inp  = (const float*)d_in[0];
    const float* dwq  = (const float*)d_in[1];
    const float* dwk  = (const float*)d_in[2];
    const float* dwv  = (const float*)d_in[3];
    const float* owq  = (const float*)d_in[5];
    const float* owk  = (const float*)d_in[6];
    const float* owv  = (const float*)d_in[7];
    const float* owo  = (const float*)d_in[8];
    const float* gam  = (const float*)d_in[9];
    const float* bet  = (const float*)d_in[10];
    float* x  = (float*)d_out;
    float* stats = (float*)d_ws;          // [2][1024]
    short* wsS = (short*)(stats + 2048);
    short* xbf = wsS + S_XBF;

    cvt_w_kernel<<<448, 256, 0, stream>>>(dwq, dwk, dwv, owq, owk, owv, owo, wsS, stats);
    xin_kernel<<<4032, 256, 0, stream>>>(inp, xbf, stats);

    for (int layer = 0; layer < 2; ++layer) {
        float* stL = stats + layer * 1024;
        size_t coff = (size_t)layer * D_N;
        proj_mfma_kernel<<<504, 256, 0, stream>>>(xbf, wsS, layer);
        demo_attn_mfma_kernel<<<256, 192, 0, stream>>>(wsS);
        obs_attn_mfma_kernel<<<1024, 256, 0, stream>>>(wsS);
        outproj_mfma_kernel<<<1024, 256, 0, stream>>>(xbf, wsS, layer, stL);
        if (layer == 0) {
            bn_mid_kernel<<<504, 256, 0, stream>>>(
                xbf, stL, gam + coff, bet + coff, stats + 1024);
        } else {
            bn_out_kernel<<<4032, 256, 0, stream>>>(
                xbf, x, stL, gam + coff, bet + coff);
        }
    }
    (void)in_sizes; (void)n_in; (void)out_size; (void)ws_size;
}